// Round 4
// baseline (22161.224 us; speedup 1.0000x reference)
//
#include <hip/hip_runtime.h>
#include <stdint.h>

// ---------------------------------------------------------------------------
// Block_6554120094246: dual-stream transformer block (CLIP + video streams).
// Inputs f32, output f32 (reference dtype). Residual streams live directly in
// d_out (f32). bf16 intermediates + f32 accumulation (threshold 0.111 is
// bf16-compute tolerant). ws use ~65 MB.
// ---------------------------------------------------------------------------

typedef uint16_t u16;
typedef uint16_t u16x8 __attribute__((ext_vector_type(8)));

__device__ __forceinline__ float b2f(u16 u) {
    union { float f; uint32_t i; } x;
    x.i = ((uint32_t)u) << 16;
    return x.f;
}
__device__ __forceinline__ u16 f2b(float f) {
    union { float f; uint32_t i; } x;
    x.f = f;
    uint32_t i = x.i;
    uint32_t r = (i + 0x7FFFu + ((i >> 16) & 1u)) >> 16;  // RNE
    return (u16)r;
}

__global__ void f2b_kernel(const float* __restrict__ in, u16* __restrict__ out, int n) {
    int i = blockIdx.x * 256 + threadIdx.x;
    if (i < n) out[i] = f2b(in[i]);
}
__global__ void copy_f32(const float* __restrict__ in, float* __restrict__ out, int n) {
    int i = blockIdx.x * 256 + threadIdx.x;
    if (i < n) out[i] = in[i];
}

// ---- bias builder: dst = concat(p0[0:n0], p1[0:n1], p2[0:n2]); null -> 0 ----
__global__ void build_bias(float* __restrict__ dst,
                           const float* p0, int n0, const float* p1, int n1,
                           const float* p2, int n2) {
    int i = blockIdx.x * 256 + threadIdx.x;
    int total = n0 + n1 + n2;
    if (i >= total) return;
    const float* p; int j;
    if (i < n0)           { p = p0; j = i; }
    else if (i < n0 + n1) { p = p1; j = i - n0; }
    else                  { p = p2; j = i - n0 - n1; }
    dst[i] = p ? p[j] : 0.f;
}

// ---- block reductions (blockDim.x == 256, 4 waves of 64) --------------------
__device__ __forceinline__ float block_sum(float v, float* red) {
    #pragma unroll
    for (int o = 32; o > 0; o >>= 1) v += __shfl_down(v, o, 64);
    int w = threadIdx.x >> 6, l = threadIdx.x & 63;
    __syncthreads();
    if (l == 0) red[w] = v;
    __syncthreads();
    return red[0] + red[1] + red[2] + red[3];
}
__device__ __forceinline__ float block_max(float v, float* red) {
    #pragma unroll
    for (int o = 32; o > 0; o >>= 1) v = fmaxf(v, __shfl_down(v, o, 64));
    int w = threadIdx.x >> 6, l = threadIdx.x & 63;
    __syncthreads();
    if (l == 0) red[w] = v;
    __syncthreads();
    return fmaxf(fmaxf(red[0], red[1]), fmaxf(red[2], red[3]));
}

// ---- LayerNorm over C=768: f32 in, f32 params, bf16 out ---------------------
__global__ __launch_bounds__(256) void ln_kernel(
    const float* __restrict__ x, const float* __restrict__ g,
    const float* __restrict__ bta, u16* __restrict__ y) {
    const int r = blockIdx.x;
    const int t = threadIdx.x;
    const float* xr = x + (size_t)r * 768;
    float v0 = xr[t], v1 = xr[t + 256], v2 = xr[t + 512];
    __shared__ float red[4];
    float mean = block_sum(v0 + v1 + v2, red) * (1.0f / 768.0f);
    float d0 = v0 - mean, d1 = v1 - mean, d2 = v2 - mean;
    float var = block_sum(d0 * d0 + d1 * d1 + d2 * d2, red) * (1.0f / 768.0f);
    float rs = rsqrtf(var + 1e-5f);
    u16* yr = y + (size_t)r * 768;
    yr[t]       = f2b(d0 * rs * g[t]       + bta[t]);
    yr[t + 256] = f2b(d1 * rs * g[t + 256] + bta[t + 256]);
    yr[t + 512] = f2b(d2 * rs * g[t + 512] + bta[t + 512]);
}

// ---- GEMM: C[M,N] = A[M,K](bf16) @ W[N,K](f32)^T + bias[N], f32 accumulate --
// MODE 0: store bf16.  MODE 1: Cf[r,c] += v (f32 residual add).
// MODE 2: QuickGELU -> bf16.  MODE 3: exact GELU -> bf16.
template <int MODE>
__global__ __launch_bounds__(256) void gemm_bias(
    const u16* __restrict__ A, const float* __restrict__ W,
    const float* __restrict__ bias, u16* __restrict__ Cb,
    float* __restrict__ Cf, int M, int N, int K) {
    __shared__ float As[32][65];
    __shared__ float Bs[32][65];
    const int tid = threadIdx.x;
    const int m0 = blockIdx.x * 64;
    const int n0 = blockIdx.y * 64;
    const int lrow = tid >> 2;        // 0..63
    const int lcg = (tid & 3) << 3;   // 0,8,16,24
    const int ty = tid >> 4, tx = tid & 15;
    float acc[4][4] = {};
    for (int k0 = 0; k0 < K; k0 += 32) {
        int ar = m0 + lrow;
        if (ar < M) {
            u16x8 va = *(const u16x8*)(A + (size_t)ar * K + k0 + lcg);
            #pragma unroll
            for (int e = 0; e < 8; e++) As[lcg + e][lrow] = b2f(va[e]);
        } else {
            #pragma unroll
            for (int e = 0; e < 8; e++) As[lcg + e][lrow] = 0.f;
        }
        const float* wr = W + (size_t)(n0 + lrow) * K + k0 + lcg;
        float4 w0 = *(const float4*)wr;
        float4 w1 = *(const float4*)(wr + 4);
        Bs[lcg + 0][lrow] = w0.x; Bs[lcg + 1][lrow] = w0.y;
        Bs[lcg + 2][lrow] = w0.z; Bs[lcg + 3][lrow] = w0.w;
        Bs[lcg + 4][lrow] = w1.x; Bs[lcg + 5][lrow] = w1.y;
        Bs[lcg + 6][lrow] = w1.z; Bs[lcg + 7][lrow] = w1.w;
        __syncthreads();
        #pragma unroll
        for (int kk = 0; kk < 32; kk++) {
            float a[4], b[4];
            #pragma unroll
            for (int i = 0; i < 4; i++) a[i] = As[kk][ty * 4 + i];
            #pragma unroll
            for (int j = 0; j < 4; j++) b[j] = Bs[kk][tx * 4 + j];
            #pragma unroll
            for (int i = 0; i < 4; i++)
                #pragma unroll
                for (int j = 0; j < 4; j++)
                    acc[i][j] = fmaf(a[i], b[j], acc[i][j]);
        }
        __syncthreads();
    }
    #pragma unroll
    for (int i = 0; i < 4; i++) {
        int r = m0 + ty * 4 + i;
        if (r >= M) continue;
        #pragma unroll
        for (int j = 0; j < 4; j++) {
            int c = n0 + tx * 4 + j;
            float v = acc[i][j] + bias[c];
            if (MODE == 1) {
                Cf[(size_t)r * N + c] += v;
            } else {
                if (MODE == 2) v = v / (1.0f + expf(-1.702f * v));
                if (MODE == 3) v = 0.5f * v * (1.0f + erff(v * 0.70710678118654752f));
                Cb[(size_t)r * N + c] = f2b(v);
            }
        }
    }
}

// ---- generic strided attention (HD=64, scale=0.125) -------------------------
// grid = (Nq, A*12); a = blockIdx.y/12, h = blockIdx.y%12.
// q row i: qp + a*qA + i*qI + h*64 ; k/v row j: kp + a*kA + j*kJ + h*64.
__global__ __launch_bounds__(256) void attn_kernel(
    const u16* __restrict__ qp, const u16* __restrict__ kp,
    const u16* __restrict__ vp, u16* __restrict__ op, int Nk,
    long long qA, long long qI, long long kA, long long kJ,
    long long vA, long long vJ, long long oA, long long oI) {
    const int i = blockIdx.x;
    const int a = blockIdx.y / 12, h = blockIdx.y % 12;
    const int tid = threadIdx.x;
    __shared__ float qs[64];
    __shared__ float sc[1568];
    __shared__ float red[4];
    __shared__ float pacc[4][64];

    const u16* q = qp + a * qA + (long long)i * qI + h * 64;
    if (tid < 64) qs[tid] = b2f(q[tid]);
    __syncthreads();

    const u16* kbase = kp + a * kA + h * 64;
    float lmax = -INFINITY;
    for (int j = tid; j < Nk; j += 256) {
        const u16x8* kr = (const u16x8*)(kbase + (long long)j * kJ);
        float dot = 0.f;
        #pragma unroll
        for (int w = 0; w < 8; w++) {
            u16x8 kv = kr[w];
            #pragma unroll
            for (int e = 0; e < 8; e++) dot += qs[w * 8 + e] * b2f(kv[e]);
        }
        dot *= 0.125f;
        sc[j] = dot;
        lmax = fmaxf(lmax, dot);
    }
    float m = block_max(lmax, red);
    float lsum = 0.f;
    for (int j = tid; j < Nk; j += 256) {
        float e = expf(sc[j] - m);
        sc[j] = e;
        lsum += e;
    }
    float denom = block_sum(lsum, red);
    __syncthreads();

    const u16* vbase = vp + a * vA + h * 64;
    int d = tid & 63, part = tid >> 6;
    float acc = 0.f;
    for (int j = part; j < Nk; j += 4)
        acc += sc[j] * b2f(vbase[(long long)j * vJ + d]);
    pacc[part][d] = acc;
    __syncthreads();
    if (tid < 64) {
        float o = (pacc[0][tid] + pacc[1][tid] + pacc[2][tid] + pacc[3][tid]) / denom;
        op[a * oA + (long long)i * oI + h * 64 + tid] = f2b(o);
    }
}

// ---------------------------------------------------------------------------
extern "C" void kernel_launch(void* const* d_in, const int* in_sizes, int n_in,
                              void* d_out, int out_size, void* d_ws, size_t ws_size,
                              hipStream_t stream) {
    const int B = 8, sN = 196, tN = 1568;
    const int Ms = B * sN;            // 1568
    const int Mt = B * tN;            // 12544
    const int n_sf = Ms * 768;        // 1204224
    const int n_tf = Mt * 768;        // 9633792
    (void)n_in; (void)out_size; (void)ws_size;

    const bool dict_order = (in_sizes[0] == n_sf);
    auto IN = [&](int di, int ai) -> const float* {
        return (const float*)d_in[dict_order ? di : ai];
    };
    const float* in_sx      = IN(0, 35);
    const float* in_tx      = IN(1, 42);
    const float* ln1s_g     = IN(2, 14);
    const float* ln1s_b     = IN(3, 13);
    const float* mha_w      = IN(4, 28);
    const float* mha_b      = IN(5, 25);
    const float* mha_ow     = IN(6, 27);
    const float* mha_ob     = IN(7, 26);
    const float* ln1t_g     = IN(8, 16);
    const float* ln1t_b     = IN(9, 15);
    const float* attn_qkv_w = IN(10, 3);
    const float* attn_q_b   = IN(11, 2);
    const float* attn_v_b   = IN(12, 4);
    const float* attn_pw    = IN(13, 1);
    const float* attn_pb    = IN(14, 0);
    const float* lnt2s_g    = IN(15, 24);
    const float* lnt2s_b    = IN(16, 23);
    const float* t2s_qw     = IN(17, 41);
    const float* t2s_qb     = IN(18, 40);
    const float* t2s_kvw    = IN(19, 37);
    const float* t2s_kvb    = IN(20, 36);
    const float* t2s_pw     = IN(21, 39);
    const float* t2s_pb     = IN(22, 38);
    const float* lns2t_g    = IN(23, 22);
    const float* lns2t_b    = IN(24, 21);
    const float* s2t_qw     = IN(25, 34);
    const float* s2t_qb     = IN(26, 33);
    const float* s2t_kvw    = IN(27, 30);
    const float* s2t_kvb    = IN(28, 29);
    const float* s2t_pw     = IN(29, 32);
    const float* s2t_pb     = IN(30, 31);
    const float* ln2s_g     = IN(31, 18);
    const float* ln2s_b     = IN(32, 17);
    const float* cfc_w      = IN(33, 6);
    const float* cfc_b      = IN(34, 5);
    const float* cproj_w    = IN(35, 8);
    const float* cproj_b    = IN(36, 7);
    const float* ln2t_g     = IN(37, 20);
    const float* ln2t_b     = IN(38, 19);
    const float* fc1_w      = IN(39, 10);
    const float* fc1_b      = IN(40, 9);
    const float* fc2_w      = IN(41, 12);
    const float* fc2_b      = IN(42, 11);

    // ---- residual streams live in d_out (f32 output dtype) ------------------
    float* s_f = (float*)d_out;           // n_sf
    float* t_f = (float*)d_out + n_sf;    // n_tf

    // ---- workspace (~65 MB) -------------------------------------------------
    char* ws = (char*)d_ws;
    size_t off = 0;
    auto take = [&](size_t bytes) { size_t o = off; off += (bytes + 255) & ~(size_t)255; return o; };
    float* biasf = (float*)(ws + take(3072 * 4));
    u16*   yb    = (u16*)(ws + take((size_t)Mt * 768 * 2));          // 19.3 MB
    u16*   big   = (u16*)(ws + take((size_t)Mt * 1536 * 2));         // 38.5 MB

    auto cdiv = [](int a, int b) { return (a + b - 1) / b; };
    #define BB(b0, c0, b1, c1, b2, c2) \
        build_bias<<<cdiv((c0) + (c1) + (c2), 256), 256, 0, stream>>>(biasf, b0, c0, b1, c1, b2, c2)

    // residual streams <- inputs
    copy_f32<<<cdiv(n_sf, 256), 256, 0, stream>>>(in_sx, s_f, n_sf);
    copy_f32<<<cdiv(n_tf, 256), 256, 0, stream>>>(in_tx, t_f, n_tf);

    // ---- stage 1: clip self-attention (attends over the batch axis) ---------
    ln_kernel<<<Ms, 256, 0, stream>>>(s_f, ln1s_g, ln1s_b, yb);
    BB(mha_b, 2304, (const float*)0, 0, (const float*)0, 0);
    gemm_bias<0><<<dim3(cdiv(Ms, 64), 36), 256, 0, stream>>>(yb, mha_w, biasf, big, (float*)0, Ms, 2304, 768);
    attn_kernel<<<dim3(8, sN * 12), 256, 0, stream>>>(
        big, big + 768, big + 1536, yb + (size_t)Ms * 768, /*Nk=*/8,
        /*qA=*/2304LL, /*qI=*/(long long)sN * 2304,
        /*kA=*/2304LL, /*kJ=*/(long long)sN * 2304,
        /*vA=*/2304LL, /*vJ=*/(long long)sN * 2304,
        /*oA=*/768LL,  /*oI=*/(long long)sN * 768);
    BB(mha_ob, 768, (const float*)0, 0, (const float*)0, 0);
    gemm_bias<1><<<dim3(cdiv(Ms, 64), 12), 256, 0, stream>>>(yb + (size_t)Ms * 768, mha_ow, biasf, (u16*)0, s_f, Ms, 768, 768);

    // ---- stage 2: video self-attention (per-batch QKV to bound ws) ----------
    ln_kernel<<<Mt, 256, 0, stream>>>(t_f, ln1t_g, ln1t_b, yb);
    BB(attn_q_b, 768, (const float*)0, 768, attn_v_b, 768);  // [q_b, 0, v_b]
    u16* s2out = big + (size_t)tN * 2304;                    // attn out (Mt*768)
    for (int b = 0; b < B; b++) {
        gemm_bias<0><<<dim3(cdiv(tN, 64), 36), 256, 0, stream>>>(
            yb + (size_t)b * tN * 768, attn_qkv_w, biasf, big, (float*)0, tN, 2304, 768);
        attn_kernel<<<dim3(tN, 12), 256, 0, stream>>>(
            big, big + 768, big + 1536, s2out + (size_t)b * tN * 768, /*Nk=*/tN,
            0LL, 2304LL, 0LL, 2304LL, 0LL, 2304LL, 0LL, 768LL);
    }
    BB(attn_pb, 768, (const float*)0, 0, (const float*)0, 0);
    gemm_bias<1><<<dim3(cdiv(Mt, 64), 12), 256, 0, stream>>>(s2out, attn_pw, biasf, (u16*)0, t_f, Mt, 768, 768);

    // ---- stage 3: T2S cross (q from LN(s_x), kv from updated t_x) -----------
    f2b_kernel<<<cdiv(n_tf, 256), 256, 0, stream>>>(t_f, yb, n_tf);   // bf16(t_x)
    BB((const float*)0, 768, t2s_kvb, 768, (const float*)0, 0);       // [0, kvb]
    gemm_bias<0><<<dim3(cdiv(Mt, 64), 24), 256, 0, stream>>>(yb, t2s_kvw, biasf, big, (float*)0, Mt, 1536, 768);
    ln_kernel<<<Ms, 256, 0, stream>>>(s_f, lnt2s_g, lnt2s_b, yb);     // yb[0:Ms*768]
    BB(t2s_qb, 768, (const float*)0, 0, (const float*)0, 0);
    u16* q3 = yb + (size_t)Ms * 768;
    u16* o3 = yb + (size_t)2 * Ms * 768;
    gemm_bias<0><<<dim3(cdiv(Ms, 64), 12), 256, 0, stream>>>(yb, t2s_qw, biasf, q3, (float*)0, Ms, 768, 768);
    attn_kernel<<<dim3(sN, B * 12), 256, 0, stream>>>(
        q3, big, big + 768, o3, /*Nk=*/tN,
        (long long)sN * 768, 768LL,
        (long long)tN * 1536, 1536LL,
        (long long)tN * 1536, 1536LL,
        (long long)sN * 768, 768LL);
    BB(t2s_pb, 768, (const float*)0, 0, (const float*)0, 0);
    gemm_bias<1><<<dim3(cdiv(Ms, 64), 12), 256, 0, stream>>>(o3, t2s_pw, biasf, (u16*)0, s_f, Ms, 768, 768);

    // ---- stage 4: S2T cross (q from LN(t_x), kv from updated s_x) -----------
    ln_kernel<<<Mt, 256, 0, stream>>>(t_f, lns2t_g, lns2t_b, yb);
    BB(s2t_qb, 768, (const float*)0, 0, (const float*)0, 0);
    u16* q4 = big;                                  // Mt*768
    u16* kv4 = big + (size_t)Mt * 768;              // Ms*1536
    gemm_bias<0><<<dim3(cdiv(Mt, 64), 12), 256, 0, stream>>>(yb, s2t_qw, biasf, q4, (float*)0, Mt, 768, 768);
    f2b_kernel<<<cdiv(n_sf, 256), 256, 0, stream>>>(s_f, yb, n_sf);   // bf16(s_x)
    BB((const float*)0, 768, s2t_kvb, 768, (const float*)0, 0);
    gemm_bias<0><<<dim3(cdiv(Ms, 64), 24), 256, 0, stream>>>(yb, s2t_kvw, biasf, kv4, (float*)0, Ms, 1536, 768);
    attn_kernel<<<dim3(tN, B * 12), 256, 0, stream>>>(
        q4, kv4, kv4 + 768, yb, /*Nk=*/sN,
        (long long)tN * 768, 768LL,
        (long long)sN * 1536, 1536LL,
        (long long)sN * 1536, 1536LL,
        (long long)tN * 768, 768LL);
    BB(s2t_pb, 768, (const float*)0, 0, (const float*)0, 0);
    gemm_bias<1><<<dim3(cdiv(Mt, 64), 12), 256, 0, stream>>>(yb, s2t_pw, biasf, (u16*)0, t_f, Mt, 768, 768);

    // ---- stage 5: clip MLP (QuickGELU) --------------------------------------
    ln_kernel<<<Ms, 256, 0, stream>>>(s_f, ln2s_g, ln2s_b, yb);
    BB(cfc_b, 3072, (const float*)0, 0, (const float*)0, 0);
    gemm_bias<2><<<dim3(cdiv(Ms, 64), 48), 256, 0, stream>>>(yb, cfc_w, biasf, big, (float*)0, Ms, 3072, 768);
    BB(cproj_b, 768, (const float*)0, 0, (const float*)0, 0);
    gemm_bias<1><<<dim3(cdiv(Ms, 64), 12), 256, 0, stream>>>(big, cproj_w, biasf, (u16*)0, s_f, Ms, 768, 3072);

    // ---- stage 6: video MLP (exact GELU), two row-halves --------------------
    ln_kernel<<<Mt, 256, 0, stream>>>(t_f, ln2t_g, ln2t_b, yb);
    for (int c = 0; c < 2; c++) {
        int r0 = c * (Mt / 2), Mc = Mt / 2;
        BB(fc1_b, 3072, (const float*)0, 0, (const float*)0, 0);
        gemm_bias<3><<<dim3(cdiv(Mc, 64), 48), 256, 0, stream>>>(
            yb + (size_t)r0 * 768, fc1_w, biasf, big, (float*)0, Mc, 3072, 768);
        BB(fc2_b, 768, (const float*)0, 0, (const float*)0, 0);
        gemm_bias<1><<<dim3(cdiv(Mc, 64), 12), 256, 0, stream>>>(
            big, fc2_w, biasf, (u16*)0, t_f + (size_t)r0 * 768, Mc, 768, 3072);
    }
    #undef BB
}

// Round 5
// 15436.459 us; speedup vs baseline: 1.4356x; 1.4356x over previous
//
#include <hip/hip_runtime.h>
#include <stdint.h>

// ---------------------------------------------------------------------------
// Block_6554120094246: dual-stream transformer block (CLIP + video streams).
// f32 in/out. Residual streams in d_out. bf16 intermediates + MFMA GEMM
// (16x16x32 bf16, 128x128 tile), f32 accumulation. ws ~134 MB.
// ---------------------------------------------------------------------------

typedef uint16_t u16;
typedef uint16_t u16x8 __attribute__((ext_vector_type(8)));
typedef short bf16x8 __attribute__((ext_vector_type(8)));
typedef float f32x4 __attribute__((ext_vector_type(4)));

__device__ __forceinline__ float b2f(u16 u) {
    union { float f; uint32_t i; } x;
    x.i = ((uint32_t)u) << 16;
    return x.f;
}
__device__ __forceinline__ u16 f2b(float f) {
    union { float f; uint32_t i; } x;
    x.f = f;
    uint32_t i = x.i;
    uint32_t r = (i + 0x7FFFu + ((i >> 16) & 1u)) >> 16;  // RNE
    return (u16)r;
}

__global__ void f2b_kernel(const float* __restrict__ in, u16* __restrict__ out, int n) {
    int i = blockIdx.x * 256 + threadIdx.x;
    if (i < n) out[i] = f2b(in[i]);
}
__global__ void copy_f32(const float* __restrict__ in, float* __restrict__ out, int n) {
    int i = blockIdx.x * 256 + threadIdx.x;
    if (i < n) out[i] = in[i];
}

// ---- bias builder: dst = concat(p0[0:n0], p1[0:n1], p2[0:n2]); null -> 0 ----
__global__ void build_bias(float* __restrict__ dst,
                           const float* p0, int n0, const float* p1, int n1,
                           const float* p2, int n2) {
    int i = blockIdx.x * 256 + threadIdx.x;
    int total = n0 + n1 + n2;
    if (i >= total) return;
    const float* p; int j;
    if (i < n0)           { p = p0; j = i; }
    else if (i < n0 + n1) { p = p1; j = i - n0; }
    else                  { p = p2; j = i - n0 - n1; }
    dst[i] = p ? p[j] : 0.f;
}

// ---- block reductions (blockDim.x == 256, 4 waves of 64) --------------------
__device__ __forceinline__ float block_sum(float v, float* red) {
    #pragma unroll
    for (int o = 32; o > 0; o >>= 1) v += __shfl_down(v, o, 64);
    int w = threadIdx.x >> 6, l = threadIdx.x & 63;
    __syncthreads();
    if (l == 0) red[w] = v;
    __syncthreads();
    return red[0] + red[1] + red[2] + red[3];
}
__device__ __forceinline__ float block_max(float v, float* red) {
    #pragma unroll
    for (int o = 32; o > 0; o >>= 1) v = fmaxf(v, __shfl_down(v, o, 64));
    int w = threadIdx.x >> 6, l = threadIdx.x & 63;
    __syncthreads();
    if (l == 0) red[w] = v;
    __syncthreads();
    return fmaxf(fmaxf(red[0], red[1]), fmaxf(red[2], red[3]));
}

// ---- LayerNorm over C=768: f32 in, f32 params, bf16 out ---------------------
__global__ __launch_bounds__(256) void ln_kernel(
    const float* __restrict__ x, const float* __restrict__ g,
    const float* __restrict__ bta, u16* __restrict__ y) {
    const int r = blockIdx.x;
    const int t = threadIdx.x;
    const float* xr = x + (size_t)r * 768;
    float v0 = xr[t], v1 = xr[t + 256], v2 = xr[t + 512];
    __shared__ float red[4];
    float mean = block_sum(v0 + v1 + v2, red) * (1.0f / 768.0f);
    float d0 = v0 - mean, d1 = v1 - mean, d2 = v2 - mean;
    float var = block_sum(d0 * d0 + d1 * d1 + d2 * d2, red) * (1.0f / 768.0f);
    float rs = rsqrtf(var + 1e-5f);
    u16* yr = y + (size_t)r * 768;
    yr[t]       = f2b(d0 * rs * g[t]       + bta[t]);
    yr[t + 256] = f2b(d1 * rs * g[t + 256] + bta[t + 256]);
    yr[t + 512] = f2b(d2 * rs * g[t + 512] + bta[t + 512]);
}

// ---- MFMA GEMM: C[M,N] = A[M,K](bf16) @ W[N,K](bf16)^T + bias[N] ------------
// 128x128 tile, BK=32, 256 thr (4 waves, each 64x64), mfma_f32_16x16x32_bf16.
// A-frag: lane holds A[row=lane&15][k=(lane>>4)*8 + j]; B-frag same with
// row->col (W is [N][K] so both operands stage/read identically).
// C/D: col=lane&15, row=(lane>>4)*4+reg (m89/m91-verified).
// MODE 0: store bf16.  1: Cf += v.  2: QuickGELU->bf16.  3: exact GELU->bf16.
template <int MODE>
__global__ __launch_bounds__(256) void gemm_mfma(
    const u16* __restrict__ A, const u16* __restrict__ W,
    const float* __restrict__ bias, u16* __restrict__ Cb,
    float* __restrict__ Cf, int M, int N, int K) {
    __shared__ u16 As[128][40];  // +8 pad: frag ds_read lands 2-way on banks
    __shared__ u16 Bs[128][40];
    const int tid = threadIdx.x;
    const int lane = tid & 63;
    const int wid = tid >> 6;
    const int wr = (wid >> 1) * 64, wc = (wid & 1) * 64;
    const int m0 = blockIdx.x * 128, n0 = blockIdx.y * 128;
    const int srow = tid >> 1, soff = (tid & 1) * 16;  // stage: 32B per thread
    const int fr = lane & 15, fk = (lane >> 4) * 8;
    f32x4 acc[4][4] = {};
    for (int k0 = 0; k0 < K; k0 += 32) {
        if (m0 + srow < M) {
            const u16* src = A + (size_t)(m0 + srow) * K + k0 + soff;
            *(u16x8*)&As[srow][soff]     = *(const u16x8*)src;
            *(u16x8*)&As[srow][soff + 8] = *(const u16x8*)(src + 8);
        } else {
            u16x8 z = {};
            *(u16x8*)&As[srow][soff] = z;
            *(u16x8*)&As[srow][soff + 8] = z;
        }
        const u16* wsrc = W + (size_t)(n0 + srow) * K + k0 + soff;
        *(u16x8*)&Bs[srow][soff]     = *(const u16x8*)wsrc;
        *(u16x8*)&Bs[srow][soff + 8] = *(const u16x8*)(wsrc + 8);
        __syncthreads();
        bf16x8 a[4], b[4];
        #pragma unroll
        for (int i = 0; i < 4; i++) a[i] = *(const bf16x8*)&As[wr + i * 16 + fr][fk];
        #pragma unroll
        for (int j = 0; j < 4; j++) b[j] = *(const bf16x8*)&Bs[wc + j * 16 + fr][fk];
        #pragma unroll
        for (int i = 0; i < 4; i++)
            #pragma unroll
            for (int j = 0; j < 4; j++)
                acc[i][j] = __builtin_amdgcn_mfma_f32_16x16x32_bf16(a[i], b[j], acc[i][j], 0, 0, 0);
        __syncthreads();
    }
    const int er = (lane >> 4) * 4;
    #pragma unroll
    for (int i = 0; i < 4; i++) {
        #pragma unroll
        for (int reg = 0; reg < 4; reg++) {
            int r = m0 + wr + i * 16 + er + reg;
            if (r >= M) continue;
            #pragma unroll
            for (int j = 0; j < 4; j++) {
                int c = n0 + wc + j * 16 + fr;
                float v = acc[i][j][reg] + bias[c];
                if (MODE == 1) {
                    Cf[(size_t)r * N + c] += v;
                } else {
                    if (MODE == 2) v = v / (1.0f + expf(-1.702f * v));
                    if (MODE == 3) v = 0.5f * v * (1.0f + erff(v * 0.70710678118654752f));
                    Cb[(size_t)r * N + c] = f2b(v);
                }
            }
        }
    }
}

// ---- generic strided attention (HD=64, scale=0.125) -------------------------
__global__ __launch_bounds__(256) void attn_kernel(
    const u16* __restrict__ qp, const u16* __restrict__ kp,
    const u16* __restrict__ vp, u16* __restrict__ op, int Nk,
    long long qA, long long qI, long long kA, long long kJ,
    long long vA, long long vJ, long long oA, long long oI) {
    const int i = blockIdx.x;
    const int a = blockIdx.y / 12, h = blockIdx.y % 12;
    const int tid = threadIdx.x;
    __shared__ float qs[64];
    __shared__ float sc[1568];
    __shared__ float red[4];
    __shared__ float pacc[4][64];

    const u16* q = qp + a * qA + (long long)i * qI + h * 64;
    if (tid < 64) qs[tid] = b2f(q[tid]);
    __syncthreads();

    const u16* kbase = kp + a * kA + h * 64;
    float lmax = -INFINITY;
    for (int j = tid; j < Nk; j += 256) {
        const u16x8* kr = (const u16x8*)(kbase + (long long)j * kJ);
        float dot = 0.f;
        #pragma unroll
        for (int w = 0; w < 8; w++) {
            u16x8 kv = kr[w];
            #pragma unroll
            for (int e = 0; e < 8; e++) dot += qs[w * 8 + e] * b2f(kv[e]);
        }
        dot *= 0.125f;
        sc[j] = dot;
        lmax = fmaxf(lmax, dot);
    }
    float m = block_max(lmax, red);
    float lsum = 0.f;
    for (int j = tid; j < Nk; j += 256) {
        float e = expf(sc[j] - m);
        sc[j] = e;
        lsum += e;
    }
    float denom = block_sum(lsum, red);
    __syncthreads();

    const u16* vbase = vp + a * vA + h * 64;
    int d = tid & 63, part = tid >> 6;
    float acc = 0.f;
    for (int j = part; j < Nk; j += 4)
        acc += sc[j] * b2f(vbase[(long long)j * vJ + d]);
    pacc[part][d] = acc;
    __syncthreads();
    if (tid < 64) {
        float o = (pacc[0][tid] + pacc[1][tid] + pacc[2][tid] + pacc[3][tid]) / denom;
        op[a * oA + (long long)i * oI + h * 64 + tid] = f2b(o);
    }
}

// ---------------------------------------------------------------------------
extern "C" void kernel_launch(void* const* d_in, const int* in_sizes, int n_in,
                              void* d_out, int out_size, void* d_ws, size_t ws_size,
                              hipStream_t stream) {
    const int B = 8, sN = 196, tN = 1568;
    const int Ms = B * sN;            // 1568
    const int Mt = B * tN;            // 12544
    const int n_sf = Ms * 768;        // 1204224
    const int n_tf = Mt * 768;        // 9633792
    (void)n_in; (void)out_size; (void)ws_size;

    const bool dict_order = (in_sizes[0] == n_sf);
    auto IN = [&](int di, int ai) -> const float* {
        return (const float*)d_in[dict_order ? di : ai];
    };
    const float* in_sx      = IN(0, 35);
    const float* in_tx      = IN(1, 42);
    const float* ln1s_g     = IN(2, 14);
    const float* ln1s_b     = IN(3, 13);
    const float* mha_w      = IN(4, 28);
    const float* mha_b      = IN(5, 25);
    const float* mha_ow     = IN(6, 27);
    const float* mha_ob     = IN(7, 26);
    const float* ln1t_g     = IN(8, 16);
    const float* ln1t_b     = IN(9, 15);
    const float* attn_qkv_w = IN(10, 3);
    const float* attn_q_b   = IN(11, 2);
    const float* attn_v_b   = IN(12, 4);
    const float* attn_pw    = IN(13, 1);
    const float* attn_pb    = IN(14, 0);
    const float* lnt2s_g    = IN(15, 24);
    const float* lnt2s_b    = IN(16, 23);
    const float* t2s_qw     = IN(17, 41);
    const float* t2s_qb     = IN(18, 40);
    const float* t2s_kvw    = IN(19, 37);
    const float* t2s_kvb    = IN(20, 36);
    const float* t2s_pw     = IN(21, 39);
    const float* t2s_pb     = IN(22, 38);
    const float* lns2t_g    = IN(23, 22);
    const float* lns2t_b    = IN(24, 21);
    const float* s2t_qw     = IN(25, 34);
    const float* s2t_qb     = IN(26, 33);
    const float* s2t_kvw    = IN(27, 30);
    const float* s2t_kvb    = IN(28, 29);
    const float* s2t_pw     = IN(29, 32);
    const float* s2t_pb     = IN(30, 31);
    const float* ln2s_g     = IN(31, 18);
    const float* ln2s_b     = IN(32, 17);
    const float* cfc_w      = IN(33, 6);
    const float* cfc_b      = IN(34, 5);
    const float* cproj_w    = IN(35, 8);
    const float* cproj_b    = IN(36, 7);
    const float* ln2t_g     = IN(37, 20);
    const float* ln2t_b     = IN(38, 19);
    const float* fc1_w      = IN(39, 10);
    const float* fc1_b      = IN(40, 9);
    const float* fc2_w      = IN(41, 12);
    const float* fc2_b      = IN(42, 11);

    // ---- residual streams live in d_out (f32) -------------------------------
    float* s_f = (float*)d_out;
    float* t_f = (float*)d_out + n_sf;

    // ---- workspace (~134 MB) ------------------------------------------------
    char* ws = (char*)d_ws;
    size_t off = 0;
    auto take = [&](size_t bytes) { size_t o = off; off += (bytes + 255) & ~(size_t)255; return o; };
    float* biasf = (float*)(ws + take(3072 * 4));
    u16*   yb    = (u16*)(ws + take((size_t)Mt * 768 * 2));   // 19.3 MB
    u16*   bufA  = (u16*)(ws + take((size_t)Mt * 2304 * 2));  // 57.8 MB
    u16*   bufB  = (u16*)(ws + take((size_t)Mt * 768 * 2));   // 19.3 MB
    auto wtake = [&](size_t nelem) { return (u16*)(ws + take(nelem * 2)); };
    u16 *W_mha   = wtake(2304 * 768), *W_mhao  = wtake(768 * 768);
    u16 *W_qkv   = wtake(2304 * 768), *W_attnp = wtake(768 * 768);
    u16 *W_t2sq  = wtake(768 * 768),  *W_t2skv = wtake(1536 * 768), *W_t2sp = wtake(768 * 768);
    u16 *W_s2tq  = wtake(768 * 768),  *W_s2tkv = wtake(1536 * 768), *W_s2tp = wtake(768 * 768);
    u16 *W_cfc   = wtake(3072 * 768), *W_cproj = wtake(768 * 3072);
    u16 *W_fc1   = wtake(3072 * 768), *W_fc2   = wtake(768 * 3072);

    auto cdiv = [](int a, int b) { return (a + b - 1) / b; };
    #define BB(b0, c0, b1, c1, b2, c2) \
        build_bias<<<cdiv((c0) + (c1) + (c2), 256), 256, 0, stream>>>(biasf, b0, c0, b1, c1, b2, c2)
    auto CW = [&](const float* src, u16* dst, int n) {
        f2b_kernel<<<cdiv(n, 256), 256, 0, stream>>>(src, dst, n);
    };
    // weights -> bf16 pool (one-time per call, ~37.7 MB)
    CW(mha_w, W_mha, 2304 * 768);      CW(mha_ow, W_mhao, 768 * 768);
    CW(attn_qkv_w, W_qkv, 2304 * 768); CW(attn_pw, W_attnp, 768 * 768);
    CW(t2s_qw, W_t2sq, 768 * 768);     CW(t2s_kvw, W_t2skv, 1536 * 768);
    CW(t2s_pw, W_t2sp, 768 * 768);     CW(s2t_qw, W_s2tq, 768 * 768);
    CW(s2t_kvw, W_s2tkv, 1536 * 768);  CW(s2t_pw, W_s2tp, 768 * 768);
    CW(cfc_w, W_cfc, 3072 * 768);      CW(cproj_w, W_cproj, 768 * 3072);
    CW(fc1_w, W_fc1, 3072 * 768);      CW(fc2_w, W_fc2, 768 * 3072);

    // residual streams <- inputs
    copy_f32<<<cdiv(n_sf, 256), 256, 0, stream>>>(in_sx, s_f, n_sf);
    copy_f32<<<cdiv(n_tf, 256), 256, 0, stream>>>(in_tx, t_f, n_tf);

    // ---- stage 1: clip self-attention (attends over the batch axis) ---------
    ln_kernel<<<Ms, 256, 0, stream>>>(s_f, ln1s_g, ln1s_b, yb);
    BB(mha_b, 2304, (const float*)0, 0, (const float*)0, 0);
    gemm_mfma<0><<<dim3(cdiv(Ms, 128), 18), 256, 0, stream>>>(yb, W_mha, biasf, bufA, (float*)0, Ms, 2304, 768);
    attn_kernel<<<dim3(8, sN * 12), 256, 0, stream>>>(
        bufA, bufA + 768, bufA + 1536, bufB, /*Nk=*/8,
        /*qA=*/2304LL, /*qI=*/(long long)sN * 2304,
        /*kA=*/2304LL, /*kJ=*/(long long)sN * 2304,
        /*vA=*/2304LL, /*vJ=*/(long long)sN * 2304,
        /*oA=*/768LL,  /*oI=*/(long long)sN * 768);
    BB(mha_ob, 768, (const float*)0, 0, (const float*)0, 0);
    gemm_mfma<1><<<dim3(cdiv(Ms, 128), 6), 256, 0, stream>>>(bufB, W_mhao, biasf, (u16*)0, s_f, Ms, 768, 768);

    // ---- stage 2: video self-attention (single-shot QKV) --------------------
    ln_kernel<<<Mt, 256, 0, stream>>>(t_f, ln1t_g, ln1t_b, yb);
    BB(attn_q_b, 768, (const float*)0, 768, attn_v_b, 768);  // [q_b, 0, v_b]
    gemm_mfma<0><<<dim3(cdiv(Mt, 128), 18), 256, 0, stream>>>(yb, W_qkv, biasf, bufA, (float*)0, Mt, 2304, 768);
    attn_kernel<<<dim3(tN, B * 12), 256, 0, stream>>>(
        bufA, bufA + 768, bufA + 1536, bufB, /*Nk=*/tN,
        (long long)tN * 2304, 2304LL,
        (long long)tN * 2304, 2304LL,
        (long long)tN * 2304, 2304LL,
        (long long)tN * 768, 768LL);
    BB(attn_pb, 768, (const float*)0, 0, (const float*)0, 0);
    gemm_mfma<1><<<dim3(cdiv(Mt, 128), 6), 256, 0, stream>>>(bufB, W_attnp, biasf, (u16*)0, t_f, Mt, 768, 768);

    // ---- stage 3: T2S cross (q from LN(s_x), kv from updated t_x) -----------
    f2b_kernel<<<cdiv(n_tf, 256), 256, 0, stream>>>(t_f, yb, n_tf);   // bf16(t_x)
    BB((const float*)0, 768, t2s_kvb, 768, (const float*)0, 0);       // [0, kvb]
    gemm_mfma<0><<<dim3(cdiv(Mt, 128), 12), 256, 0, stream>>>(yb, W_t2skv, biasf, bufA, (float*)0, Mt, 1536, 768);
    ln_kernel<<<Ms, 256, 0, stream>>>(s_f, lnt2s_g, lnt2s_b, yb);
    BB(t2s_qb, 768, (const float*)0, 0, (const float*)0, 0);
    u16* q3 = bufB;
    u16* o3 = bufB + (size_t)Ms * 768;
    gemm_mfma<0><<<dim3(cdiv(Ms, 128), 6), 256, 0, stream>>>(yb, W_t2sq, biasf, q3, (float*)0, Ms, 768, 768);
    attn_kernel<<<dim3(sN, B * 12), 256, 0, stream>>>(
        q3, bufA, bufA + 768, o3, /*Nk=*/tN,
        (long long)sN * 768, 768LL,
        (long long)tN * 1536, 1536LL,
        (long long)tN * 1536, 1536LL,
        (long long)sN * 768, 768LL);
    BB(t2s_pb, 768, (const float*)0, 0, (const float*)0, 0);
    gemm_mfma<1><<<dim3(cdiv(Ms, 128), 6), 256, 0, stream>>>(o3, W_t2sp, biasf, (u16*)0, s_f, Ms, 768, 768);

    // ---- stage 4: S2T cross (q from LN(t_x), kv from updated s_x) -----------
    ln_kernel<<<Mt, 256, 0, stream>>>(t_f, lns2t_g, lns2t_b, yb);
    BB(s2t_qb, 768, (const float*)0, 0, (const float*)0, 0);
    gemm_mfma<0><<<dim3(cdiv(Mt, 128), 6), 256, 0, stream>>>(yb, W_s2tq, biasf, bufB, (float*)0, Mt, 768, 768);
    f2b_kernel<<<cdiv(n_sf, 256), 256, 0, stream>>>(s_f, yb, n_sf);   // bf16(s_x)
    BB((const float*)0, 768, s2t_kvb, 768, (const float*)0, 0);
    gemm_mfma<0><<<dim3(cdiv(Ms, 128), 12), 256, 0, stream>>>(yb, W_s2tkv, biasf, bufA, (float*)0, Ms, 1536, 768);
    attn_kernel<<<dim3(tN, B * 12), 256, 0, stream>>>(
        bufB, bufA, bufA + 768, yb, /*Nk=*/sN,
        (long long)tN * 768, 768LL,
        (long long)sN * 1536, 1536LL,
        (long long)sN * 1536, 1536LL,
        (long long)tN * 768, 768LL);
    BB(s2t_pb, 768, (const float*)0, 0, (const float*)0, 0);
    gemm_mfma<1><<<dim3(cdiv(Mt, 128), 6), 256, 0, stream>>>(yb, W_s2tp, biasf, (u16*)0, t_f, Mt, 768, 768);

    // ---- stage 5: clip MLP (QuickGELU) --------------------------------------
    ln_kernel<<<Ms, 256, 0, stream>>>(s_f, ln2s_g, ln2s_b, yb);
    BB(cfc_b, 3072, (const float*)0, 0, (const float*)0, 0);
    gemm_mfma<2><<<dim3(cdiv(Ms, 128), 24), 256, 0, stream>>>(yb, W_cfc, biasf, bufA, (float*)0, Ms, 3072, 768);
    BB(cproj_b, 768, (const float*)0, 0, (const float*)0, 0);
    gemm_mfma<1><<<dim3(cdiv(Ms, 128), 6), 256, 0, stream>>>(bufA, W_cproj, biasf, (u16*)0, s_f, Ms, 768, 3072);

    // ---- stage 6: video MLP (exact GELU), two row-halves --------------------
    ln_kernel<<<Mt, 256, 0, stream>>>(t_f, ln2t_g, ln2t_b, yb);
    for (int c = 0; c < 2; c++) {
        int r0 = c * (Mt / 2), Mc = Mt / 2;
        BB(fc1_b, 3072, (const float*)0, 0, (const float*)0, 0);
        gemm_mfma<3><<<dim3(cdiv(Mc, 128), 24), 256, 0, stream>>>(
            yb + (size_t)r0 * 768, W_fc1, biasf, bufA, (float*)0, Mc, 3072, 768);
        BB(fc2_b, 768, (const float*)0, 0, (const float*)0, 0);
        gemm_mfma<1><<<dim3(cdiv(Mc, 128), 6), 256, 0, stream>>>(
            bufA, W_fc2, biasf, (u16*)0, t_f + (size_t)r0 * 768, Mc, 768, 3072);
    }
    #undef BB
}

// Round 6
// 1593.469 us; speedup vs baseline: 13.9075x; 9.6873x over previous
//
#include <hip/hip_runtime.h>
#include <stdint.h>

// ---------------------------------------------------------------------------
// Block_6554120094246: dual-stream transformer block (CLIP + video streams).
// f32 in/out. Residual streams in d_out. bf16 intermediates + MFMA GEMM
// (16x16x32 bf16, 128x128 tile) + MFMA flash attention. ws ~134 MB.
// ---------------------------------------------------------------------------

typedef uint16_t u16;
typedef uint16_t u16x8 __attribute__((ext_vector_type(8)));
typedef short bf16x8 __attribute__((ext_vector_type(8)));
typedef float f32x4 __attribute__((ext_vector_type(4)));

__device__ __forceinline__ float b2f(u16 u) {
    union { float f; uint32_t i; } x;
    x.i = ((uint32_t)u) << 16;
    return x.f;
}
__device__ __forceinline__ u16 f2b(float f) {
    union { float f; uint32_t i; } x;
    x.f = f;
    uint32_t i = x.i;
    uint32_t r = (i + 0x7FFFu + ((i >> 16) & 1u)) >> 16;  // RNE
    return (u16)r;
}

__global__ void f2b_kernel(const float* __restrict__ in, u16* __restrict__ out, int n) {
    int i = blockIdx.x * 256 + threadIdx.x;
    if (i < n) out[i] = f2b(in[i]);
}
__global__ void copy_f32(const float* __restrict__ in, float* __restrict__ out, int n) {
    int i = blockIdx.x * 256 + threadIdx.x;
    if (i < n) out[i] = in[i];
}

// ---- bias builder: dst = concat(p0[0:n0], p1[0:n1], p2[0:n2]); null -> 0 ----
__global__ void build_bias(float* __restrict__ dst,
                           const float* p0, int n0, const float* p1, int n1,
                           const float* p2, int n2) {
    int i = blockIdx.x * 256 + threadIdx.x;
    int total = n0 + n1 + n2;
    if (i >= total) return;
    const float* p; int j;
    if (i < n0)           { p = p0; j = i; }
    else if (i < n0 + n1) { p = p1; j = i - n0; }
    else                  { p = p2; j = i - n0 - n1; }
    dst[i] = p ? p[j] : 0.f;
}

// ---- block reductions (blockDim.x == 256, 4 waves of 64) --------------------
__device__ __forceinline__ float block_sum(float v, float* red) {
    #pragma unroll
    for (int o = 32; o > 0; o >>= 1) v += __shfl_down(v, o, 64);
    int w = threadIdx.x >> 6, l = threadIdx.x & 63;
    __syncthreads();
    if (l == 0) red[w] = v;
    __syncthreads();
    return red[0] + red[1] + red[2] + red[3];
}

// ---- LayerNorm over C=768: f32 in, f32 params, bf16 out ---------------------
__global__ __launch_bounds__(256) void ln_kernel(
    const float* __restrict__ x, const float* __restrict__ g,
    const float* __restrict__ bta, u16* __restrict__ y) {
    const int r = blockIdx.x;
    const int t = threadIdx.x;
    const float* xr = x + (size_t)r * 768;
    float v0 = xr[t], v1 = xr[t + 256], v2 = xr[t + 512];
    __shared__ float red[4];
    float mean = block_sum(v0 + v1 + v2, red) * (1.0f / 768.0f);
    float d0 = v0 - mean, d1 = v1 - mean, d2 = v2 - mean;
    float var = block_sum(d0 * d0 + d1 * d1 + d2 * d2, red) * (1.0f / 768.0f);
    float rs = rsqrtf(var + 1e-5f);
    u16* yr = y + (size_t)r * 768;
    yr[t]       = f2b(d0 * rs * g[t]       + bta[t]);
    yr[t + 256] = f2b(d1 * rs * g[t + 256] + bta[t + 256]);
    yr[t + 512] = f2b(d2 * rs * g[t + 512] + bta[t + 512]);
}

// ---- MFMA GEMM: C[M,N] = A[M,K](bf16) @ W[N,K](bf16)^T + bias[N] ------------
template <int MODE>
__global__ __launch_bounds__(256) void gemm_mfma(
    const u16* __restrict__ A, const u16* __restrict__ W,
    const float* __restrict__ bias, u16* __restrict__ Cb,
    float* __restrict__ Cf, int M, int N, int K) {
    __shared__ u16 As[128][40];
    __shared__ u16 Bs[128][40];
    const int tid = threadIdx.x;
    const int lane = tid & 63;
    const int wid = tid >> 6;
    const int wr = (wid >> 1) * 64, wc = (wid & 1) * 64;
    const int m0 = blockIdx.x * 128, n0 = blockIdx.y * 128;
    const int srow = tid >> 1, soff = (tid & 1) * 16;
    const int fr = lane & 15, fk = (lane >> 4) * 8;
    f32x4 acc[4][4] = {};
    for (int k0 = 0; k0 < K; k0 += 32) {
        if (m0 + srow < M) {
            const u16* src = A + (size_t)(m0 + srow) * K + k0 + soff;
            *(u16x8*)&As[srow][soff]     = *(const u16x8*)src;
            *(u16x8*)&As[srow][soff + 8] = *(const u16x8*)(src + 8);
        } else {
            u16x8 z = {};
            *(u16x8*)&As[srow][soff] = z;
            *(u16x8*)&As[srow][soff + 8] = z;
        }
        const u16* wsrc = W + (size_t)(n0 + srow) * K + k0 + soff;
        *(u16x8*)&Bs[srow][soff]     = *(const u16x8*)wsrc;
        *(u16x8*)&Bs[srow][soff + 8] = *(const u16x8*)(wsrc + 8);
        __syncthreads();
        bf16x8 a[4], b[4];
        #pragma unroll
        for (int i = 0; i < 4; i++) a[i] = *(const bf16x8*)&As[wr + i * 16 + fr][fk];
        #pragma unroll
        for (int j = 0; j < 4; j++) b[j] = *(const bf16x8*)&Bs[wc + j * 16 + fr][fk];
        #pragma unroll
        for (int i = 0; i < 4; i++)
            #pragma unroll
            for (int j = 0; j < 4; j++)
                acc[i][j] = __builtin_amdgcn_mfma_f32_16x16x32_bf16(a[i], b[j], acc[i][j], 0, 0, 0);
        __syncthreads();
    }
    const int er = (lane >> 4) * 4;
    #pragma unroll
    for (int i = 0; i < 4; i++) {
        #pragma unroll
        for (int reg = 0; reg < 4; reg++) {
            int r = m0 + wr + i * 16 + er + reg;
            if (r >= M) continue;
            #pragma unroll
            for (int j = 0; j < 4; j++) {
                int c = n0 + wc + j * 16 + fr;
                float v = acc[i][j][reg] + bias[c];
                if (MODE == 1) {
                    Cf[(size_t)r * N + c] += v;
                } else {
                    if (MODE == 2) v = v / (1.0f + expf(-1.702f * v));
                    if (MODE == 3) v = 0.5f * v * (1.0f + erff(v * 0.70710678118654752f));
                    Cb[(size_t)r * N + c] = f2b(v);
                }
            }
        }
    }
}

// ---- MFMA flash attention (HD=64, scale=0.125) ------------------------------
// grid = (ceil(Nq/64), A*12). Block = 4 waves; wave w owns Q rows
// q0 = bx*64 + w*16 + [0,16). KV tiles of 32 staged in LDS (V transposed).
// Layouts (m89/m91-verified, reused from gemm_mfma): A-frag row=lane&15,
// k=(lane>>4)*8+j; B-frag col=lane&15; C/D col=lane&15, row=(lane>>4)*4+reg.
__global__ __launch_bounds__(256) void flash_attn(
    const u16* __restrict__ qp, const u16* __restrict__ kp,
    const u16* __restrict__ vp, u16* __restrict__ op, int Nq, int Nk,
    long long qA, long long qI, long long kA, long long kJ,
    long long vA, long long vJ, long long oA, long long oI) {
    const int a = blockIdx.y / 12, h = blockIdx.y % 12;
    const int tid = threadIdx.x, lane = tid & 63, w = tid >> 6;
    const int fr = lane & 15, g = lane >> 4, fk = g * 8;
    __shared__ u16 Ks[32][66];      // row stride 33 dwords (odd)
    __shared__ u16 Vt[64][34];      // V transposed; stride 17 dwords
    __shared__ u16 Ps[4][16][34];   // per-wave P tile
    const u16* qb = qp + a * qA + h * 64;
    const u16* kb = kp + a * kA + h * 64;
    const u16* vb = vp + a * vA + h * 64;
    const int q0 = blockIdx.x * 64 + w * 16;

    bf16x8 qf[2];
    {
        int qr = q0 + fr;
        if (qr < Nq) {
            const u16* qrp = qb + (long long)qr * qI;
            qf[0] = *(const bf16x8*)(qrp + fk);
            qf[1] = *(const bf16x8*)(qrp + 32 + fk);
        } else {
            bf16x8 z = {};
            qf[0] = z; qf[1] = z;
        }
    }
    float m[4] = {-INFINITY, -INFINITY, -INFINITY, -INFINITY};
    float lsum[4] = {};
    f32x4 o[4] = {};

    for (int t0 = 0; t0 < Nk; t0 += 32) {
        // stage K (linear) and V (transposed): thread -> kv=tid>>3, d=(tid&7)*8
        {
            int kv = tid >> 3, db = (tid & 7) * 8;
            u16x8 z = {};
            u16x8 kval = z, vval = z;
            if (t0 + kv < Nk) {
                kval = *(const u16x8*)(kb + (long long)(t0 + kv) * kJ + db);
                vval = *(const u16x8*)(vb + (long long)(t0 + kv) * vJ + db);
            }
            *(u16x8*)&Ks[kv][db] = kval;
            #pragma unroll
            for (int e = 0; e < 8; e++) Vt[db + e][kv] = vval[e];
        }
        __syncthreads();

        // S[16q][32kv] = Q K^T (2 halves x 2 d-chunks)
        f32x4 s[2] = {};
        #pragma unroll
        for (int hh = 0; hh < 2; hh++) {
            bf16x8 k0 = *(const bf16x8*)&Ks[hh * 16 + fr][fk];
            bf16x8 k1 = *(const bf16x8*)&Ks[hh * 16 + fr][32 + fk];
            s[hh] = __builtin_amdgcn_mfma_f32_16x16x32_bf16(qf[0], k0, s[hh], 0, 0, 0);
            s[hh] = __builtin_amdgcn_mfma_f32_16x16x32_bf16(qf[1], k1, s[hh], 0, 0, 0);
        }
        // scale + mask (kv index of s[hh][*] is t0 + hh*16 + fr)
        #pragma unroll
        for (int hh = 0; hh < 2; hh++) {
            bool valid = (t0 + hh * 16 + fr) < Nk;
            #pragma unroll
            for (int r = 0; r < 4; r++)
                s[hh][r] = valid ? s[hh][r] * 0.125f : -1e30f;
        }
        // online softmax per q-row (row = g*4 + r; kv spread over fr lanes)
        float pout[2][4];
        #pragma unroll
        for (int r = 0; r < 4; r++) {
            float mx = fmaxf(s[0][r], s[1][r]);
            #pragma unroll
            for (int d = 1; d <= 8; d <<= 1) mx = fmaxf(mx, __shfl_xor(mx, d, 64));
            float mn = fmaxf(m[r], mx);
            float p0 = __expf(s[0][r] - mn);
            float p1 = __expf(s[1][r] - mn);
            float ps = p0 + p1;
            #pragma unroll
            for (int d = 1; d <= 8; d <<= 1) ps += __shfl_xor(ps, d, 64);
            float sf = __expf(m[r] - mn);
            m[r] = mn;
            lsum[r] = lsum[r] * sf + ps;
            #pragma unroll
            for (int dt = 0; dt < 4; dt++) o[dt][r] *= sf;
            pout[0][r] = p0; pout[1][r] = p1;
        }
        // P -> per-wave LDS (transpose to A-frag layout), then PV
        #pragma unroll
        for (int hh = 0; hh < 2; hh++)
            #pragma unroll
            for (int r = 0; r < 4; r++)
                Ps[w][g * 4 + r][hh * 16 + fr] = f2b(pout[hh][r]);
        bf16x8 pa = *(const bf16x8*)&Ps[w][fr][fk];
        #pragma unroll
        for (int dt = 0; dt < 4; dt++) {
            bf16x8 vf = *(const bf16x8*)&Vt[dt * 16 + fr][fk];
            o[dt] = __builtin_amdgcn_mfma_f32_16x16x32_bf16(pa, vf, o[dt], 0, 0, 0);
        }
        __syncthreads();
    }
    // epilogue: O[q][d] = o/l ; q = q0 + g*4 + r, d = dt*16 + fr
    #pragma unroll
    for (int r = 0; r < 4; r++) {
        int q = q0 + g * 4 + r;
        if (q >= Nq) continue;
        float rcp = 1.0f / lsum[r];
        u16* orow = op + a * oA + (long long)q * oI + h * 64;
        #pragma unroll
        for (int dt = 0; dt < 4; dt++)
            orow[dt * 16 + fr] = f2b(o[dt][r] * rcp);
    }
}

// ---------------------------------------------------------------------------
extern "C" void kernel_launch(void* const* d_in, const int* in_sizes, int n_in,
                              void* d_out, int out_size, void* d_ws, size_t ws_size,
                              hipStream_t stream) {
    const int B = 8, sN = 196, tN = 1568;
    const int Ms = B * sN;            // 1568
    const int Mt = B * tN;            // 12544
    const int n_sf = Ms * 768;        // 1204224
    const int n_tf = Mt * 768;        // 9633792
    (void)n_in; (void)out_size; (void)ws_size;

    const bool dict_order = (in_sizes[0] == n_sf);
    auto IN = [&](int di, int ai) -> const float* {
        return (const float*)d_in[dict_order ? di : ai];
    };
    const float* in_sx      = IN(0, 35);
    const float* in_tx      = IN(1, 42);
    const float* ln1s_g     = IN(2, 14);
    const float* ln1s_b     = IN(3, 13);
    const float* mha_w      = IN(4, 28);
    const float* mha_b      = IN(5, 25);
    const float* mha_ow     = IN(6, 27);
    const float* mha_ob     = IN(7, 26);
    const float* ln1t_g     = IN(8, 16);
    const float* ln1t_b     = IN(9, 15);
    const float* attn_qkv_w = IN(10, 3);
    const float* attn_q_b   = IN(11, 2);
    const float* attn_v_b   = IN(12, 4);
    const float* attn_pw    = IN(13, 1);
    const float* attn_pb    = IN(14, 0);
    const float* lnt2s_g    = IN(15, 24);
    const float* lnt2s_b    = IN(16, 23);
    const float* t2s_qw     = IN(17, 41);
    const float* t2s_qb     = IN(18, 40);
    const float* t2s_kvw    = IN(19, 37);
    const float* t2s_kvb    = IN(20, 36);
    const float* t2s_pw     = IN(21, 39);
    const float* t2s_pb     = IN(22, 38);
    const float* lns2t_g    = IN(23, 22);
    const float* lns2t_b    = IN(24, 21);
    const float* s2t_qw     = IN(25, 34);
    const float* s2t_qb     = IN(26, 33);
    const float* s2t_kvw    = IN(27, 30);
    const float* s2t_kvb    = IN(28, 29);
    const float* s2t_pw     = IN(29, 32);
    const float* s2t_pb     = IN(30, 31);
    const float* ln2s_g     = IN(31, 18);
    const float* ln2s_b     = IN(32, 17);
    const float* cfc_w      = IN(33, 6);
    const float* cfc_b      = IN(34, 5);
    const float* cproj_w    = IN(35, 8);
    const float* cproj_b    = IN(36, 7);
    const float* ln2t_g     = IN(37, 20);
    const float* ln2t_b     = IN(38, 19);
    const float* fc1_w      = IN(39, 10);
    const float* fc1_b      = IN(40, 9);
    const float* fc2_w      = IN(41, 12);
    const float* fc2_b      = IN(42, 11);

    // ---- residual streams live in d_out (f32) -------------------------------
    float* s_f = (float*)d_out;
    float* t_f = (float*)d_out + n_sf;

    // ---- workspace (~134 MB) ------------------------------------------------
    char* ws = (char*)d_ws;
    size_t off = 0;
    auto take = [&](size_t bytes) { size_t o = off; off += (bytes + 255) & ~(size_t)255; return o; };
    float* biasf = (float*)(ws + take(3072 * 4));
    u16*   yb    = (u16*)(ws + take((size_t)Mt * 768 * 2));   // 19.3 MB
    u16*   bufA  = (u16*)(ws + take((size_t)Mt * 2304 * 2));  // 57.8 MB
    u16*   bufB  = (u16*)(ws + take((size_t)Mt * 768 * 2));   // 19.3 MB
    auto wtake = [&](size_t nelem) { return (u16*)(ws + take(nelem * 2)); };
    u16 *W_mha   = wtake(2304 * 768), *W_mhao  = wtake(768 * 768);
    u16 *W_qkv   = wtake(2304 * 768), *W_attnp = wtake(768 * 768);
    u16 *W_t2sq  = wtake(768 * 768),  *W_t2skv = wtake(1536 * 768), *W_t2sp = wtake(768 * 768);
    u16 *W_s2tq  = wtake(768 * 768),  *W_s2tkv = wtake(1536 * 768), *W_s2tp = wtake(768 * 768);
    u16 *W_cfc   = wtake(3072 * 768), *W_cproj = wtake(768 * 3072);
    u16 *W_fc1   = wtake(3072 * 768), *W_fc2   = wtake(768 * 3072);

    auto cdiv = [](int a, int b) { return (a + b - 1) / b; };
    #define BB(b0, c0, b1, c1, b2, c2) \
        build_bias<<<cdiv((c0) + (c1) + (c2), 256), 256, 0, stream>>>(biasf, b0, c0, b1, c1, b2, c2)
    auto CW = [&](const float* src, u16* dst, int n) {
        f2b_kernel<<<cdiv(n, 256), 256, 0, stream>>>(src, dst, n);
    };
    // weights -> bf16 pool
    CW(mha_w, W_mha, 2304 * 768);      CW(mha_ow, W_mhao, 768 * 768);
    CW(attn_qkv_w, W_qkv, 2304 * 768); CW(attn_pw, W_attnp, 768 * 768);
    CW(t2s_qw, W_t2sq, 768 * 768);     CW(t2s_kvw, W_t2skv, 1536 * 768);
    CW(t2s_pw, W_t2sp, 768 * 768);     CW(s2t_qw, W_s2tq, 768 * 768);
    CW(s2t_kvw, W_s2tkv, 1536 * 768);  CW(s2t_pw, W_s2tp, 768 * 768);
    CW(cfc_w, W_cfc, 3072 * 768);      CW(cproj_w, W_cproj, 768 * 3072);
    CW(fc1_w, W_fc1, 3072 * 768);      CW(fc2_w, W_fc2, 768 * 3072);

    // residual streams <- inputs
    copy_f32<<<cdiv(n_sf, 256), 256, 0, stream>>>(in_sx, s_f, n_sf);
    copy_f32<<<cdiv(n_tf, 256), 256, 0, stream>>>(in_tx, t_f, n_tf);

    // ---- stage 1: clip self-attention (attends over the batch axis) ---------
    ln_kernel<<<Ms, 256, 0, stream>>>(s_f, ln1s_g, ln1s_b, yb);
    BB(mha_b, 2304, (const float*)0, 0, (const float*)0, 0);
    gemm_mfma<0><<<dim3(cdiv(Ms, 128), 18), 256, 0, stream>>>(yb, W_mha, biasf, bufA, (float*)0, Ms, 2304, 768);
    flash_attn<<<dim3(1, sN * 12), 256, 0, stream>>>(
        bufA, bufA + 768, bufA + 1536, bufB, /*Nq=*/8, /*Nk=*/8,
        /*qA=*/2304LL, /*qI=*/(long long)sN * 2304,
        /*kA=*/2304LL, /*kJ=*/(long long)sN * 2304,
        /*vA=*/2304LL, /*vJ=*/(long long)sN * 2304,
        /*oA=*/768LL,  /*oI=*/(long long)sN * 768);
    BB(mha_ob, 768, (const float*)0, 0, (const float*)0, 0);
    gemm_mfma<1><<<dim3(cdiv(Ms, 128), 6), 256, 0, stream>>>(bufB, W_mhao, biasf, (u16*)0, s_f, Ms, 768, 768);

    // ---- stage 2: video self-attention --------------------------------------
    ln_kernel<<<Mt, 256, 0, stream>>>(t_f, ln1t_g, ln1t_b, yb);
    BB(attn_q_b, 768, (const float*)0, 768, attn_v_b, 768);  // [q_b, 0, v_b]
    gemm_mfma<0><<<dim3(cdiv(Mt, 128), 18), 256, 0, stream>>>(yb, W_qkv, biasf, bufA, (float*)0, Mt, 2304, 768);
    flash_attn<<<dim3(cdiv(tN, 64), B * 12), 256, 0, stream>>>(
        bufA, bufA + 768, bufA + 1536, bufB, /*Nq=*/tN, /*Nk=*/tN,
        (long long)tN * 2304, 2304LL,
        (long long)tN * 2304, 2304LL,
        (long long)tN * 2304, 2304LL,
        (long long)tN * 768, 768LL);
    BB(attn_pb, 768, (const float*)0, 0, (const float*)0, 0);
    gemm_mfma<1><<<dim3(cdiv(Mt, 128), 6), 256, 0, stream>>>(bufB, W_attnp, biasf, (u16*)0, t_f, Mt, 768, 768);

    // ---- stage 3: T2S cross (q from LN(s_x), kv from updated t_x) -----------
    f2b_kernel<<<cdiv(n_tf, 256), 256, 0, stream>>>(t_f, yb, n_tf);   // bf16(t_x)
    BB((const float*)0, 768, t2s_kvb, 768, (const float*)0, 0);       // [0, kvb]
    gemm_mfma<0><<<dim3(cdiv(Mt, 128), 12), 256, 0, stream>>>(yb, W_t2skv, biasf, bufA, (float*)0, Mt, 1536, 768);
    ln_kernel<<<Ms, 256, 0, stream>>>(s_f, lnt2s_g, lnt2s_b, yb);
    BB(t2s_qb, 768, (const float*)0, 0, (const float*)0, 0);
    u16* q3 = bufB;
    u16* o3 = bufB + (size_t)Ms * 768;
    gemm_mfma<0><<<dim3(cdiv(Ms, 128), 6), 256, 0, stream>>>(yb, W_t2sq, biasf, q3, (float*)0, Ms, 768, 768);
    flash_attn<<<dim3(cdiv(sN, 64), B * 12), 256, 0, stream>>>(
        q3, bufA, bufA + 768, o3, /*Nq=*/sN, /*Nk=*/tN,
        (long long)sN * 768, 768LL,
        (long long)tN * 1536, 1536LL,
        (long long)tN * 1536, 1536LL,
        (long long)sN * 768, 768LL);
    BB(t2s_pb, 768, (const float*)0, 0, (const float*)0, 0);
    gemm_mfma<1><<<dim3(cdiv(Ms, 128), 6), 256, 0, stream>>>(o3, W_t2sp, biasf, (u16*)0, s_f, Ms, 768, 768);

    // ---- stage 4: S2T cross (q from LN(t_x), kv from updated s_x) -----------
    ln_kernel<<<Mt, 256, 0, stream>>>(t_f, lns2t_g, lns2t_b, yb);
    BB(s2t_qb, 768, (const float*)0, 0, (const float*)0, 0);
    gemm_mfma<0><<<dim3(cdiv(Mt, 128), 6), 256, 0, stream>>>(yb, W_s2tq, biasf, bufB, (float*)0, Mt, 768, 768);
    f2b_kernel<<<cdiv(n_sf, 256), 256, 0, stream>>>(s_f, yb, n_sf);   // bf16(s_x)
    BB((const float*)0, 768, s2t_kvb, 768, (const float*)0, 0);
    gemm_mfma<0><<<dim3(cdiv(Ms, 128), 12), 256, 0, stream>>>(yb, W_s2tkv, biasf, bufA, (float*)0, Ms, 1536, 768);
    flash_attn<<<dim3(cdiv(tN, 64), B * 12), 256, 0, stream>>>(
        bufB, bufA, bufA + 768, yb, /*Nq=*/tN, /*Nk=*/sN,
        (long long)tN * 768, 768LL,
        (long long)sN * 1536, 1536LL,
        (long long)sN * 1536, 1536LL,
        (long long)tN * 768, 768LL);
    BB(s2t_pb, 768, (const float*)0, 0, (const float*)0, 0);
    gemm_mfma<1><<<dim3(cdiv(Mt, 128), 6), 256, 0, stream>>>(yb, W_s2tp, biasf, (u16*)0, t_f, Mt, 768, 768);

    // ---- stage 5: clip MLP (QuickGELU) --------------------------------------
    ln_kernel<<<Ms, 256, 0, stream>>>(s_f, ln2s_g, ln2s_b, yb);
    BB(cfc_b, 3072, (const float*)0, 0, (const float*)0, 0);
    gemm_mfma<2><<<dim3(cdiv(Ms, 128), 24), 256, 0, stream>>>(yb, W_cfc, biasf, bufA, (float*)0, Ms, 3072, 768);
    BB(cproj_b, 768, (const float*)0, 0, (const float*)0, 0);
    gemm_mfma<1><<<dim3(cdiv(Ms, 128), 6), 256, 0, stream>>>(bufA, W_cproj, biasf, (u16*)0, s_f, Ms, 768, 3072);

    // ---- stage 6: video MLP (exact GELU), two row-halves --------------------
    ln_kernel<<<Mt, 256, 0, stream>>>(t_f, ln2t_g, ln2t_b, yb);
    for (int c = 0; c < 2; c++) {
        int r0 = c * (Mt / 2), Mc = Mt / 2;
        BB(fc1_b, 3072, (const float*)0, 0, (const float*)0, 0);
        gemm_mfma<3><<<dim3(cdiv(Mc, 128), 24), 256, 0, stream>>>(
            yb + (size_t)r0 * 768, W_fc1, biasf, bufA, (float*)0, Mc, 3072, 768);
        BB(fc2_b, 768, (const float*)0, 0, (const float*)0, 0);
        gemm_mfma<1><<<dim3(cdiv(Mc, 128), 6), 256, 0, stream>>>(
            bufA, W_fc2, biasf, (u16*)0, t_f + (size_t)r0 * 768, Mc, 768, 3072);
    }
    #undef BB
}

// Round 7
// 1446.847 us; speedup vs baseline: 15.3169x; 1.1013x over previous
//
#include <hip/hip_runtime.h>
#include <stdint.h>

// ---------------------------------------------------------------------------
// Block_6554120094246: dual-stream transformer block (CLIP + video streams).
// f32 in/out. Residual streams in d_out. bf16 intermediates + MFMA GEMM
// (16x16x32 bf16, 128x128 tile, global_load_lds staging) + MFMA flash
// attention (KVBLK=64, pair-packed V transpose, pre-scaled Q). ws ~134 MB.
// ---------------------------------------------------------------------------

typedef uint16_t u16;
typedef uint16_t u16x8 __attribute__((ext_vector_type(8)));
typedef short bf16x8 __attribute__((ext_vector_type(8)));
typedef float f32x4 __attribute__((ext_vector_type(4)));
typedef int i32x4 __attribute__((ext_vector_type(4)));

__device__ __forceinline__ float b2f(u16 u) {
    union { float f; uint32_t i; } x;
    x.i = ((uint32_t)u) << 16;
    return x.f;
}
__device__ __forceinline__ u16 f2b(float f) {
    union { float f; uint32_t i; } x;
    x.f = f;
    uint32_t i = x.i;
    uint32_t r = (i + 0x7FFFu + ((i >> 16) & 1u)) >> 16;  // RNE
    return (u16)r;
}

// async global->LDS, 16B per lane; LDS dest must be wave-uniform base.
__device__ __forceinline__ void gload16(const u16* g, u16* l) {
    __builtin_amdgcn_global_load_lds(
        (const __attribute__((address_space(1))) uint32_t*)g,
        (__attribute__((address_space(3))) uint32_t*)l, 16, 0, 0);
}

__global__ void f2b_kernel(const float* __restrict__ in, u16* __restrict__ out, int n) {
    int i = blockIdx.x * 256 + threadIdx.x;
    if (i < n) out[i] = f2b(in[i]);
}
__global__ void copy_f32(const float* __restrict__ in, float* __restrict__ out, int n) {
    int i = blockIdx.x * 256 + threadIdx.x;
    if (i < n) out[i] = in[i];
}

// ---- bias builder: dst = concat(p0[0:n0], p1[0:n1], p2[0:n2]); null -> 0 ----
__global__ void build_bias(float* __restrict__ dst,
                           const float* p0, int n0, const float* p1, int n1,
                           const float* p2, int n2) {
    int i = blockIdx.x * 256 + threadIdx.x;
    int total = n0 + n1 + n2;
    if (i >= total) return;
    const float* p; int j;
    if (i < n0)           { p = p0; j = i; }
    else if (i < n0 + n1) { p = p1; j = i - n0; }
    else                  { p = p2; j = i - n0 - n1; }
    dst[i] = p ? p[j] : 0.f;
}

// ---- block reductions (blockDim.x == 256, 4 waves of 64) --------------------
__device__ __forceinline__ float block_sum(float v, float* red) {
    #pragma unroll
    for (int o = 32; o > 0; o >>= 1) v += __shfl_down(v, o, 64);
    int w = threadIdx.x >> 6, l = threadIdx.x & 63;
    __syncthreads();
    if (l == 0) red[w] = v;
    __syncthreads();
    return red[0] + red[1] + red[2] + red[3];
}

// ---- LayerNorm over C=768: f32 in, f32 params, bf16 out ---------------------
__global__ __launch_bounds__(256) void ln_kernel(
    const float* __restrict__ x, const float* __restrict__ g,
    const float* __restrict__ bta, u16* __restrict__ y) {
    const int r = blockIdx.x;
    const int t = threadIdx.x;
    const float* xr = x + (size_t)r * 768;
    float v0 = xr[t], v1 = xr[t + 256], v2 = xr[t + 512];
    __shared__ float red[4];
    float mean = block_sum(v0 + v1 + v2, red) * (1.0f / 768.0f);
    float d0 = v0 - mean, d1 = v1 - mean, d2 = v2 - mean;
    float var = block_sum(d0 * d0 + d1 * d1 + d2 * d2, red) * (1.0f / 768.0f);
    float rs = rsqrtf(var + 1e-5f);
    u16* yr = y + (size_t)r * 768;
    yr[t]       = f2b(d0 * rs * g[t]       + bta[t]);
    yr[t + 256] = f2b(d1 * rs * g[t + 256] + bta[t + 256]);
    yr[t + 512] = f2b(d2 * rs * g[t + 512] + bta[t + 512]);
}

// ---- MFMA GEMM: C[M,N] = A[M,K](bf16) @ W[N,K](bf16)^T + bias[N] ------------
// 128x128x32 tile, 4 waves (each 64x64). Staging via global_load_lds width=16
// into LINEAR [128][32] LDS (m97 pattern; dest wave-uniform + lane*16).
template <int MODE>
__global__ __launch_bounds__(256) void gemm_mfma(
    const u16* __restrict__ A, const u16* __restrict__ W,
    const float* __restrict__ bias, u16* __restrict__ Cb,
    float* __restrict__ Cf, int M, int N, int K) {
    __shared__ u16 As[128][32];
    __shared__ u16 Bs[128][32];
    const int tid = threadIdx.x;
    const int lane = tid & 63;
    const int wid = tid >> 6;
    const int wr = (wid >> 1) * 64, wc = (wid & 1) * 64;
    const int m0 = blockIdx.x * 128, n0 = blockIdx.y * 128;
    const int lr = lane >> 2, lc = (lane & 3) * 8;   // staging row/col within 16-row slab
    const int fr = lane & 15, fk = (lane >> 4) * 8;
    const int base_row = wid * 32;
    f32x4 acc[4][4] = {};
    for (int k0 = 0; k0 < K; k0 += 32) {
        #pragma unroll
        for (int j = 0; j < 2; j++) {
            int rowa = m0 + base_row + j * 16 + lr;
            rowa = rowa < M ? rowa : M - 1;        // clamp (values unused)
            gload16(A + (size_t)rowa * K + k0 + lc, &As[base_row + j * 16][0]);
            gload16(W + (size_t)(n0 + base_row + j * 16 + lr) * K + k0 + lc,
                    &Bs[base_row + j * 16][0]);
        }
        __syncthreads();
        bf16x8 a[4], b[4];
        #pragma unroll
        for (int i = 0; i < 4; i++) a[i] = *(const bf16x8*)&As[wr + i * 16 + fr][fk];
        #pragma unroll
        for (int j = 0; j < 4; j++) b[j] = *(const bf16x8*)&Bs[wc + j * 16 + fr][fk];
        #pragma unroll
        for (int i = 0; i < 4; i++)
            #pragma unroll
            for (int j = 0; j < 4; j++)
                acc[i][j] = __builtin_amdgcn_mfma_f32_16x16x32_bf16(a[i], b[j], acc[i][j], 0, 0, 0);
        __syncthreads();
    }
    const int er = (lane >> 4) * 4;
    #pragma unroll
    for (int i = 0; i < 4; i++) {
        #pragma unroll
        for (int reg = 0; reg < 4; reg++) {
            int r = m0 + wr + i * 16 + er + reg;
            if (r >= M) continue;
            #pragma unroll
            for (int j = 0; j < 4; j++) {
                int c = n0 + wc + j * 16 + fr;
                float v = acc[i][j][reg] + bias[c];
                if (MODE == 1) {
                    Cf[(size_t)r * N + c] += v;
                } else {
                    if (MODE == 2) v = v / (1.0f + expf(-1.702f * v));
                    if (MODE == 3) v = 0.5f * v * (1.0f + erff(v * 0.70710678118654752f));
                    Cb[(size_t)r * N + c] = f2b(v);
                }
            }
        }
    }
}

// ---- MFMA flash attention v2 (HD=64, scale pre-folded into Q) ---------------
// grid = (ceil(Nq/64), A*12). 4 waves; wave w owns Q rows q0=bx*64+w*16+[0,16).
// KV tiles of 64. V transposed into LDS via kv-pair packing (shfl_xor(4) +
// u32 stores). Fragment layouts as in gemm_mfma (m89/m91-verified).
__global__ __launch_bounds__(256) void flash_attn(
    const u16* __restrict__ qp, const u16* __restrict__ kp,
    const u16* __restrict__ vp, u16* __restrict__ op, int Nq, int Nk,
    long long qA, long long qI, long long kA, long long kJ,
    long long vA, long long vJ, long long oA, long long oI) {
    const int a = blockIdx.y / 12, h = blockIdx.y % 12;
    const int tid = threadIdx.x, lane = tid & 63, w = tid >> 6;
    const int fr = lane & 15, g = lane >> 4, fk = g * 8;
    __shared__ u16 Ks[64][66];      // K tile [kv][d]
    __shared__ u16 Vt[64][66];      // V^T tile [d][kv]
    __shared__ u16 Ps[4][16][66];   // per-wave P tile [q][kv]
    const u16* qb = qp + a * qA + h * 64;
    const u16* kb = kp + a * kA + h * 64;
    const u16* vb = vp + a * vA + h * 64;
    const int q0 = blockIdx.x * 64 + w * 16;

    // Q fragments, pre-scaled by 0.125 (exact exponent shift in bf16)
    bf16x8 qf[2];
    {
        u16x8 raw0 = {}, raw1 = {};
        int qr = q0 + fr;
        if (qr < Nq) {
            const u16* qrp = qb + (long long)qr * qI;
            raw0 = *(const u16x8*)(qrp + fk);
            raw1 = *(const u16x8*)(qrp + 32 + fk);
        }
        u16x8 s0, s1;
        #pragma unroll
        for (int e = 0; e < 8; e++) {
            s0[e] = f2b(b2f(raw0[e]) * 0.125f);
            s1[e] = f2b(b2f(raw1[e]) * 0.125f);
        }
        qf[0] = *(bf16x8*)&s0;
        qf[1] = *(bf16x8*)&s1;
    }
    float m[4] = {-INFINITY, -INFINITY, -INFINITY, -INFINITY};
    float lsum[4] = {};
    f32x4 o[4] = {};

    const int kv = tid >> 2, dbs = (tid & 3) * 16;
    const int kvb = kv & ~1, epair = (kv & 1) * 4;

    for (int t0 = 0; t0 < Nk; t0 += 64) {
        // ---- stage K linear + V transposed (kv-pair packed u32 stores) ------
        {
            u16x8 kv0 = {}, kv1 = {}, vv0 = {}, vv1 = {};
            if (t0 + kv < Nk) {
                const u16* kr = kb + (long long)(t0 + kv) * kJ + dbs;
                const u16* vr = vb + (long long)(t0 + kv) * vJ + dbs;
                kv0 = *(const u16x8*)kr;  kv1 = *(const u16x8*)(kr + 8);
                vv0 = *(const u16x8*)vr;  vv1 = *(const u16x8*)(vr + 8);
            }
            *(u16x8*)&Ks[kv][dbs]     = kv0;
            *(u16x8*)&Ks[kv][dbs + 8] = kv1;
            #pragma unroll
            for (int hh2 = 0; hh2 < 2; hh2++) {
                u16x8 mine = hh2 ? vv1 : vv0;
                i32x4 m32 = *(i32x4*)&mine;
                i32x4 o32;
                #pragma unroll
                for (int d2 = 0; d2 < 4; d2++) o32[d2] = __shfl_xor(m32[d2], 4, 64);
                u16x8 other = *(u16x8*)&o32;
                // lo = even-kv row, hi = odd-kv row
                #pragma unroll
                for (int e2 = 0; e2 < 4; e2++) {
                    int e = epair + e2;
                    uint32_t lo = (kv & 1) ? other[e] : mine[e];
                    uint32_t hi = (kv & 1) ? mine[e] : other[e];
                    *(uint32_t*)&Vt[dbs + hh2 * 8 + e][kvb] = lo | (hi << 16);
                }
            }
        }
        __syncthreads();

        // ---- S[16q][64kv] = Qs K^T ------------------------------------------
        f32x4 s[4] = {};
        #pragma unroll
        for (int hh = 0; hh < 4; hh++) {
            bf16x8 k0f = *(const bf16x8*)&Ks[hh * 16 + fr][fk];
            bf16x8 k1f = *(const bf16x8*)&Ks[hh * 16 + fr][32 + fk];
            s[hh] = __builtin_amdgcn_mfma_f32_16x16x32_bf16(qf[0], k0f, s[hh], 0, 0, 0);
            s[hh] = __builtin_amdgcn_mfma_f32_16x16x32_bf16(qf[1], k1f, s[hh], 0, 0, 0);
        }
        // mask invalid kv
        #pragma unroll
        for (int hh = 0; hh < 4; hh++) {
            bool valid = (t0 + hh * 16 + fr) < Nk;
            #pragma unroll
            for (int r = 0; r < 4; r++)
                s[hh][r] = valid ? s[hh][r] : -1e30f;
        }
        // ---- online softmax per q-row (row = g*4+r, kv over fr lanes) -------
        #pragma unroll
        for (int r = 0; r < 4; r++) {
            float mx = fmaxf(fmaxf(s[0][r], s[1][r]), fmaxf(s[2][r], s[3][r]));
            #pragma unroll
            for (int d = 1; d <= 8; d <<= 1) mx = fmaxf(mx, __shfl_xor(mx, d, 64));
            float mn = fmaxf(m[r], mx);
            float p0 = __expf(s[0][r] - mn);
            float p1 = __expf(s[1][r] - mn);
            float p2 = __expf(s[2][r] - mn);
            float p3 = __expf(s[3][r] - mn);
            float ps = (p0 + p1) + (p2 + p3);
            #pragma unroll
            for (int d = 1; d <= 8; d <<= 1) ps += __shfl_xor(ps, d, 64);
            float sf = __expf(m[r] - mn);
            m[r] = mn;
            lsum[r] = lsum[r] * sf + ps;
            #pragma unroll
            for (int dt = 0; dt < 4; dt++) o[dt][r] *= sf;
            Ps[w][g * 4 + r][fr]      = f2b(p0);
            Ps[w][g * 4 + r][16 + fr] = f2b(p1);
            Ps[w][g * 4 + r][32 + fr] = f2b(p2);
            Ps[w][g * 4 + r][48 + fr] = f2b(p3);
        }
        // ---- PV (per-wave; same-wave LDS RAW is ordered) --------------------
        bf16x8 pa0 = *(const bf16x8*)&Ps[w][fr][fk];
        bf16x8 pa1 = *(const bf16x8*)&Ps[w][fr][32 + fk];
        #pragma unroll
        for (int dt = 0; dt < 4; dt++) {
            bf16x8 vf0 = *(const bf16x8*)&Vt[dt * 16 + fr][fk];
            bf16x8 vf1 = *(const bf16x8*)&Vt[dt * 16 + fr][32 + fk];
            o[dt] = __builtin_amdgcn_mfma_f32_16x16x32_bf16(pa0, vf0, o[dt], 0, 0, 0);
            o[dt] = __builtin_amdgcn_mfma_f32_16x16x32_bf16(pa1, vf1, o[dt], 0, 0, 0);
        }
        __syncthreads();
    }
    // ---- epilogue: O[q][d] = o/l -------------------------------------------
    #pragma unroll
    for (int r = 0; r < 4; r++) {
        int q = q0 + g * 4 + r;
        if (q >= Nq) continue;
        float rcp = 1.0f / lsum[r];
        u16* orow = op + a * oA + (long long)q * oI + h * 64;
        #pragma unroll
        for (int dt = 0; dt < 4; dt++)
            orow[dt * 16 + fr] = f2b(o[dt][r] * rcp);
    }
}

// ---------------------------------------------------------------------------
extern "C" void kernel_launch(void* const* d_in, const int* in_sizes, int n_in,
                              void* d_out, int out_size, void* d_ws, size_t ws_size,
                              hipStream_t stream) {
    const int B = 8, sN = 196, tN = 1568;
    const int Ms = B * sN;            // 1568
    const int Mt = B * tN;            // 12544
    const int n_sf = Ms * 768;        // 1204224
    const int n_tf = Mt * 768;        // 9633792
    (void)n_in; (void)out_size; (void)ws_size;

    const bool dict_order = (in_sizes[0] == n_sf);
    auto IN = [&](int di, int ai) -> const float* {
        return (const float*)d_in[dict_order ? di : ai];
    };
    const float* in_sx      = IN(0, 35);
    const float* in_tx      = IN(1, 42);
    const float* ln1s_g     = IN(2, 14);
    const float* ln1s_b     = IN(3, 13);
    const float* mha_w      = IN(4, 28);
    const float* mha_b      = IN(5, 25);
    const float* mha_ow     = IN(6, 27);
    const float* mha_ob     = IN(7, 26);
    const float* ln1t_g     = IN(8, 16);
    const float* ln1t_b     = IN(9, 15);
    const float* attn_qkv_w = IN(10, 3);
    const float* attn_q_b   = IN(11, 2);
    const float* attn_v_b   = IN(12, 4);
    const float* attn_pw    = IN(13, 1);
    const float* attn_pb    = IN(14, 0);
    const float* lnt2s_g    = IN(15, 24);
    const float* lnt2s_b    = IN(16, 23);
    const float* t2s_qw     = IN(17, 41);
    const float* t2s_qb     = IN(18, 40);
    const float* t2s_kvw    = IN(19, 37);
    const float* t2s_kvb    = IN(20, 36);
    const float* t2s_pw     = IN(21, 39);
    const float* t2s_pb     = IN(22, 38);
    const float* lns2t_g    = IN(23, 22);
    const float* lns2t_b    = IN(24, 21);
    const float* s2t_qw     = IN(25, 34);
    const float* s2t_qb     = IN(26, 33);
    const float* s2t_kvw    = IN(27, 30);
    const float* s2t_kvb    = IN(28, 29);
    const float* s2t_pw     = IN(29, 32);
    const float* s2t_pb     = IN(30, 31);
    const float* ln2s_g     = IN(31, 18);
    const float* ln2s_b     = IN(32, 17);
    const float* cfc_w      = IN(33, 6);
    const float* cfc_b      = IN(34, 5);
    const float* cproj_w    = IN(35, 8);
    const float* cproj_b    = IN(36, 7);
    const float* ln2t_g     = IN(37, 20);
    const float* ln2t_b     = IN(38, 19);
    const float* fc1_w      = IN(39, 10);
    const float* fc1_b      = IN(40, 9);
    const float* fc2_w      = IN(41, 12);
    const float* fc2_b      = IN(42, 11);

    // ---- residual streams live in d_out (f32) -------------------------------
    float* s_f = (float*)d_out;
    float* t_f = (float*)d_out + n_sf;

    // ---- workspace (~134 MB) ------------------------------------------------
    char* ws = (char*)d_ws;
    size_t off = 0;
    auto take = [&](size_t bytes) { size_t o = off; off += (bytes + 255) & ~(size_t)255; return o; };
    float* biasf = (float*)(ws + take(3072 * 4));
    u16*   yb    = (u16*)(ws + take((size_t)Mt * 768 * 2));   // 19.3 MB
    u16*   bufA  = (u16*)(ws + take((size_t)Mt * 2304 * 2));  // 57.8 MB
    u16*   bufB  = (u16*)(ws + take((size_t)Mt * 768 * 2));   // 19.3 MB
    auto wtake = [&](size_t nelem) { return (u16*)(ws + take(nelem * 2)); };
    u16 *W_mha   = wtake(2304 * 768), *W_mhao  = wtake(768 * 768);
    u16 *W_qkv   = wtake(2304 * 768), *W_attnp = wtake(768 * 768);
    u16 *W_t2sq  = wtake(768 * 768),  *W_t2skv = wtake(1536 * 768), *W_t2sp = wtake(768 * 768);
    u16 *W_s2tq  = wtake(768 * 768),  *W_s2tkv = wtake(1536 * 768), *W_s2tp = wtake(768 * 768);
    u16 *W_cfc   = wtake(3072 * 768), *W_cproj = wtake(768 * 3072);
    u16 *W_fc1   = wtake(3072 * 768), *W_fc2   = wtake(768 * 3072);

    auto cdiv = [](int a, int b) { return (a + b - 1) / b; };
    #define BB(b0, c0, b1, c1, b2, c2) \
        build_bias<<<cdiv((c0) + (c1) + (c2), 256), 256, 0, stream>>>(biasf, b0, c0, b1, c1, b2, c2)
    auto CW = [&](const float* src, u16* dst, int n) {
        f2b_kernel<<<cdiv(n, 256), 256, 0, stream>>>(src, dst, n);
    };
    // weights -> bf16 pool
    CW(mha_w, W_mha, 2304 * 768);      CW(mha_ow, W_mhao, 768 * 768);
    CW(attn_qkv_w, W_qkv, 2304 * 768); CW(attn_pw, W_attnp, 768 * 768);
    CW(t2s_qw, W_t2sq, 768 * 768);     CW(t2s_kvw, W_t2skv, 1536 * 768);
    CW(t2s_pw, W_t2sp, 768 * 768);     CW(s2t_qw, W_s2tq, 768 * 768);
    CW(s2t_kvw, W_s2tkv, 1536 * 768);  CW(s2t_pw, W_s2tp, 768 * 768);
    CW(cfc_w, W_cfc, 3072 * 768);      CW(cproj_w, W_cproj, 768 * 3072);
    CW(fc1_w, W_fc1, 3072 * 768);      CW(fc2_w, W_fc2, 768 * 3072);

    // residual streams <- inputs
    copy_f32<<<cdiv(n_sf, 256), 256, 0, stream>>>(in_sx, s_f, n_sf);
    copy_f32<<<cdiv(n_tf, 256), 256, 0, stream>>>(in_tx, t_f, n_tf);

    // ---- stage 1: clip self-attention (attends over the batch axis) ---------
    ln_kernel<<<Ms, 256, 0, stream>>>(s_f, ln1s_g, ln1s_b, yb);
    BB(mha_b, 2304, (const float*)0, 0, (const float*)0, 0);
    gemm_mfma<0><<<dim3(cdiv(Ms, 128), 18), 256, 0, stream>>>(yb, W_mha, biasf, bufA, (float*)0, Ms, 2304, 768);
    flash_attn<<<dim3(1, sN * 12), 256, 0, stream>>>(
        bufA, bufA + 768, bufA + 1536, bufB, /*Nq=*/8, /*Nk=*/8,
        /*qA=*/2304LL, /*qI=*/(long long)sN * 2304,
        /*kA=*/2304LL, /*kJ=*/(long long)sN * 2304,
        /*vA=*/2304LL, /*vJ=*/(long long)sN * 2304,
        /*oA=*/768LL,  /*oI=*/(long long)sN * 768);
    BB(mha_ob, 768, (const float*)0, 0, (const float*)0, 0);
    gemm_mfma<1><<<dim3(cdiv(Ms, 128), 6), 256, 0, stream>>>(bufB, W_mhao, biasf, (u16*)0, s_f, Ms, 768, 768);

    // ---- stage 2: video self-attention --------------------------------------
    ln_kernel<<<Mt, 256, 0, stream>>>(t_f, ln1t_g, ln1t_b, yb);
    BB(attn_q_b, 768, (const float*)0, 768, attn_v_b, 768);  // [q_b, 0, v_b]
    gemm_mfma<0><<<dim3(cdiv(Mt, 128), 18), 256, 0, stream>>>(yb, W_qkv, biasf, bufA, (float*)0, Mt, 2304, 768);
    flash_attn<<<dim3(cdiv(tN, 64), B * 12), 256, 0, stream>>>(
        bufA, bufA + 768, bufA + 1536, bufB, /*Nq=*/tN, /*Nk=*/tN,
        (long long)tN * 2304, 2304LL,
        (long long)tN * 2304, 2304LL,
        (long long)tN * 2304, 2304LL,
        (long long)tN * 768, 768LL);
    BB(attn_pb, 768, (const float*)0, 0, (const float*)0, 0);
    gemm_mfma<1><<<dim3(cdiv(Mt, 128), 6), 256, 0, stream>>>(bufB, W_attnp, biasf, (u16*)0, t_f, Mt, 768, 768);

    // ---- stage 3: T2S cross (q from LN(s_x), kv from updated t_x) -----------
    f2b_kernel<<<cdiv(n_tf, 256), 256, 0, stream>>>(t_f, yb, n_tf);   // bf16(t_x)
    BB((const float*)0, 768, t2s_kvb, 768, (const float*)0, 0);       // [0, kvb]
    gemm_mfma<0><<<dim3(cdiv(Mt, 128), 12), 256, 0, stream>>>(yb, W_t2skv, biasf, bufA, (float*)0, Mt, 1536, 768);
    ln_kernel<<<Ms, 256, 0, stream>>>(s_f, lnt2s_g, lnt2s_b, yb);
    BB(t2s_qb, 768, (const float*)0, 0, (const float*)0, 0);
    u16* q3 = bufB;
    u16* o3 = bufB + (size_t)Ms * 768;
    gemm_mfma<0><<<dim3(cdiv(Ms, 128), 6), 256, 0, stream>>>(yb, W_t2sq, biasf, q3, (float*)0, Ms, 768, 768);
    flash_attn<<<dim3(cdiv(sN, 64), B * 12), 256, 0, stream>>>(
        q3, bufA, bufA + 768, o3, /*Nq=*/sN, /*Nk=*/tN,
        (long long)sN * 768, 768LL,
        (long long)tN * 1536, 1536LL,
        (long long)tN * 1536, 1536LL,
        (long long)sN * 768, 768LL);
    BB(t2s_pb, 768, (const float*)0, 0, (const float*)0, 0);
    gemm_mfma<1><<<dim3(cdiv(Ms, 128), 6), 256, 0, stream>>>(o3, W_t2sp, biasf, (u16*)0, s_f, Ms, 768, 768);

    // ---- stage 4: S2T cross (q from LN(t_x), kv from updated s_x) -----------
    ln_kernel<<<Mt, 256, 0, stream>>>(t_f, lns2t_g, lns2t_b, yb);
    BB(s2t_qb, 768, (const float*)0, 0, (const float*)0, 0);
    gemm_mfma<0><<<dim3(cdiv(Mt, 128), 6), 256, 0, stream>>>(yb, W_s2tq, biasf, bufB, (float*)0, Mt, 768, 768);
    f2b_kernel<<<cdiv(n_sf, 256), 256, 0, stream>>>(s_f, yb, n_sf);   // bf16(s_x)
    BB((const float*)0, 768, s2t_kvb, 768, (const float*)0, 0);
    gemm_mfma<0><<<dim3(cdiv(Ms, 128), 12), 256, 0, stream>>>(yb, W_s2tkv, biasf, bufA, (float*)0, Ms, 1536, 768);
    flash_attn<<<dim3(cdiv(tN, 64), B * 12), 256, 0, stream>>>(
        bufB, bufA, bufA + 768, yb, /*Nq=*/tN, /*Nk=*/sN,
        (long long)tN * 768, 768LL,
        (long long)sN * 1536, 1536LL,
        (long long)sN * 1536, 1536LL,
        (long long)tN * 768, 768LL);
    BB(s2t_pb, 768, (const float*)0, 0, (const float*)0, 0);
    gemm_mfma<1><<<dim3(cdiv(Mt, 128), 6), 256, 0, stream>>>(yb, W_s2tp, biasf, (u16*)0, t_f, Mt, 768, 768);

    // ---- stage 5: clip MLP (QuickGELU) --------------------------------------
    ln_kernel<<<Ms, 256, 0, stream>>>(s_f, ln2s_g, ln2s_b, yb);
    BB(cfc_b, 3072, (const float*)0, 0, (const float*)0, 0);
    gemm_mfma<2><<<dim3(cdiv(Ms, 128), 24), 256, 0, stream>>>(yb, W_cfc, biasf, bufA, (float*)0, Ms, 3072, 768);
    BB(cproj_b, 768, (const float*)0, 0, (const float*)0, 0);
    gemm_mfma<1><<<dim3(cdiv(Ms, 128), 6), 256, 0, stream>>>(bufA, W_cproj, biasf, (u16*)0, s_f, Ms, 768, 3072);

    // ---- stage 6: video MLP (exact GELU), two row-halves --------------------
    ln_kernel<<<Mt, 256, 0, stream>>>(t_f, ln2t_g, ln2t_b, yb);
    for (int c = 0; c < 2; c++) {
        int r0 = c * (Mt / 2), Mc = Mt / 2;
        BB(fc1_b, 3072, (const float*)0, 0, (const float*)0, 0);
        gemm_mfma<3><<<dim3(cdiv(Mc, 128), 24), 256, 0, stream>>>(
            yb + (size_t)r0 * 768, W_fc1, biasf, bufA, (float*)0, Mc, 3072, 768);
        BB(fc2_b, 768, (const float*)0, 0, (const float*)0, 0);
        gemm_mfma<1><<<dim3(cdiv(Mc, 128), 6), 256, 0, stream>>>(
            bufA, W_fc2, biasf, (u16*)0, t_f + (size_t)r0 * 768, Mc, 768, 3072);
    }
    #undef BB
}

// Round 8
// 1278.114 us; speedup vs baseline: 17.3390x; 1.1320x over previous
//
#include <hip/hip_runtime.h>
#include <stdint.h>

// ---------------------------------------------------------------------------
// Block_6554120094246: dual-stream transformer block (CLIP + video streams).
// f32 in/out. Residual streams in d_out. bf16 intermediates + MFMA GEMM
// (16x16x32 bf16, 128x128 tile, global_load_lds staging) + MFMA flash
// attention v3: swapped QK^T (lane-local softmax rows), stride-72 LDS
// (conflict-free b128), b64 P stores. ws ~136 MB.
// ---------------------------------------------------------------------------

typedef uint16_t u16;
typedef uint16_t u16x8 __attribute__((ext_vector_type(8)));
typedef uint16_t u16x4 __attribute__((ext_vector_type(4)));
typedef short bf16x8 __attribute__((ext_vector_type(8)));
typedef float f32x4 __attribute__((ext_vector_type(4)));
typedef int i32x4 __attribute__((ext_vector_type(4)));

__device__ __forceinline__ float b2f(u16 u) {
    union { float f; uint32_t i; } x;
    x.i = ((uint32_t)u) << 16;
    return x.f;
}
__device__ __forceinline__ u16 f2b(float f) {
    union { float f; uint32_t i; } x;
    x.f = f;
    uint32_t i = x.i;
    uint32_t r = (i + 0x7FFFu + ((i >> 16) & 1u)) >> 16;  // RNE
    return (u16)r;
}
__device__ __forceinline__ u16 f2b_trunc(float f) {      // for P in [0,1]
    union { float f; uint32_t i; } x;
    x.f = f;
    return (u16)(x.i >> 16);
}

// async global->LDS, 16B per lane; LDS dest must be wave-uniform base.
__device__ __forceinline__ void gload16(const u16* g, u16* l) {
    __builtin_amdgcn_global_load_lds(
        (const __attribute__((address_space(1))) uint32_t*)g,
        (__attribute__((address_space(3))) uint32_t*)l, 16, 0, 0);
}

__global__ void f2b_kernel(const float* __restrict__ in, u16* __restrict__ out, int n) {
    int i = blockIdx.x * 256 + threadIdx.x;
    if (i < n) out[i] = f2b(in[i]);
}
__global__ void copy_f32(const float* __restrict__ in, float* __restrict__ out, int n) {
    int i = blockIdx.x * 256 + threadIdx.x;
    if (i < n) out[i] = in[i];
}

// ---- bias builder: dst = concat(p0[0:n0], p1[0:n1], p2[0:n2]); null -> 0 ----
__global__ void build_bias(float* __restrict__ dst,
                           const float* p0, int n0, const float* p1, int n1,
                           const float* p2, int n2) {
    int i = blockIdx.x * 256 + threadIdx.x;
    int total = n0 + n1 + n2;
    if (i >= total) return;
    const float* p; int j;
    if (i < n0)           { p = p0; j = i; }
    else if (i < n0 + n1) { p = p1; j = i - n0; }
    else                  { p = p2; j = i - n0 - n1; }
    dst[i] = p ? p[j] : 0.f;
}

// ---- block reductions (blockDim.x == 256, 4 waves of 64) --------------------
__device__ __forceinline__ float block_sum(float v, float* red) {
    #pragma unroll
    for (int o = 32; o > 0; o >>= 1) v += __shfl_down(v, o, 64);
    int w = threadIdx.x >> 6, l = threadIdx.x & 63;
    __syncthreads();
    if (l == 0) red[w] = v;
    __syncthreads();
    return red[0] + red[1] + red[2] + red[3];
}

// ---- LayerNorm over C=768: f32 in, f32 params, bf16 out ---------------------
__global__ __launch_bounds__(256) void ln_kernel(
    const float* __restrict__ x, const float* __restrict__ g,
    const float* __restrict__ bta, u16* __restrict__ y) {
    const int r = blockIdx.x;
    const int t = threadIdx.x;
    const float* xr = x + (size_t)r * 768;
    float v0 = xr[t], v1 = xr[t + 256], v2 = xr[t + 512];
    __shared__ float red[4];
    float mean = block_sum(v0 + v1 + v2, red) * (1.0f / 768.0f);
    float d0 = v0 - mean, d1 = v1 - mean, d2 = v2 - mean;
    float var = block_sum(d0 * d0 + d1 * d1 + d2 * d2, red) * (1.0f / 768.0f);
    float rs = rsqrtf(var + 1e-5f);
    u16* yr = y + (size_t)r * 768;
    yr[t]       = f2b(d0 * rs * g[t]       + bta[t]);
    yr[t + 256] = f2b(d1 * rs * g[t + 256] + bta[t + 256]);
    yr[t + 512] = f2b(d2 * rs * g[t + 512] + bta[t + 512]);
}

// ---- MFMA GEMM: C[M,N] = A[M,K](bf16) @ W[N,K](bf16)^T + bias[N] ------------
// MODE 0: store bf16.  1: Cf += v.  2: QuickGELU->bf16.  3: exact GELU->bf16.
// MODE 4: Cf += v AND Cb = f2b(new Cf)  (residual + bf16 mirror).
template <int MODE>
__global__ __launch_bounds__(256) void gemm_mfma(
    const u16* __restrict__ A, const u16* __restrict__ W,
    const float* __restrict__ bias, u16* __restrict__ Cb,
    float* __restrict__ Cf, int M, int N, int K) {
    __shared__ u16 As[128][32];
    __shared__ u16 Bs[128][32];
    const int tid = threadIdx.x;
    const int lane = tid & 63;
    const int wid = tid >> 6;
    const int wr = (wid >> 1) * 64, wc = (wid & 1) * 64;
    const int m0 = blockIdx.x * 128, n0 = blockIdx.y * 128;
    const int lr = lane >> 2, lc = (lane & 3) * 8;
    const int fr = lane & 15, fk = (lane >> 4) * 8;
    const int base_row = wid * 32;
    f32x4 acc[4][4] = {};
    for (int k0 = 0; k0 < K; k0 += 32) {
        #pragma unroll
        for (int j = 0; j < 2; j++) {
            int rowa = m0 + base_row + j * 16 + lr;
            rowa = rowa < M ? rowa : M - 1;        // clamp (values unused)
            gload16(A + (size_t)rowa * K + k0 + lc, &As[base_row + j * 16][0]);
            gload16(W + (size_t)(n0 + base_row + j * 16 + lr) * K + k0 + lc,
                    &Bs[base_row + j * 16][0]);
        }
        __syncthreads();
        bf16x8 a[4], b[4];
        #pragma unroll
        for (int i = 0; i < 4; i++) a[i] = *(const bf16x8*)&As[wr + i * 16 + fr][fk];
        #pragma unroll
        for (int j = 0; j < 4; j++) b[j] = *(const bf16x8*)&Bs[wc + j * 16 + fr][fk];
        #pragma unroll
        for (int i = 0; i < 4; i++)
            #pragma unroll
            for (int j = 0; j < 4; j++)
                acc[i][j] = __builtin_amdgcn_mfma_f32_16x16x32_bf16(a[i], b[j], acc[i][j], 0, 0, 0);
        __syncthreads();
    }
    const int er = (lane >> 4) * 4;
    #pragma unroll
    for (int i = 0; i < 4; i++) {
        #pragma unroll
        for (int reg = 0; reg < 4; reg++) {
            int r = m0 + wr + i * 16 + er + reg;
            if (r >= M) continue;
            #pragma unroll
            for (int j = 0; j < 4; j++) {
                int c = n0 + wc + j * 16 + fr;
                float v = acc[i][j][reg] + bias[c];
                size_t idx = (size_t)r * N + c;
                if (MODE == 1) {
                    Cf[idx] += v;
                } else if (MODE == 4) {
                    float nv = Cf[idx] + v;
                    Cf[idx] = nv;
                    Cb[idx] = f2b(nv);
                } else {
                    if (MODE == 2) v = v / (1.0f + expf(-1.702f * v));
                    if (MODE == 3) v = 0.5f * v * (1.0f + erff(v * 0.70710678118654752f));
                    Cb[idx] = f2b(v);
                }
            }
        }
    }
}

// ---- MFMA flash attention v3 (HD=64, scale pre-folded into Q) ---------------
// Swapped QK^T: s = mfma(K, Q) gives S^T; lane holds one q-row (q = lane&15),
// kv = (lane>>4)*4 + reg + hh*16. Softmax: local 16-reduce + shfl_xor(16,32).
// P stored as 4x b64 per lane; PV uses same A/B frags as the GEMM. Strides 72
// u16 (36 dw == 4 mod 32) => all b128 LDS ops at the 8-cycle minimum.
__global__ __launch_bounds__(256) void flash_attn(
    const u16* __restrict__ qp, const u16* __restrict__ kp,
    const u16* __restrict__ vp, u16* __restrict__ op, int Nq, int Nk,
    long long qA, long long qI, long long kA, long long kJ,
    long long vA, long long vJ, long long oA, long long oI) {
    const int a = blockIdx.y / 12, h = blockIdx.y % 12;
    const int tid = threadIdx.x, lane = tid & 63, w = tid >> 6;
    const int fr = lane & 15, g = lane >> 4, fk = g * 8;
    __shared__ u16 Ks[64][72];      // K tile [kv][d]
    __shared__ u16 Vt[64][72];      // V^T tile [d][kv]
    __shared__ u16 Ps[4][16][72];   // per-wave P tile [q][kv]
    const u16* qb = qp + a * qA + h * 64;
    const u16* kb = kp + a * kA + h * 64;
    const u16* vb = vp + a * vA + h * 64;
    const int q0 = blockIdx.x * 64 + w * 16;

    // Q as B-operand (col = q = fr), pre-scaled by 0.125 (exact in bf16)
    bf16x8 qf[2];
    {
        u16x8 raw0 = {}, raw1 = {};
        int qr = q0 + fr;
        if (qr < Nq) {
            const u16* qrp = qb + (long long)qr * qI;
            raw0 = *(const u16x8*)(qrp + fk);
            raw1 = *(const u16x8*)(qrp + 32 + fk);
        }
        u16x8 s0, s1;
        #pragma unroll
        for (int e = 0; e < 8; e++) {
            s0[e] = f2b(b2f(raw0[e]) * 0.125f);
            s1[e] = f2b(b2f(raw1[e]) * 0.125f);
        }
        qf[0] = *(bf16x8*)&s0;
        qf[1] = *(bf16x8*)&s1;
    }
    float mrun = -1e30f, lrun = 0.f;
    f32x4 o[4] = {};

    const int kv = tid >> 2, dbs = (tid & 3) * 16;
    const int kvb = kv & ~1, epair = (kv & 1) * 4;

    for (int t0 = 0; t0 < Nk; t0 += 64) {
        // ---- stage K linear + V transposed (kv-pair packed u32 stores) ------
        {
            u16x8 kv0 = {}, kv1 = {}, vv0 = {}, vv1 = {};
            if (t0 + kv < Nk) {
                const u16* kr = kb + (long long)(t0 + kv) * kJ + dbs;
                const u16* vr = vb + (long long)(t0 + kv) * vJ + dbs;
                kv0 = *(const u16x8*)kr;  kv1 = *(const u16x8*)(kr + 8);
                vv0 = *(const u16x8*)vr;  vv1 = *(const u16x8*)(vr + 8);
            }
            *(u16x8*)&Ks[kv][dbs]     = kv0;
            *(u16x8*)&Ks[kv][dbs + 8] = kv1;
            #pragma unroll
            for (int hh2 = 0; hh2 < 2; hh2++) {
                u16x8 mine = hh2 ? vv1 : vv0;
                i32x4 m32 = *(i32x4*)&mine;
                i32x4 o32;
                #pragma unroll
                for (int d2 = 0; d2 < 4; d2++) o32[d2] = __shfl_xor(m32[d2], 4, 64);
                u16x8 other = *(u16x8*)&o32;
                #pragma unroll
                for (int e2 = 0; e2 < 4; e2++) {
                    int e = epair + e2;
                    uint32_t lo = (kv & 1) ? other[e] : mine[e];
                    uint32_t hi = (kv & 1) ? mine[e] : other[e];
                    *(uint32_t*)&Vt[dbs + hh2 * 8 + e][kvb] = lo | (hi << 16);
                }
            }
        }
        __syncthreads();

        // ---- S^T[kv][q] = K Qs^T : s[hh][r] = S[q=fr][kv = t0+hh*16+4g+r] ----
        f32x4 s[4] = {};
        #pragma unroll
        for (int hh = 0; hh < 4; hh++) {
            bf16x8 k0f = *(const bf16x8*)&Ks[hh * 16 + fr][fk];
            bf16x8 k1f = *(const bf16x8*)&Ks[hh * 16 + fr][32 + fk];
            s[hh] = __builtin_amdgcn_mfma_f32_16x16x32_bf16(k0f, qf[0], s[hh], 0, 0, 0);
            s[hh] = __builtin_amdgcn_mfma_f32_16x16x32_bf16(k1f, qf[1], s[hh], 0, 0, 0);
        }
        // ---- online softmax, one q-row per lane ------------------------------
        float lmax = -1e30f;
        if (t0 + 64 <= Nk) {
            #pragma unroll
            for (int hh = 0; hh < 4; hh++)
                #pragma unroll
                for (int r = 0; r < 4; r++) lmax = fmaxf(lmax, s[hh][r]);
        } else {
            #pragma unroll
            for (int hh = 0; hh < 4; hh++)
                #pragma unroll
                for (int r = 0; r < 4; r++) {
                    if (t0 + hh * 16 + 4 * g + r >= Nk) s[hh][r] = -1e30f;
                    lmax = fmaxf(lmax, s[hh][r]);
                }
        }
        lmax = fmaxf(lmax, __shfl_xor(lmax, 16, 64));
        lmax = fmaxf(lmax, __shfl_xor(lmax, 32, 64));
        float mn = fmaxf(mrun, lmax);
        float p[4][4];
        float ps = 0.f;
        #pragma unroll
        for (int hh = 0; hh < 4; hh++)
            #pragma unroll
            for (int r = 0; r < 4; r++) {
                p[hh][r] = __expf(s[hh][r] - mn);
                ps += p[hh][r];
            }
        ps += __shfl_xor(ps, 16, 64);
        ps += __shfl_xor(ps, 32, 64);
        float sf = __expf(mrun - mn);
        mrun = mn;
        lrun = lrun * sf + ps;
        float sfo[4];
        #pragma unroll
        for (int r = 0; r < 4; r++) sfo[r] = __shfl(sf, g * 4 + r, 64);
        #pragma unroll
        for (int dt = 0; dt < 4; dt++)
            #pragma unroll
            for (int r = 0; r < 4; r++) o[dt][r] *= sfo[r];
        // ---- P -> LDS (4x b64, row = own q-row) ------------------------------
        #pragma unroll
        for (int hh = 0; hh < 4; hh++) {
            u16x4 pk;
            #pragma unroll
            for (int r = 0; r < 4; r++) pk[r] = f2b_trunc(p[hh][r]);
            *(u16x4*)&Ps[w][fr][hh * 16 + g * 4] = pk;
        }
        // ---- PV (same-wave LDS RAW is ordered) -------------------------------
        bf16x8 pa0 = *(const bf16x8*)&Ps[w][fr][fk];
        bf16x8 pa1 = *(const bf16x8*)&Ps[w][fr][32 + fk];
        #pragma unroll
        for (int dt = 0; dt < 4; dt++) {
            bf16x8 vf0 = *(const bf16x8*)&Vt[dt * 16 + fr][fk];
            bf16x8 vf1 = *(const bf16x8*)&Vt[dt * 16 + fr][32 + fk];
            o[dt] = __builtin_amdgcn_mfma_f32_16x16x32_bf16(pa0, vf0, o[dt], 0, 0, 0);
            o[dt] = __builtin_amdgcn_mfma_f32_16x16x32_bf16(pa1, vf1, o[dt], 0, 0, 0);
        }
        __syncthreads();
    }
    // ---- epilogue: O[q][d] = o/l ; q = q0 + 4g + r, d = dt*16 + fr ----------
    float rcp = 1.0f / lrun;
    #pragma unroll
    for (int r = 0; r < 4; r++) {
        float rr = __shfl(rcp, g * 4 + r, 64);
        int q = q0 + g * 4 + r;
        if (q >= Nq) continue;
        u16* orow = op + a * oA + (long long)q * oI + h * 64;
        #pragma unroll
        for (int dt = 0; dt < 4; dt++)
            orow[dt * 16 + fr] = f2b(o[dt][r] * rr);
    }
}

// ---------------------------------------------------------------------------
extern "C" void kernel_launch(void* const* d_in, const int* in_sizes, int n_in,
                              void* d_out, int out_size, void* d_ws, size_t ws_size,
                              hipStream_t stream) {
    const int B = 8, sN = 196, tN = 1568;
    const int Ms = B * sN;            // 1568
    const int Mt = B * tN;            // 12544
    const int n_sf = Ms * 768;        // 1204224
    const int n_tf = Mt * 768;        // 9633792
    (void)n_in; (void)out_size; (void)ws_size;

    const bool dict_order = (in_sizes[0] == n_sf);
    auto IN = [&](int di, int ai) -> const float* {
        return (const float*)d_in[dict_order ? di : ai];
    };
    const float* in_sx      = IN(0, 35);
    const float* in_tx      = IN(1, 42);
    const float* ln1s_g     = IN(2, 14);
    const float* ln1s_b     = IN(3, 13);
    const float* mha_w      = IN(4, 28);
    const float* mha_b      = IN(5, 25);
    const float* mha_ow     = IN(6, 27);
    const float* mha_ob     = IN(7, 26);
    const float* ln1t_g     = IN(8, 16);
    const float* ln1t_b     = IN(9, 15);
    const float* attn_qkv_w = IN(10, 3);
    const float* attn_q_b   = IN(11, 2);
    const float* attn_v_b   = IN(12, 4);
    const float* attn_pw    = IN(13, 1);
    const float* attn_pb    = IN(14, 0);
    const float* lnt2s_g    = IN(15, 24);
    const float* lnt2s_b    = IN(16, 23);
    const float* t2s_qw     = IN(17, 41);
    const float* t2s_qb     = IN(18, 40);
    const float* t2s_kvw    = IN(19, 37);
    const float* t2s_kvb    = IN(20, 36);
    const float* t2s_pw     = IN(21, 39);
    const float* t2s_pb     = IN(22, 38);
    const float* lns2t_g    = IN(23, 22);
    const float* lns2t_b    = IN(24, 21);
    const float* s2t_qw     = IN(25, 34);
    const float* s2t_qb     = IN(26, 33);
    const float* s2t_kvw    = IN(27, 30);
    const float* s2t_kvb    = IN(28, 29);
    const float* s2t_pw     = IN(29, 32);
    const float* s2t_pb     = IN(30, 31);
    const float* ln2s_g     = IN(31, 18);
    const float* ln2s_b     = IN(32, 17);
    const float* cfc_w      = IN(33, 6);
    const float* cfc_b      = IN(34, 5);
    const float* cproj_w    = IN(35, 8);
    const float* cproj_b    = IN(36, 7);
    const float* ln2t_g     = IN(37, 20);
    const float* ln2t_b     = IN(38, 19);
    const float* fc1_w      = IN(39, 10);
    const float* fc1_b      = IN(40, 9);
    const float* fc2_w      = IN(41, 12);
    const float* fc2_b      = IN(42, 11);

    // ---- residual streams live in d_out (f32) -------------------------------
    float* s_f = (float*)d_out;
    float* t_f = (float*)d_out + n_sf;

    // ---- workspace (~136 MB) ------------------------------------------------
    char* ws = (char*)d_ws;
    size_t off = 0;
    auto take = [&](size_t bytes) { size_t o = off; off += (bytes + 255) & ~(size_t)255; return o; };
    float* biasf = (float*)(ws + take(3072 * 4));
    u16*   yb    = (u16*)(ws + take((size_t)Mt * 768 * 2));   // 19.3 MB
    u16*   bufA  = (u16*)(ws + take((size_t)Mt * 2304 * 2));  // 57.8 MB
    u16*   bufB  = (u16*)(ws + take((size_t)Mt * 768 * 2));   // 19.3 MB
    u16*   sxb   = (u16*)(ws + take((size_t)Ms * 768 * 2));   // 2.4 MB (bf16 s_x mirror)
    auto wtake = [&](size_t nelem) { return (u16*)(ws + take(nelem * 2)); };
    u16 *W_mha   = wtake(2304 * 768), *W_mhao  = wtake(768 * 768);
    u16 *W_qkv   = wtake(2304 * 768), *W_attnp = wtake(768 * 768);
    u16 *W_t2sq  = wtake(768 * 768),  *W_t2skv = wtake(1536 * 768), *W_t2sp = wtake(768 * 768);
    u16 *W_s2tq  = wtake(768 * 768),  *W_s2tkv = wtake(1536 * 768), *W_s2tp = wtake(768 * 768);
    u16 *W_cfc   = wtake(3072 * 768), *W_cproj = wtake(768 * 3072);
    u16 *W_fc1   = wtake(3072 * 768), *W_fc2   = wtake(768 * 3072);

    auto cdiv = [](int a, int b) { return (a + b - 1) / b; };
    #define BB(b0, c0, b1, c1, b2, c2) \
        build_bias<<<cdiv((c0) + (c1) + (c2), 256), 256, 0, stream>>>(biasf, b0, c0, b1, c1, b2, c2)
    auto CW = [&](const float* src, u16* dst, int n) {
        f2b_kernel<<<cdiv(n, 256), 256, 0, stream>>>(src, dst, n);
    };
    // weights -> bf16 pool
    CW(mha_w, W_mha, 2304 * 768);      CW(mha_ow, W_mhao, 768 * 768);
    CW(attn_qkv_w, W_qkv, 2304 * 768); CW(attn_pw, W_attnp, 768 * 768);
    CW(t2s_qw, W_t2sq, 768 * 768);     CW(t2s_kvw, W_t2skv, 1536 * 768);
    CW(t2s_pw, W_t2sp, 768 * 768);     CW(s2t_qw, W_s2tq, 768 * 768);
    CW(s2t_kvw, W_s2tkv, 1536 * 768);  CW(s2t_pw, W_s2tp, 768 * 768);
    CW(cfc_w, W_cfc, 3072 * 768);      CW(cproj_w, W_cproj, 768 * 3072);
    CW(fc1_w, W_fc1, 3072 * 768);      CW(fc2_w, W_fc2, 768 * 3072);

    // residual streams <- inputs
    copy_f32<<<cdiv(n_sf, 256), 256, 0, stream>>>(in_sx, s_f, n_sf);
    copy_f32<<<cdiv(n_tf, 256), 256, 0, stream>>>(in_tx, t_f, n_tf);

    // ---- stage 1: clip self-attention (attends over the batch axis) ---------
    ln_kernel<<<Ms, 256, 0, stream>>>(s_f, ln1s_g, ln1s_b, yb);
    BB(mha_b, 2304, (const float*)0, 0, (const float*)0, 0);
    gemm_mfma<0><<<dim3(cdiv(Ms, 128), 18), 256, 0, stream>>>(yb, W_mha, biasf, bufA, (float*)0, Ms, 2304, 768);
    flash_attn<<<dim3(1, sN * 12), 256, 0, stream>>>(
        bufA, bufA + 768, bufA + 1536, bufB, /*Nq=*/8, /*Nk=*/8,
        /*qA=*/2304LL, /*qI=*/(long long)sN * 2304,
        /*kA=*/2304LL, /*kJ=*/(long long)sN * 2304,
        /*vA=*/2304LL, /*vJ=*/(long long)sN * 2304,
        /*oA=*/768LL,  /*oI=*/(long long)sN * 768);
    BB(mha_ob, 768, (const float*)0, 0, (const float*)0, 0);
    gemm_mfma<1><<<dim3(cdiv(Ms, 128), 6), 256, 0, stream>>>(bufB, W_mhao, biasf, (u16*)0, s_f, Ms, 768, 768);

    // ---- stage 2: video self-attention --------------------------------------
    ln_kernel<<<Mt, 256, 0, stream>>>(t_f, ln1t_g, ln1t_b, yb);
    BB(attn_q_b, 768, (const float*)0, 768, attn_v_b, 768);  // [q_b, 0, v_b]
    gemm_mfma<0><<<dim3(cdiv(Mt, 128), 18), 256, 0, stream>>>(yb, W_qkv, biasf, bufA, (float*)0, Mt, 2304, 768);
    flash_attn<<<dim3(cdiv(tN, 64), B * 12), 256, 0, stream>>>(
        bufA, bufA + 768, bufA + 1536, bufB, /*Nq=*/tN, /*Nk=*/tN,
        (long long)tN * 2304, 2304LL,
        (long long)tN * 2304, 2304LL,
        (long long)tN * 2304, 2304LL,
        (long long)tN * 768, 768LL);
    BB(attn_pb, 768, (const float*)0, 0, (const float*)0, 0);
    // MODE 4: t_f += proj, yb = bf16(new t_f)  (feeds stage-3 KV)
    gemm_mfma<4><<<dim3(cdiv(Mt, 128), 6), 256, 0, stream>>>(bufB, W_attnp, biasf, yb, t_f, Mt, 768, 768);

    // ---- stage 3: T2S cross (q from LN(s_x), kv from updated t_x) -----------
    BB((const float*)0, 768, t2s_kvb, 768, (const float*)0, 0);       // [0, kvb]
    gemm_mfma<0><<<dim3(cdiv(Mt, 128), 12), 256, 0, stream>>>(yb, W_t2skv, biasf, bufA, (float*)0, Mt, 1536, 768);
    ln_kernel<<<Ms, 256, 0, stream>>>(s_f, lnt2s_g, lnt2s_b, yb);
    BB(t2s_qb, 768, (const float*)0, 0, (const float*)0, 0);
    u16* q3 = bufB;
    u16* o3 = bufB + (size_t)Ms * 768;
    gemm_mfma<0><<<dim3(cdiv(Ms, 128), 6), 256, 0, stream>>>(yb, W_t2sq, biasf, q3, (float*)0, Ms, 768, 768);
    flash_attn<<<dim3(cdiv(sN, 64), B * 12), 256, 0, stream>>>(
        q3, bufA, bufA + 768, o3, /*Nq=*/sN, /*Nk=*/tN,
        (long long)sN * 768, 768LL,
        (long long)tN * 1536, 1536LL,
        (long long)tN * 1536, 1536LL,
        (long long)sN * 768, 768LL);
    BB(t2s_pb, 768, (const float*)0, 0, (const float*)0, 0);
    // MODE 4: s_f += proj, sxb = bf16(new s_f)  (feeds stage-4 KV)
    gemm_mfma<4><<<dim3(cdiv(Ms, 128), 6), 256, 0, stream>>>(o3, W_t2sp, biasf, sxb, s_f, Ms, 768, 768);

    // ---- stage 4: S2T cross (q from LN(t_x), kv from updated s_x) -----------
    ln_kernel<<<Mt, 256, 0, stream>>>(t_f, lns2t_g, lns2t_b, yb);
    BB(s2t_qb, 768, (const float*)0, 0, (const float*)0, 0);
    gemm_mfma<0><<<dim3(cdiv(Mt, 128), 6), 256, 0, stream>>>(yb, W_s2tq, biasf, bufB, (float*)0, Mt, 768, 768);
    BB((const float*)0, 768, s2t_kvb, 768, (const float*)0, 0);
    gemm_mfma<0><<<dim3(cdiv(Ms, 128), 12), 256, 0, stream>>>(sxb, W_s2tkv, biasf, bufA, (float*)0, Ms, 1536, 768);
    flash_attn<<<dim3(cdiv(tN, 64), B * 12), 256, 0, stream>>>(
        bufB, bufA, bufA + 768, yb, /*Nq=*/tN, /*Nk=*/sN,
        (long long)tN * 768, 768LL,
        (long long)sN * 1536, 1536LL,
        (long long)sN * 1536, 1536LL,
        (long long)tN * 768, 768LL);
    BB(s2t_pb, 768, (const float*)0, 0, (const float*)0, 0);
    gemm_mfma<1><<<dim3(cdiv(Mt, 128), 6), 256, 0, stream>>>(yb, W_s2tp, biasf, (u16*)0, t_f, Mt, 768, 768);

    // ---- stage 5: clip MLP (QuickGELU) --------------------------------------
    ln_kernel<<<Ms, 256, 0, stream>>>(s_f, ln2s_g, ln2s_b, yb);
    BB(cfc_b, 3072, (const float*)0, 0, (const float*)0, 0);
    gemm_mfma<2><<<dim3(cdiv(Ms, 128), 24), 256, 0, stream>>>(yb, W_cfc, biasf, bufA, (float*)0, Ms, 3072, 768);
    BB(cproj_b, 768, (const float*)0, 0, (const float*)0, 0);
    gemm_mfma<1><<<dim3(cdiv(Ms, 128), 6), 256, 0, stream>>>(bufA, W_cproj, biasf, (u16*)0, s_f, Ms, 768, 3072);

    // ---- stage 6: video MLP (exact GELU), two row-halves --------------------
    ln_kernel<<<Mt, 256, 0, stream>>>(t_f, ln2t_g, ln2t_b, yb);
    for (int c = 0; c < 2; c++) {
        int r0 = c * (Mt / 2), Mc = Mt / 2;
        BB(fc1_b, 3072, (const float*)0, 0, (const float*)0, 0);
        gemm_mfma<3><<<dim3(cdiv(Mc, 128), 24), 256, 0, stream>>>(
            yb + (size_t)r0 * 768, W_fc1, biasf, bufA, (float*)0, Mc, 3072, 768);
        BB(fc2_b, 768, (const float*)0, 0, (const float*)0, 0);
        gemm_mfma<1><<<dim3(cdiv(Mc, 128), 6), 256, 0, stream>>>(
            bufA, W_fc2, biasf, (u16*)0, t_f + (size_t)r0 * 768, Mc, 768, 3072);
    }
    #undef BB
}

// Round 9
// 1225.711 us; speedup vs baseline: 18.0803x; 1.0428x over previous
//
#include <hip/hip_runtime.h>
#include <stdint.h>

// ---------------------------------------------------------------------------
// Block_6554120094246: dual-stream transformer block (CLIP + video streams).
// f32 in/out. Residual streams in d_out. bf16 intermediates + MFMA GEMM
// (128x128x32, global_load_lds) + MFMA flash attention v4: pre-transposed V,
// gload_lds K/V staging with XOR-swizzled source, swizzled Ps, defer-max,
// exp2-domain softmax. ws ~156 MB.
// ---------------------------------------------------------------------------

typedef uint16_t u16;
typedef uint16_t u16x8 __attribute__((ext_vector_type(8)));
typedef uint16_t u16x4 __attribute__((ext_vector_type(4)));
typedef short bf16x8 __attribute__((ext_vector_type(8)));
typedef float f32x4 __attribute__((ext_vector_type(4)));

__device__ __forceinline__ float b2f(u16 u) {
    union { float f; uint32_t i; } x;
    x.i = ((uint32_t)u) << 16;
    return x.f;
}
__device__ __forceinline__ u16 f2b(float f) {
    union { float f; uint32_t i; } x;
    x.f = f;
    uint32_t i = x.i;
    uint32_t r = (i + 0x7FFFu + ((i >> 16) & 1u)) >> 16;  // RNE
    return (u16)r;
}
__device__ __forceinline__ u16 f2b_trunc(float f) {      // for P in [0,256]
    union { float f; uint32_t i; } x;
    x.f = f;
    return (u16)(x.i >> 16);
}

// async global->LDS, 16B per lane; LDS dest wave-uniform base (+lane*16B).
__device__ __forceinline__ void gload16(const u16* g, u16* l) {
    __builtin_amdgcn_global_load_lds(
        (const __attribute__((address_space(1))) uint32_t*)g,
        (__attribute__((address_space(3))) uint32_t*)l, 16, 0, 0);
}

__global__ void f2b_kernel(const float* __restrict__ in, u16* __restrict__ out, int n) {
    int i = blockIdx.x * 256 + threadIdx.x;
    if (i < n) out[i] = f2b(in[i]);
}
__global__ void copy_f32(const float* __restrict__ in, float* __restrict__ out, int n) {
    int i = blockIdx.x * 256 + threadIdx.x;
    if (i < n) out[i] = in[i];
}

// ---- bias builder ------------------------------------------------------------
__global__ void build_bias(float* __restrict__ dst,
                           const float* p0, int n0, const float* p1, int n1,
                           const float* p2, int n2) {
    int i = blockIdx.x * 256 + threadIdx.x;
    int total = n0 + n1 + n2;
    if (i >= total) return;
    const float* p; int j;
    if (i < n0)           { p = p0; j = i; }
    else if (i < n0 + n1) { p = p1; j = i - n0; }
    else                  { p = p2; j = i - n0 - n1; }
    dst[i] = p ? p[j] : 0.f;
}

// ---- block reductions ---------------------------------------------------------
__device__ __forceinline__ float block_sum(float v, float* red) {
    #pragma unroll
    for (int o = 32; o > 0; o >>= 1) v += __shfl_down(v, o, 64);
    int w = threadIdx.x >> 6, l = threadIdx.x & 63;
    __syncthreads();
    if (l == 0) red[w] = v;
    __syncthreads();
    return red[0] + red[1] + red[2] + red[3];
}

// ---- LayerNorm over C=768 ------------------------------------------------------
__global__ __launch_bounds__(256) void ln_kernel(
    const float* __restrict__ x, const float* __restrict__ g,
    const float* __restrict__ bta, u16* __restrict__ y) {
    const int r = blockIdx.x;
    const int t = threadIdx.x;
    const float* xr = x + (size_t)r * 768;
    float v0 = xr[t], v1 = xr[t + 256], v2 = xr[t + 512];
    __shared__ float red[4];
    float mean = block_sum(v0 + v1 + v2, red) * (1.0f / 768.0f);
    float d0 = v0 - mean, d1 = v1 - mean, d2 = v2 - mean;
    float var = block_sum(d0 * d0 + d1 * d1 + d2 * d2, red) * (1.0f / 768.0f);
    float rs = rsqrtf(var + 1e-5f);
    u16* yr = y + (size_t)r * 768;
    yr[t]       = f2b(d0 * rs * g[t]       + bta[t]);
    yr[t + 256] = f2b(d1 * rs * g[t + 256] + bta[t + 256]);
    yr[t + 512] = f2b(d2 * rs * g[t + 512] + bta[t + 512]);
}

// ---- V transpose: vt[(inst*64+d)*Nkp + kv] = V[kv][d], zero-padded to Nkp ----
__global__ __launch_bounds__(256) void transpose_v(
    const u16* __restrict__ vp, u16* __restrict__ vt, int Nk, int Nkp,
    long long vA, long long vJ) {
    const int inst = blockIdx.y;
    const int a = inst / 12, h = inst % 12;
    const int t0 = blockIdx.x * 64;
    const int tid = threadIdx.x;
    __shared__ u16 T[64][72];
    const int kvl = tid >> 2, dseg = (tid & 3) * 16;
    u16x8 v0 = {}, v1 = {};
    if (t0 + kvl < Nk) {
        const u16* src = vp + a * vA + (long long)(t0 + kvl) * vJ + h * 64 + dseg;
        v0 = *(const u16x8*)src;
        v1 = *(const u16x8*)(src + 8);
    }
    *(u16x8*)&T[kvl][dseg]     = v0;
    *(u16x8*)&T[kvl][dseg + 8] = v1;
    __syncthreads();
    const int dl = tid >> 2, kseg = (tid & 3) * 16;
    u16x8 w0, w1;
    #pragma unroll
    for (int j = 0; j < 8; j++) w0[j] = T[kseg + j][dl];
    #pragma unroll
    for (int j = 0; j < 8; j++) w1[j] = T[kseg + 8 + j][dl];
    u16* orow = vt + ((size_t)inst * 64 + dl) * Nkp + t0 + kseg;
    *(u16x8*)orow = w0;
    *(u16x8*)(orow + 8) = w1;
}

// ---- MFMA GEMM: C[M,N] = A[M,K](bf16) @ W[N,K](bf16)^T + bias[N] --------------
// MODE 0: store bf16.  1: Cf += v.  2: QuickGELU->bf16.  3: exact GELU->bf16.
// MODE 4: Cf += v AND Cb = f2b(new Cf).
template <int MODE>
__global__ __launch_bounds__(256) void gemm_mfma(
    const u16* __restrict__ A, const u16* __restrict__ W,
    const float* __restrict__ bias, u16* __restrict__ Cb,
    float* __restrict__ Cf, int M, int N, int K) {
    __shared__ u16 As[128][32];
    __shared__ u16 Bs[128][32];
    const int tid = threadIdx.x;
    const int lane = tid & 63;
    const int wid = tid >> 6;
    const int wr = (wid >> 1) * 64, wc = (wid & 1) * 64;
    const int m0 = blockIdx.x * 128, n0 = blockIdx.y * 128;
    const int lr = lane >> 2, lc = (lane & 3) * 8;
    const int fr = lane & 15, fk = (lane >> 4) * 8;
    const int base_row = wid * 32;
    f32x4 acc[4][4] = {};
    for (int k0 = 0; k0 < K; k0 += 32) {
        #pragma unroll
        for (int j = 0; j < 2; j++) {
            int rowa = m0 + base_row + j * 16 + lr;
            rowa = rowa < M ? rowa : M - 1;        // clamp (values unused)
            gload16(A + (size_t)rowa * K + k0 + lc, &As[base_row + j * 16][0]);
            gload16(W + (size_t)(n0 + base_row + j * 16 + lr) * K + k0 + lc,
                    &Bs[base_row + j * 16][0]);
        }
        __syncthreads();
        bf16x8 a[4], b[4];
        #pragma unroll
        for (int i = 0; i < 4; i++) a[i] = *(const bf16x8*)&As[wr + i * 16 + fr][fk];
        #pragma unroll
        for (int j = 0; j < 4; j++) b[j] = *(const bf16x8*)&Bs[wc + j * 16 + fr][fk];
        #pragma unroll
        for (int i = 0; i < 4; i++)
            #pragma unroll
            for (int j = 0; j < 4; j++)
                acc[i][j] = __builtin_amdgcn_mfma_f32_16x16x32_bf16(a[i], b[j], acc[i][j], 0, 0, 0);
        __syncthreads();
    }
    const int er = (lane >> 4) * 4;
    #pragma unroll
    for (int i = 0; i < 4; i++) {
        #pragma unroll
        for (int reg = 0; reg < 4; reg++) {
            int r = m0 + wr + i * 16 + er + reg;
            if (r >= M) continue;
            #pragma unroll
            for (int j = 0; j < 4; j++) {
                int c = n0 + wc + j * 16 + fr;
                float v = acc[i][j][reg] + bias[c];
                size_t idx = (size_t)r * N + c;
                if (MODE == 1) {
                    Cf[idx] += v;
                } else if (MODE == 4) {
                    float nv = Cf[idx] + v;
                    Cf[idx] = nv;
                    Cb[idx] = f2b(nv);
                } else {
                    if (MODE == 2) v = v / (1.0f + expf(-1.702f * v));
                    if (MODE == 3) v = 0.5f * v * (1.0f + erff(v * 0.70710678118654752f));
                    Cb[idx] = f2b(v);
                }
            }
        }
    }
}

// ---- MFMA flash attention v4 -------------------------------------------------
// Swapped QK^T (lane q = fr), KV tiles 64. K and pre-transposed V staged via
// global_load_lds into linear [64][64] LDS with XOR-swizzled SOURCE cols
// (col ^= (row&7)<<3); all reads apply the same XOR -> 2-way (free) banks.
// Softmax in exp2 domain (Q pre-scaled by 0.125*log2e) with defer-max THR=8.
__global__ __launch_bounds__(256) void flash_attn(
    const u16* __restrict__ qp, const u16* __restrict__ kp,
    const u16* __restrict__ vt, u16* __restrict__ op,
    int Nq, int Nk, int Nkp,
    long long qA, long long qI, long long kA, long long kJ,
    long long oA, long long oI) {
    const int inst = blockIdx.y;
    const int a = inst / 12, h = inst % 12;
    const int tid = threadIdx.x, lane = tid & 63, w = tid >> 6;
    const int fr = lane & 15, g = lane >> 4, fk = g * 8;
    const int f3s = (fr & 7) << 3;                  // read-side XOR (u16 units)
    __shared__ u16 Ks[64][64];
    __shared__ u16 Vs[64][64];                       // logical [d][kv]
    __shared__ u16 Ps[4][16][64];                    // logical [q][kv], swizzled
    const u16* qb = qp + a * qA + h * 64;
    const u16* kb = kp + a * kA + h * 64;
    const u16* vtb = vt + (size_t)inst * 64 * Nkp;
    const int q0 = blockIdx.x * 64 + w * 16;

    // Q fragments, pre-scaled by 0.125*log2(e) (softmax in exp2 domain)
    bf16x8 qf[2];
    {
        u16x8 raw0 = {}, raw1 = {};
        int qr = q0 + fr;
        if (qr < Nq) {
            const u16* qrp = qb + (long long)qr * qI;
            raw0 = *(const u16x8*)(qrp + fk);
            raw1 = *(const u16x8*)(qrp + 32 + fk);
        }
        const float QS = 0.125f * 1.44269504088896340736f;
        u16x8 s0, s1;
        #pragma unroll
        for (int e = 0; e < 8; e++) {
            s0[e] = f2b(b2f(raw0[e]) * QS);
            s1[e] = f2b(b2f(raw1[e]) * QS);
        }
        qf[0] = *(bf16x8*)&s0;
        qf[1] = *(bf16x8*)&s1;
    }
    float mrun = -1e30f, lrun = 0.f;
    f32x4 o[4] = {};

    // staging geometry: call c covers rows c*32..c*32+31; lane l fills LDS
    // bytes (c*4096 + w*1024 + l*16); row = c*32 + w*8 + (l>>3); physical col
    // (u16) = (l&7)*8 ; logical col = phys ^ ((row&7)<<3).
    const int l = lane;
    const int srow = w * 8 + (l >> 3);               // +c*32
    const int sdcol = ((l & 7) * 8) ^ (((l >> 3) & 7) << 3);

    for (int t0 = 0; t0 < Nk; t0 += 64) {
        #pragma unroll
        for (int c = 0; c < 2; c++) {
            int row = c * 32 + srow;
            int kr = t0 + row; if (kr >= Nk) kr = Nk - 1;     // masked later
            gload16(kb + (long long)kr * kJ + sdcol, &Ks[0][0] + c * 2048 + w * 512);
            gload16(vtb + (size_t)row * Nkp + t0 + sdcol, &Vs[0][0] + c * 2048 + w * 512);
        }
        __syncthreads();

        // ---- S^T = K Qs^T : s[hh][r] = S[q=fr][kv = t0 + hh*16 + 4g + r] ----
        f32x4 s[4] = {};
        #pragma unroll
        for (int hh = 0; hh < 4; hh++) {
            bf16x8 k0f = *(const bf16x8*)&Ks[hh * 16 + fr][fk ^ f3s];
            bf16x8 k1f = *(const bf16x8*)&Ks[hh * 16 + fr][(32 + fk) ^ f3s];
            s[hh] = __builtin_amdgcn_mfma_f32_16x16x32_bf16(k0f, qf[0], s[hh], 0, 0, 0);
            s[hh] = __builtin_amdgcn_mfma_f32_16x16x32_bf16(k1f, qf[1], s[hh], 0, 0, 0);
        }
        // ---- online softmax (exp2 domain), defer-max THR=8 -------------------
        float lmax = -1e30f;
        if (t0 + 64 <= Nk) {
            #pragma unroll
            for (int hh = 0; hh < 4; hh++)
                #pragma unroll
                for (int r = 0; r < 4; r++) lmax = fmaxf(lmax, s[hh][r]);
        } else {
            #pragma unroll
            for (int hh = 0; hh < 4; hh++)
                #pragma unroll
                for (int r = 0; r < 4; r++) {
                    if (t0 + hh * 16 + 4 * g + r >= Nk) s[hh][r] = -1e30f;
                    lmax = fmaxf(lmax, s[hh][r]);
                }
        }
        lmax = fmaxf(lmax, __shfl_xor(lmax, 16, 64));
        lmax = fmaxf(lmax, __shfl_xor(lmax, 32, 64));
        if (!__all(lmax <= mrun + 8.0f)) {            // rescale (rare)
            float mn = fmaxf(mrun, lmax);
            float sf = exp2f(mrun - mn);
            mrun = mn;
            lrun *= sf;
            float sfo[4];
            #pragma unroll
            for (int r = 0; r < 4; r++) sfo[r] = __shfl(sf, g * 4 + r, 64);
            #pragma unroll
            for (int dt = 0; dt < 4; dt++)
                #pragma unroll
                for (int r = 0; r < 4; r++) o[dt][r] *= sfo[r];
        }
        float p[4][4];
        float ps = 0.f;
        #pragma unroll
        for (int hh = 0; hh < 4; hh++)
            #pragma unroll
            for (int r = 0; r < 4; r++) {
                p[hh][r] = exp2f(s[hh][r] - mrun);
                ps += p[hh][r];
            }
        ps += __shfl_xor(ps, 16, 64);
        ps += __shfl_xor(ps, 32, 64);
        lrun += ps;
        // ---- P -> LDS (b64, swizzled cols) -----------------------------------
        #pragma unroll
        for (int hh = 0; hh < 4; hh++) {
            u16x4 pk;
            #pragma unroll
            for (int r = 0; r < 4; r++) pk[r] = f2b_trunc(p[hh][r]);
            *(u16x4*)&Ps[w][fr][(hh * 16 + g * 4) ^ f3s] = pk;
        }
        // ---- PV (same-wave LDS RAW ordered by compiler waitcnts) -------------
        bf16x8 pa0 = *(const bf16x8*)&Ps[w][fr][fk ^ f3s];
        bf16x8 pa1 = *(const bf16x8*)&Ps[w][fr][(32 + fk) ^ f3s];
        #pragma unroll
        for (int dt = 0; dt < 4; dt++) {
            bf16x8 vf0 = *(const bf16x8*)&Vs[dt * 16 + fr][fk ^ f3s];
            bf16x8 vf1 = *(const bf16x8*)&Vs[dt * 16 + fr][(32 + fk) ^ f3s];
            o[dt] = __builtin_amdgcn_mfma_f32_16x16x32_bf16(pa0, vf0, o[dt], 0, 0, 0);
            o[dt] = __builtin_amdgcn_mfma_f32_16x16x32_bf16(pa1, vf1, o[dt], 0, 0, 0);
        }
        __syncthreads();
    }
    // ---- epilogue: O[q][d] = o/l --------------------------------------------
    float rcp = 1.0f / lrun;
    #pragma unroll
    for (int r = 0; r < 4; r++) {
        float rr = __shfl(rcp, g * 4 + r, 64);
        int q = q0 + g * 4 + r;
        if (q >= Nq) continue;
        u16* orow = op + a * oA + (long long)q * oI + h * 64;
        #pragma unroll
        for (int dt = 0; dt < 4; dt++)
            orow[dt * 16 + fr] = f2b(o[dt][r] * rr);
    }
}

// ---------------------------------------------------------------------------
extern "C" void kernel_launch(void* const* d_in, const int* in_sizes, int n_in,
                              void* d_out, int out_size, void* d_ws, size_t ws_size,
                              hipStream_t stream) {
    const int B = 8, sN = 196, tN = 1568;
    const int Ms = B * sN;            // 1568
    const int Mt = B * tN;            // 12544
    const int n_sf = Ms * 768;        // 1204224
    const int n_tf = Mt * 768;        // 9633792
    (void)n_in; (void)out_size; (void)ws_size;

    const bool dict_order = (in_sizes[0] == n_sf);
    auto IN = [&](int di, int ai) -> const float* {
        return (const float*)d_in[dict_order ? di : ai];
    };
    const float* in_sx      = IN(0, 35);
    const float* in_tx      = IN(1, 42);
    const float* ln1s_g     = IN(2, 14);
    const float* ln1s_b     = IN(3, 13);
    const float* mha_w      = IN(4, 28);
    const float* mha_b      = IN(5, 25);
    const float* mha_ow     = IN(6, 27);
    const float* mha_ob     = IN(7, 26);
    const float* ln1t_g     = IN(8, 16);
    const float* ln1t_b     = IN(9, 15);
    const float* attn_qkv_w = IN(10, 3);
    const float* attn_q_b   = IN(11, 2);
    const float* attn_v_b   = IN(12, 4);
    const float* attn_pw    = IN(13, 1);
    const float* attn_pb    = IN(14, 0);
    const float* lnt2s_g    = IN(15, 24);
    const float* lnt2s_b    = IN(16, 23);
    const float* t2s_qw     = IN(17, 41);
    const float* t2s_qb     = IN(18, 40);
    const float* t2s_kvw    = IN(19, 37);
    const float* t2s_kvb    = IN(20, 36);
    const float* t2s_pw     = IN(21, 39);
    const float* t2s_pb     = IN(22, 38);
    const float* lns2t_g    = IN(23, 22);
    const float* lns2t_b    = IN(24, 21);
    const float* s2t_qw     = IN(25, 34);
    const float* s2t_qb     = IN(26, 33);
    const float* s2t_kvw    = IN(27, 30);
    const float* s2t_kvb    = IN(28, 29);
    const float* s2t_pw     = IN(29, 32);
    const float* s2t_pb     = IN(30, 31);
    const float* ln2s_g     = IN(31, 18);
    const float* ln2s_b     = IN(32, 17);
    const float* cfc_w      = IN(33, 6);
    const float* cfc_b      = IN(34, 5);
    const float* cproj_w    = IN(35, 8);
    const float* cproj_b    = IN(36, 7);
    const float* ln2t_g     = IN(37, 20);
    const float* ln2t_b     = IN(38, 19);
    const float* fc1_w      = IN(39, 10);
    const float* fc1_b      = IN(40, 9);
    const float* fc2_w      = IN(41, 12);
    const float* fc2_b      = IN(42, 11);

    // ---- residual streams live in d_out (f32) -------------------------------
    float* s_f = (float*)d_out;
    float* t_f = (float*)d_out + n_sf;

    // ---- workspace (~156 MB) ------------------------------------------------
    char* ws = (char*)d_ws;
    size_t off = 0;
    auto take = [&](size_t bytes) { size_t o = off; off += (bytes + 255) & ~(size_t)255; return o; };
    float* biasf = (float*)(ws + take(3072 * 4));
    u16*   yb    = (u16*)(ws + take((size_t)Mt * 768 * 2));   // 19.3 MB
    u16*   bufA  = (u16*)(ws + take((size_t)Mt * 2304 * 2));  // 57.8 MB
    u16*   bufB  = (u16*)(ws + take((size_t)Mt * 768 * 2));   // 19.3 MB
    u16*   sxb   = (u16*)(ws + take((size_t)Ms * 768 * 2));   // 2.4 MB
    u16*   vtb   = (u16*)(ws + take((size_t)2352 * 64 * 64 * 2)); // 19.3 MB (max use)
    auto wtake = [&](size_t nelem) { return (u16*)(ws + take(nelem * 2)); };
    u16 *W_mha   = wtake(2304 * 768), *W_mhao  = wtake(768 * 768);
    u16 *W_qkv   = wtake(2304 * 768), *W_attnp = wtake(768 * 768);
    u16 *W_t2sq  = wtake(768 * 768),  *W_t2skv = wtake(1536 * 768), *W_t2sp = wtake(768 * 768);
    u16 *W_s2tq  = wtake(768 * 768),  *W_s2tkv = wtake(1536 * 768), *W_s2tp = wtake(768 * 768);
    u16 *W_cfc   = wtake(3072 * 768), *W_cproj = wtake(768 * 3072);
    u16 *W_fc1   = wtake(3072 * 768), *W_fc2   = wtake(768 * 3072);

    auto cdiv = [](int a, int b) { return (a + b - 1) / b; };
    #define BB(b0, c0, b1, c1, b2, c2) \
        build_bias<<<cdiv((c0) + (c1) + (c2), 256), 256, 0, stream>>>(biasf, b0, c0, b1, c1, b2, c2)
    auto CW = [&](const float* src, u16* dst, int n) {
        f2b_kernel<<<cdiv(n, 256), 256, 0, stream>>>(src, dst, n);
    };
    // weights -> bf16 pool
    CW(mha_w, W_mha, 2304 * 768);      CW(mha_ow, W_mhao, 768 * 768);
    CW(attn_qkv_w, W_qkv, 2304 * 768); CW(attn_pw, W_attnp, 768 * 768);
    CW(t2s_qw, W_t2sq, 768 * 768);     CW(t2s_kvw, W_t2skv, 1536 * 768);
    CW(t2s_pw, W_t2sp, 768 * 768);     CW(s2t_qw, W_s2tq, 768 * 768);
    CW(s2t_kvw, W_s2tkv, 1536 * 768);  CW(s2t_pw, W_s2tp, 768 * 768);
    CW(cfc_w, W_cfc, 3072 * 768);      CW(cproj_w, W_cproj, 768 * 3072);
    CW(fc1_w, W_fc1, 3072 * 768);      CW(fc2_w, W_fc2, 768 * 3072);

    // residual streams <- inputs
    copy_f32<<<cdiv(n_sf, 256), 256, 0, stream>>>(in_sx, s_f, n_sf);
    copy_f32<<<cdiv(n_tf, 256), 256, 0, stream>>>(in_tx, t_f, n_tf);

    // ---- stage 1: clip self-attention (attends over the batch axis) ---------
    ln_kernel<<<Ms, 256, 0, stream>>>(s_f, ln1s_g, ln1s_b, yb);
    BB(mha_b, 2304, (const float*)0, 0, (const float*)0, 0);
    gemm_mfma<0><<<dim3(cdiv(Ms, 128), 18), 256, 0, stream>>>(yb, W_mha, biasf, bufA, (float*)0, Ms, 2304, 768);
    transpose_v<<<dim3(1, sN * 12), 256, 0, stream>>>(bufA + 1536, vtb, 8, 64, 2304LL, (long long)sN * 2304);
    flash_attn<<<dim3(1, sN * 12), 256, 0, stream>>>(
        bufA, bufA + 768, vtb, bufB, /*Nq=*/8, /*Nk=*/8, /*Nkp=*/64,
        /*qA=*/2304LL, /*qI=*/(long long)sN * 2304,
        /*kA=*/2304LL, /*kJ=*/(long long)sN * 2304,
        /*oA=*/768LL,  /*oI=*/(long long)sN * 768);
    BB(mha_ob, 768, (const float*)0, 0, (const float*)0, 0);
    gemm_mfma<1><<<dim3(cdiv(Ms, 128), 6), 256, 0, stream>>>(bufB, W_mhao, biasf, (u16*)0, s_f, Ms, 768, 768);

    // ---- stage 2: video self-attention --------------------------------------
    ln_kernel<<<Mt, 256, 0, stream>>>(t_f, ln1t_g, ln1t_b, yb);
    BB(attn_q_b, 768, (const float*)0, 768, attn_v_b, 768);  // [q_b, 0, v_b]
    gemm_mfma<0><<<dim3(cdiv(Mt, 128), 18), 256, 0, stream>>>(yb, W_qkv, biasf, bufA, (float*)0, Mt, 2304, 768);
    transpose_v<<<dim3(25, B * 12), 256, 0, stream>>>(bufA + 1536, vtb, tN, 1600, (long long)tN * 2304, 2304LL);
    flash_attn<<<dim3(cdiv(tN, 64), B * 12), 256, 0, stream>>>(
        bufA, bufA + 768, vtb, bufB, /*Nq=*/tN, /*Nk=*/tN, /*Nkp=*/1600,
        (long long)tN * 2304, 2304LL,
        (long long)tN * 2304, 2304LL,
        (long long)tN * 768, 768LL);
    BB(attn_pb, 768, (const float*)0, 0, (const float*)0, 0);
    gemm_mfma<4><<<dim3(cdiv(Mt, 128), 6), 256, 0, stream>>>(bufB, W_attnp, biasf, yb, t_f, Mt, 768, 768);

    // ---- stage 3: T2S cross (q from LN(s_x), kv from updated t_x) -----------
    BB((const float*)0, 768, t2s_kvb, 768, (const float*)0, 0);       // [0, kvb]
    gemm_mfma<0><<<dim3(cdiv(Mt, 128), 12), 256, 0, stream>>>(yb, W_t2skv, biasf, bufA, (float*)0, Mt, 1536, 768);
    transpose_v<<<dim3(25, B * 12), 256, 0, stream>>>(bufA + 768, vtb, tN, 1600, (long long)tN * 1536, 1536LL);
    ln_kernel<<<Ms, 256, 0, stream>>>(s_f, lnt2s_g, lnt2s_b, yb);
    BB(t2s_qb, 768, (const float*)0, 0, (const float*)0, 0);
    u16* q3 = bufB;
    u16* o3 = bufB + (size_t)Ms * 768;
    gemm_mfma<0><<<dim3(cdiv(Ms, 128), 6), 256, 0, stream>>>(yb, W_t2sq, biasf, q3, (float*)0, Ms, 768, 768);
    flash_attn<<<dim3(cdiv(sN, 64), B * 12), 256, 0, stream>>>(
        q3, bufA, vtb, o3, /*Nq=*/sN, /*Nk=*/tN, /*Nkp=*/1600,
        (long long)sN * 768, 768LL,
        (long long)tN * 1536, 1536LL,
        (long long)sN * 768, 768LL);
    BB(t2s_pb, 768, (const float*)0, 0, (const float*)0, 0);
    gemm_mfma<4><<<dim3(cdiv(Ms, 128), 6), 256, 0, stream>>>(o3, W_t2sp, biasf, sxb, s_f, Ms, 768, 768);

    // ---- stage 4: S2T cross (q from LN(t_x), kv from updated s_x) -----------
    ln_kernel<<<Mt, 256, 0, stream>>>(t_f, lns2t_g, lns2t_b, yb);
    BB(s2t_qb, 768, (const float*)0, 0, (const float*)0, 0);
    gemm_mfma<0><<<dim3(cdiv(Mt, 128), 6), 256, 0, stream>>>(yb, W_s2tq, biasf, bufB, (float*)0, Mt, 768, 768);
    BB((const float*)0, 768, s2t_kvb, 768, (const float*)0, 0);
    gemm_mfma<0><<<dim3(cdiv(Ms, 128), 12), 256, 0, stream>>>(sxb, W_s2tkv, biasf, bufA, (float*)0, Ms, 1536, 768);
    transpose_v<<<dim3(4, B * 12), 256, 0, stream>>>(bufA + 768, vtb, sN, 256, (long long)sN * 1536, 1536LL);
    flash_attn<<<dim3(cdiv(tN, 64), B * 12), 256, 0, stream>>>(
        bufB, bufA, vtb, yb, /*Nq=*/tN, /*Nk=*/sN, /*Nkp=*/256,
        (long long)tN * 768, 768LL,
        (long long)sN * 1536, 1536LL,
        (long long)tN * 768, 768LL);
    BB(s2t_pb, 768, (const float*)0, 0, (const float*)0, 0);
    gemm_mfma<1><<<dim3(cdiv(Mt, 128), 6), 256, 0, stream>>>(yb, W_s2tp, biasf, (u16*)0, t_f, Mt, 768, 768);

    // ---- stage 5: clip MLP (QuickGELU) --------------------------------------
    ln_kernel<<<Ms, 256, 0, stream>>>(s_f, ln2s_g, ln2s_b, yb);
    BB(cfc_b, 3072, (const float*)0, 0, (const float*)0, 0);
    gemm_mfma<2><<<dim3(cdiv(Ms, 128), 24), 256, 0, stream>>>(yb, W_cfc, biasf, bufA, (float*)0, Ms, 3072, 768);
    BB(cproj_b, 768, (const float*)0, 0, (const float*)0, 0);
    gemm_mfma<1><<<dim3(cdiv(Ms, 128), 6), 256, 0, stream>>>(bufA, W_cproj, biasf, (u16*)0, s_f, Ms, 768, 3072);

    // ---- stage 6: video MLP (exact GELU), two row-halves --------------------
    ln_kernel<<<Mt, 256, 0, stream>>>(t_f, ln2t_g, ln2t_b, yb);
    for (int c = 0; c < 2; c++) {
        int r0 = c * (Mt / 2), Mc = Mt / 2;
        BB(fc1_b, 3072, (const float*)0, 0, (const float*)0, 0);
        gemm_mfma<3><<<dim3(cdiv(Mc, 128), 24), 256, 0, stream>>>(
            yb + (size_t)r0 * 768, W_fc1, biasf, bufA, (float*)0, Mc, 3072, 768);
        BB(fc2_b, 768, (const float*)0, 0, (const float*)0, 0);
        gemm_mfma<1><<<dim3(cdiv(Mc, 128), 6), 256, 0, stream>>>(
            bufA, W_fc2, biasf, (u16*)0, t_f + (size_t)r0 * 768, Mc, 768, 3072);
    }
    #undef BB
}

// Round 10
// 1089.103 us; speedup vs baseline: 20.3482x; 1.1254x over previous
//
#include <hip/hip_runtime.h>
#include <stdint.h>

// ---------------------------------------------------------------------------
// Block_6554120094246: dual-stream transformer block (CLIP + video streams).
// f32 in/out. Residual streams in d_out. bf16 intermediates + MFMA GEMM
// (BMx128x64 twin-slab, global_load_lds, BM=64 for s-stream fill) + MFMA
// flash attention v4 (swapped QK^T, swizzled gload_lds staging, defer-max,
// exp2 softmax). Single bias-pool build. ws ~156 MB.
// ---------------------------------------------------------------------------

typedef uint16_t u16;
typedef uint16_t u16x8 __attribute__((ext_vector_type(8)));
typedef uint16_t u16x4 __attribute__((ext_vector_type(4)));
typedef short bf16x8 __attribute__((ext_vector_type(8)));
typedef float f32x4 __attribute__((ext_vector_type(4)));

__device__ __forceinline__ float b2f(u16 u) {
    union { float f; uint32_t i; } x;
    x.i = ((uint32_t)u) << 16;
    return x.f;
}
__device__ __forceinline__ u16 f2b(float f) {
    union { float f; uint32_t i; } x;
    x.f = f;
    uint32_t i = x.i;
    uint32_t r = (i + 0x7FFFu + ((i >> 16) & 1u)) >> 16;  // RNE
    return (u16)r;
}
__device__ __forceinline__ u16 f2b_trunc(float f) {      // for P in [0,256]
    union { float f; uint32_t i; } x;
    x.f = f;
    return (u16)(x.i >> 16);
}

// async global->LDS, 16B per lane; LDS dest wave-uniform base (+lane*16B).
__device__ __forceinline__ void gload16(const u16* g, u16* l) {
    __builtin_amdgcn_global_load_lds(
        (const __attribute__((address_space(1))) uint32_t*)g,
        (__attribute__((address_space(3))) uint32_t*)l, 16, 0, 0);
}

__global__ void f2b_kernel(const float* __restrict__ in, u16* __restrict__ out, int n) {
    int i = blockIdx.x * 256 + threadIdx.x;
    if (i < n) out[i] = f2b(in[i]);
}
__global__ void copy_f32(const float* __restrict__ in, float* __restrict__ out, int n) {
    int i = blockIdx.x * 256 + threadIdx.x;
    if (i < n) out[i] = in[i];
}

// ---- bias pool (single launch). Layout (f32 offsets):
// 0 mha_b[2304] | 2304 [attn_q_b,0,attn_v_b] | 4608 mha_ob | 5376 attn_pb |
// 6144 [0,t2s_kvb] | 7680 t2s_qb | 8448 t2s_pb | 9216 s2t_qb |
// 9984 [0,s2t_kvb] | 11520 s2t_pb | 12288 cfc_b[3072] | 15360 cproj_b |
// 16128 fc1_b[3072] | 19200 fc2_b | total 19968
__global__ void build_bias_pool(float* __restrict__ dst,
    const float* mha_b, const float* attn_q_b, const float* attn_v_b,
    const float* mha_ob, const float* attn_pb, const float* t2s_kvb,
    const float* t2s_qb, const float* t2s_pb, const float* s2t_qb,
    const float* s2t_kvb, const float* s2t_pb, const float* cfc_b,
    const float* cproj_b, const float* fc1_b, const float* fc2_b) {
    int i = blockIdx.x * 256 + threadIdx.x;
    float v = 0.f;
    if (i < 2304) v = mha_b[i];
    else if (i < 4608) { int j = i - 2304; v = (j < 768) ? attn_q_b[j] : (j < 1536 ? 0.f : attn_v_b[j - 1536]); }
    else if (i < 5376) v = mha_ob[i - 4608];
    else if (i < 6144) v = attn_pb[i - 5376];
    else if (i < 7680) { int j = i - 6144; v = (j < 768) ? 0.f : t2s_kvb[j - 768]; }
    else if (i < 8448) v = t2s_qb[i - 7680];
    else if (i < 9216) v = t2s_pb[i - 8448];
    else if (i < 9984) v = s2t_qb[i - 9216];
    else if (i < 11520) { int j = i - 9984; v = (j < 768) ? 0.f : s2t_kvb[j - 768]; }
    else if (i < 12288) v = s2t_pb[i - 11520];
    else if (i < 15360) v = cfc_b[i - 12288];
    else if (i < 16128) v = cproj_b[i - 15360];
    else if (i < 19200) v = fc1_b[i - 16128];
    else if (i < 19968) v = fc2_b[i - 19200];
    else return;
    dst[i] = v;
}

// ---- block reductions ---------------------------------------------------------
__device__ __forceinline__ float block_sum(float v, float* red) {
    #pragma unroll
    for (int o = 32; o > 0; o >>= 1) v += __shfl_down(v, o, 64);
    int w = threadIdx.x >> 6, l = threadIdx.x & 63;
    __syncthreads();
    if (l == 0) red[w] = v;
    __syncthreads();
    return red[0] + red[1] + red[2] + red[3];
}

// ---- LayerNorm over C=768 ------------------------------------------------------
__global__ __launch_bounds__(256) void ln_kernel(
    const float* __restrict__ x, const float* __restrict__ g,
    const float* __restrict__ bta, u16* __restrict__ y) {
    const int r = blockIdx.x;
    const int t = threadIdx.x;
    const float* xr = x + (size_t)r * 768;
    float v0 = xr[t], v1 = xr[t + 256], v2 = xr[t + 512];
    __shared__ float red[4];
    float mean = block_sum(v0 + v1 + v2, red) * (1.0f / 768.0f);
    float d0 = v0 - mean, d1 = v1 - mean, d2 = v2 - mean;
    float var = block_sum(d0 * d0 + d1 * d1 + d2 * d2, red) * (1.0f / 768.0f);
    float rs = rsqrtf(var + 1e-5f);
    u16* yr = y + (size_t)r * 768;
    yr[t]       = f2b(d0 * rs * g[t]       + bta[t]);
    yr[t + 256] = f2b(d1 * rs * g[t + 256] + bta[t + 256]);
    yr[t + 512] = f2b(d2 * rs * g[t + 512] + bta[t + 512]);
}

// ---- V transpose: vt[(inst*64+d)*Nkp + kv] = V[kv][d], zero-padded to Nkp ----
__global__ __launch_bounds__(256) void transpose_v(
    const u16* __restrict__ vp, u16* __restrict__ vt, int Nk, int Nkp,
    long long vA, long long vJ) {
    const int inst = blockIdx.y;
    const int a = inst / 12, h = inst % 12;
    const int t0 = blockIdx.x * 64;
    const int tid = threadIdx.x;
    __shared__ u16 T[64][72];
    const int kvl = tid >> 2, dseg = (tid & 3) * 16;
    u16x8 v0 = {}, v1 = {};
    if (t0 + kvl < Nk) {
        const u16* src = vp + a * vA + (long long)(t0 + kvl) * vJ + h * 64 + dseg;
        v0 = *(const u16x8*)src;
        v1 = *(const u16x8*)(src + 8);
    }
    *(u16x8*)&T[kvl][dseg]     = v0;
    *(u16x8*)&T[kvl][dseg + 8] = v1;
    __syncthreads();
    const int dl = tid >> 2, kseg = (tid & 3) * 16;
    u16x8 w0, w1;
    #pragma unroll
    for (int j = 0; j < 8; j++) w0[j] = T[kseg + j][dl];
    #pragma unroll
    for (int j = 0; j < 8; j++) w1[j] = T[kseg + 8 + j][dl];
    u16* orow = vt + ((size_t)inst * 64 + dl) * Nkp + t0 + kseg;
    *(u16x8*)orow = w0;
    *(u16x8*)(orow + 8) = w1;
}

// ---- MFMA GEMM: C[M,N] = A[M,K](bf16) @ W[N,K](bf16)^T + bias[N] --------------
// BM x 128 x 64 tile (twin 32-wide K slabs keep the conflict-free [.][32]
// bank geometry; one barrier pair per 64-K). BM=128 (t-stream) or 64
// (s-stream fill). MODE 0: bf16. 1: Cf += v. 2: QuickGELU. 3: exact GELU.
// MODE 4: Cf += v AND Cb = f2b(new Cf).
template <int MODE, int BM>
__global__ __launch_bounds__(256) void gemm_mfma(
    const u16* __restrict__ A, const u16* __restrict__ W,
    const float* __restrict__ bias, u16* __restrict__ Cb,
    float* __restrict__ Cf, int M, int N, int K) {
    constexpr int MI = BM / 32;              // acc rows per wave / 16
    __shared__ u16 As[2][BM][32];
    __shared__ u16 Bs[2][128][32];
    const int tid = threadIdx.x;
    const int lane = tid & 63;
    const int wid = tid >> 6;
    const int wr = (wid >> 1) * (BM / 2), wc = (wid & 1) * 64;
    const int m0 = blockIdx.x * BM, n0 = blockIdx.y * 128;
    const int lr = lane >> 2, lc = (lane & 3) * 8;   // 16 rows x 32 cols / call
    const int fr = lane & 15, fk = (lane >> 4) * 8;
    const int abase = wid * (BM / 4);
    const int bbase = wid * 32;
    f32x4 acc[MI][4] = {};
    for (int k0 = 0; k0 < K; k0 += 64) {
        #pragma unroll
        for (int s = 0; s < 2; s++) {
            #pragma unroll
            for (int j = 0; j < BM / 64; j++) {
                int rowa = m0 + abase + j * 16 + lr;
                rowa = rowa < M ? rowa : M - 1;      // clamp (values unused)
                gload16(A + (size_t)rowa * K + k0 + s * 32 + lc, &As[s][abase + j * 16][0]);
            }
            #pragma unroll
            for (int j = 0; j < 2; j++) {
                gload16(W + (size_t)(n0 + bbase + j * 16 + lr) * K + k0 + s * 32 + lc,
                        &Bs[s][bbase + j * 16][0]);
            }
        }
        __syncthreads();
        #pragma unroll
        for (int s = 0; s < 2; s++) {
            bf16x8 a[MI], b[4];
            #pragma unroll
            for (int i = 0; i < MI; i++) a[i] = *(const bf16x8*)&As[s][wr + i * 16 + fr][fk];
            #pragma unroll
            for (int j = 0; j < 4; j++) b[j] = *(const bf16x8*)&Bs[s][wc + j * 16 + fr][fk];
            #pragma unroll
            for (int i = 0; i < MI; i++)
                #pragma unroll
                for (int j = 0; j < 4; j++)
                    acc[i][j] = __builtin_amdgcn_mfma_f32_16x16x32_bf16(a[i], b[j], acc[i][j], 0, 0, 0);
        }
        __syncthreads();
    }
    const int er = (lane >> 4) * 4;
    #pragma unroll
    for (int i = 0; i < MI; i++) {
        #pragma unroll
        for (int reg = 0; reg < 4; reg++) {
            int r = m0 + wr + i * 16 + er + reg;
            if (r >= M) continue;
            #pragma unroll
            for (int j = 0; j < 4; j++) {
                int c = n0 + wc + j * 16 + fr;
                float v = acc[i][j][reg] + bias[c];
                size_t idx = (size_t)r * N + c;
                if (MODE == 1) {
                    Cf[idx] += v;
                } else if (MODE == 4) {
                    float nv = Cf[idx] + v;
                    Cf[idx] = nv;
                    Cb[idx] = f2b(nv);
                } else {
                    if (MODE == 2) v = v / (1.0f + expf(-1.702f * v));
                    if (MODE == 3) v = 0.5f * v * (1.0f + erff(v * 0.70710678118654752f));
                    Cb[idx] = f2b(v);
                }
            }
        }
    }
}

// ---- MFMA flash attention v4 -------------------------------------------------
__global__ __launch_bounds__(256) void flash_attn(
    const u16* __restrict__ qp, const u16* __restrict__ kp,
    const u16* __restrict__ vt, u16* __restrict__ op,
    int Nq, int Nk, int Nkp,
    long long qA, long long qI, long long kA, long long kJ,
    long long oA, long long oI) {
    const int inst = blockIdx.y;
    const int a = inst / 12, h = inst % 12;
    const int tid = threadIdx.x, lane = tid & 63, w = tid >> 6;
    const int fr = lane & 15, g = lane >> 4, fk = g * 8;
    const int f3s = (fr & 7) << 3;                  // read-side XOR (u16 units)
    __shared__ u16 Ks[64][64];
    __shared__ u16 Vs[64][64];                       // logical [d][kv]
    __shared__ u16 Ps[4][16][64];                    // logical [q][kv], swizzled
    const u16* qb = qp + a * qA + h * 64;
    const u16* kb = kp + a * kA + h * 64;
    const u16* vtb = vt + (size_t)inst * 64 * Nkp;
    const int q0 = blockIdx.x * 64 + w * 16;

    // Q fragments, pre-scaled by 0.125*log2(e) (softmax in exp2 domain)
    bf16x8 qf[2];
    {
        u16x8 raw0 = {}, raw1 = {};
        int qr = q0 + fr;
        if (qr < Nq) {
            const u16* qrp = qb + (long long)qr * qI;
            raw0 = *(const u16x8*)(qrp + fk);
            raw1 = *(const u16x8*)(qrp + 32 + fk);
        }
        const float QS = 0.125f * 1.44269504088896340736f;
        u16x8 s0, s1;
        #pragma unroll
        for (int e = 0; e < 8; e++) {
            s0[e] = f2b(b2f(raw0[e]) * QS);
            s1[e] = f2b(b2f(raw1[e]) * QS);
        }
        qf[0] = *(bf16x8*)&s0;
        qf[1] = *(bf16x8*)&s1;
    }
    float mrun = -1e30f, lrun = 0.f;
    f32x4 o[4] = {};

    const int l = lane;
    const int srow = w * 8 + (l >> 3);               // +c*32
    const int sdcol = ((l & 7) * 8) ^ (((l >> 3) & 7) << 3);

    for (int t0 = 0; t0 < Nk; t0 += 64) {
        #pragma unroll
        for (int c = 0; c < 2; c++) {
            int row = c * 32 + srow;
            int kr = t0 + row; if (kr >= Nk) kr = Nk - 1;     // masked later
            gload16(kb + (long long)kr * kJ + sdcol, &Ks[0][0] + c * 2048 + w * 512);
            gload16(vtb + (size_t)row * Nkp + t0 + sdcol, &Vs[0][0] + c * 2048 + w * 512);
        }
        __syncthreads();

        // ---- S^T = K Qs^T : s[hh][r] = S[q=fr][kv = t0 + hh*16 + 4g + r] ----
        f32x4 s[4] = {};
        #pragma unroll
        for (int hh = 0; hh < 4; hh++) {
            bf16x8 k0f = *(const bf16x8*)&Ks[hh * 16 + fr][fk ^ f3s];
            bf16x8 k1f = *(const bf16x8*)&Ks[hh * 16 + fr][(32 + fk) ^ f3s];
            s[hh] = __builtin_amdgcn_mfma_f32_16x16x32_bf16(k0f, qf[0], s[hh], 0, 0, 0);
            s[hh] = __builtin_amdgcn_mfma_f32_16x16x32_bf16(k1f, qf[1], s[hh], 0, 0, 0);
        }
        // ---- online softmax (exp2 domain), defer-max THR=8 -------------------
        float lmax = -1e30f;
        if (t0 + 64 <= Nk) {
            #pragma unroll
            for (int hh = 0; hh < 4; hh++)
                #pragma unroll
                for (int r = 0; r < 4; r++) lmax = fmaxf(lmax, s[hh][r]);
        } else {
            #pragma unroll
            for (int hh = 0; hh < 4; hh++)
                #pragma unroll
                for (int r = 0; r < 4; r++) {
                    if (t0 + hh * 16 + 4 * g + r >= Nk) s[hh][r] = -1e30f;
                    lmax = fmaxf(lmax, s[hh][r]);
                }
        }
        lmax = fmaxf(lmax, __shfl_xor(lmax, 16, 64));
        lmax = fmaxf(lmax, __shfl_xor(lmax, 32, 64));
        if (!__all(lmax <= mrun + 8.0f)) {            // rescale (rare)
            float mn = fmaxf(mrun, lmax);
            float sf = exp2f(mrun - mn);
            mrun = mn;
            lrun *= sf;
            float sfo[4];
            #pragma unroll
            for (int r = 0; r < 4; r++) sfo[r] = __shfl(sf, g * 4 + r, 64);
            #pragma unroll
            for (int dt = 0; dt < 4; dt++)
                #pragma unroll
                for (int r = 0; r < 4; r++) o[dt][r] *= sfo[r];
        }
        float p[4][4];
        float ps = 0.f;
        #pragma unroll
        for (int hh = 0; hh < 4; hh++)
            #pragma unroll
            for (int r = 0; r < 4; r++) {
                p[hh][r] = exp2f(s[hh][r] - mrun);
                ps += p[hh][r];
            }
        ps += __shfl_xor(ps, 16, 64);
        ps += __shfl_xor(ps, 32, 64);
        lrun += ps;
        // ---- P -> LDS (b64, swizzled cols) -----------------------------------
        #pragma unroll
        for (int hh = 0; hh < 4; hh++) {
            u16x4 pk;
            #pragma unroll
            for (int r = 0; r < 4; r++) pk[r] = f2b_trunc(p[hh][r]);
            *(u16x4*)&Ps[w][fr][(hh * 16 + g * 4) ^ f3s] = pk;
        }
        // ---- PV --------------------------------------------------------------
        bf16x8 pa0 = *(const bf16x8*)&Ps[w][fr][fk ^ f3s];
        bf16x8 pa1 = *(const bf16x8*)&Ps[w][fr][(32 + fk) ^ f3s];
        #pragma unroll
        for (int dt = 0; dt < 4; dt++) {
            bf16x8 vf0 = *(const bf16x8*)&Vs[dt * 16 + fr][fk ^ f3s];
            bf16x8 vf1 = *(const bf16x8*)&Vs[dt * 16 + fr][(32 + fk) ^ f3s];
            o[dt] = __builtin_amdgcn_mfma_f32_16x16x32_bf16(pa0, vf0, o[dt], 0, 0, 0);
            o[dt] = __builtin_amdgcn_mfma_f32_16x16x32_bf16(pa1, vf1, o[dt], 0, 0, 0);
        }
        __syncthreads();
    }
    // ---- epilogue: O[q][d] = o/l --------------------------------------------
    float rcp = 1.0f / lrun;
    #pragma unroll
    for (int r = 0; r < 4; r++) {
        float rr = __shfl(rcp, g * 4 + r, 64);
        int q = q0 + g * 4 + r;
        if (q >= Nq) continue;
        u16* orow = op + a * oA + (long long)q * oI + h * 64;
        #pragma unroll
        for (int dt = 0; dt < 4; dt++)
            orow[dt * 16 + fr] = f2b(o[dt][r] * rr);
    }
}

// ---------------------------------------------------------------------------
extern "C" void kernel_launch(void* const* d_in, const int* in_sizes, int n_in,
                              void* d_out, int out_size, void* d_ws, size_t ws_size,
                              hipStream_t stream) {
    const int B = 8, sN = 196, tN = 1568;
    const int Ms = B * sN;            // 1568
    const int Mt = B * tN;            // 12544
    const int n_sf = Ms * 768;        // 1204224
    const int n_tf = Mt * 768;        // 9633792
    (void)n_in; (void)out_size; (void)ws_size;

    const bool dict_order = (in_sizes[0] == n_sf);
    auto IN = [&](int di, int ai) -> const float* {
        return (const float*)d_in[dict_order ? di : ai];
    };
    const float* in_sx      = IN(0, 35);
    const float* in_tx      = IN(1, 42);
    const float* ln1s_g     = IN(2, 14);
    const float* ln1s_b     = IN(3, 13);
    const float* mha_w      = IN(4, 28);
    const float* mha_b      = IN(5, 25);
    const float* mha_ow     = IN(6, 27);
    const float* mha_ob     = IN(7, 26);
    const float* ln1t_g     = IN(8, 16);
    const float* ln1t_b     = IN(9, 15);
    const float* attn_qkv_w = IN(10, 3);
    const float* attn_q_b   = IN(11, 2);
    const float* attn_v_b   = IN(12, 4);
    const float* attn_pw    = IN(13, 1);
    const float* attn_pb    = IN(14, 0);
    const float* lnt2s_g    = IN(15, 24);
    const float* lnt2s_b    = IN(16, 23);
    const float* t2s_qw     = IN(17, 41);
    const float* t2s_qb     = IN(18, 40);
    const float* t2s_kvw    = IN(19, 37);
    const float* t2s_kvb    = IN(20, 36);
    const float* t2s_pw     = IN(21, 39);
    const float* t2s_pb     = IN(22, 38);
    const float* lns2t_g    = IN(23, 22);
    const float* lns2t_b    = IN(24, 21);
    const float* s2t_qw     = IN(25, 34);
    const float* s2t_qb     = IN(26, 33);
    const float* s2t_kvw    = IN(27, 30);
    const float* s2t_kvb    = IN(28, 29);
    const float* s2t_pw     = IN(29, 32);
    const float* s2t_pb     = IN(30, 31);
    const float* ln2s_g     = IN(31, 18);
    const float* ln2s_b     = IN(32, 17);
    const float* cfc_w      = IN(33, 6);
    const float* cfc_b      = IN(34, 5);
    const float* cproj_w    = IN(35, 8);
    const float* cproj_b    = IN(36, 7);
    const float* ln2t_g     = IN(37, 20);
    const float* ln2t_b     = IN(38, 19);
    const float* fc1_w      = IN(39, 10);
    const float* fc1_b      = IN(40, 9);
    const float* fc2_w      = IN(41, 12);
    const float* fc2_b      = IN(42, 11);

    // ---- residual streams live in d_out (f32) -------------------------------
    float* s_f = (float*)d_out;
    float* t_f = (float*)d_out + n_sf;

    // ---- workspace ----------------------------------------------------------
    char* ws = (char*)d_ws;
    size_t off = 0;
    auto take = [&](size_t bytes) { size_t o = off; off += (bytes + 255) & ~(size_t)255; return o; };
    float* biasP = (float*)(ws + take(19968 * 4));
    u16*   yb    = (u16*)(ws + take((size_t)Mt * 768 * 2));   // 19.3 MB
    u16*   bufA  = (u16*)(ws + take((size_t)Mt * 2304 * 2));  // 57.8 MB
    u16*   bufB  = (u16*)(ws + take((size_t)Mt * 768 * 2));   // 19.3 MB
    u16*   sxb   = (u16*)(ws + take((size_t)Ms * 768 * 2));   // 2.4 MB
    u16*   vtb   = (u16*)(ws + take((size_t)2352 * 64 * 64 * 2)); // 19.3 MB
    auto wtake = [&](size_t nelem) { return (u16*)(ws + take(nelem * 2)); };
    u16 *W_mha   = wtake(2304 * 768), *W_mhao  = wtake(768 * 768);
    u16 *W_qkv   = wtake(2304 * 768), *W_attnp = wtake(768 * 768);
    u16 *W_t2sq  = wtake(768 * 768),  *W_t2skv = wtake(1536 * 768), *W_t2sp = wtake(768 * 768);
    u16 *W_s2tq  = wtake(768 * 768),  *W_s2tkv = wtake(1536 * 768), *W_s2tp = wtake(768 * 768);
    u16 *W_cfc   = wtake(3072 * 768), *W_cproj = wtake(768 * 3072);
    u16 *W_fc1   = wtake(3072 * 768), *W_fc2   = wtake(768 * 3072);

    // bias pool offsets
    const int B_MHA = 0, B_QKV = 2304, B_MHAO = 4608, B_ATTNP = 5376;
    const int B_T2SKV = 6144, B_T2SQ = 7680, B_T2SP = 8448, B_S2TQ = 9216;
    const int B_S2TKV = 9984, B_S2TP = 11520, B_CFC = 12288, B_CPROJ = 15360;
    const int B_FC1 = 16128, B_FC2 = 19200;

    auto cdiv = [](int a, int b) { return (a + b - 1) / b; };
    auto CW = [&](const float* src, u16* dst, int n) {
        f2b_kernel<<<cdiv(n, 256), 256, 0, stream>>>(src, dst, n);
    };
    // weights -> bf16 pool
    CW(mha_w, W_mha, 2304 * 768);      CW(mha_ow, W_mhao, 768 * 768);
    CW(attn_qkv_w, W_qkv, 2304 * 768); CW(attn_pw, W_attnp, 768 * 768);
    CW(t2s_qw, W_t2sq, 768 * 768);     CW(t2s_kvw, W_t2skv, 1536 * 768);
    CW(t2s_pw, W_t2sp, 768 * 768);     CW(s2t_qw, W_s2tq, 768 * 768);
    CW(s2t_kvw, W_s2tkv, 1536 * 768);  CW(s2t_pw, W_s2tp, 768 * 768);
    CW(cfc_w, W_cfc, 3072 * 768);      CW(cproj_w, W_cproj, 768 * 3072);
    CW(fc1_w, W_fc1, 3072 * 768);      CW(fc2_w, W_fc2, 768 * 3072);

    build_bias_pool<<<78, 256, 0, stream>>>(biasP,
        mha_b, attn_q_b, attn_v_b, mha_ob, attn_pb, t2s_kvb, t2s_qb, t2s_pb,
        s2t_qb, s2t_kvb, s2t_pb, cfc_b, cproj_b, fc1_b, fc2_b);

    // residual streams <- inputs
    copy_f32<<<cdiv(n_sf, 256), 256, 0, stream>>>(in_sx, s_f, n_sf);
    copy_f32<<<cdiv(n_tf, 256), 256, 0, stream>>>(in_tx, t_f, n_tf);

    // ---- stage 1: clip self-attention (attends over the batch axis) ---------
    ln_kernel<<<Ms, 256, 0, stream>>>(s_f, ln1s_g, ln1s_b, yb);
    gemm_mfma<0, 64><<<dim3(cdiv(Ms, 64), 18), 256, 0, stream>>>(yb, W_mha, biasP + B_MHA, bufA, (float*)0, Ms, 2304, 768);
    transpose_v<<<dim3(1, sN * 12), 256, 0, stream>>>(bufA + 1536, vtb, 8, 64, 2304LL, (long long)sN * 2304);
    flash_attn<<<dim3(1, sN * 12), 256, 0, stream>>>(
        bufA, bufA + 768, vtb, bufB, /*Nq=*/8, /*Nk=*/8, /*Nkp=*/64,
        /*qA=*/2304LL, /*qI=*/(long long)sN * 2304,
        /*kA=*/2304LL, /*kJ=*/(long long)sN * 2304,
        /*oA=*/768LL,  /*oI=*/(long long)sN * 768);
    gemm_mfma<1, 64><<<dim3(cdiv(Ms, 64), 6), 256, 0, stream>>>(bufB, W_mhao, biasP + B_MHAO, (u16*)0, s_f, Ms, 768, 768);

    // ---- stage 2: video self-attention --------------------------------------
    ln_kernel<<<Mt, 256, 0, stream>>>(t_f, ln1t_g, ln1t_b, yb);
    gemm_mfma<0, 128><<<dim3(cdiv(Mt, 128), 18), 256, 0, stream>>>(yb, W_qkv, biasP + B_QKV, bufA, (float*)0, Mt, 2304, 768);
    transpose_v<<<dim3(25, B * 12), 256, 0, stream>>>(bufA + 1536, vtb, tN, 1600, (long long)tN * 2304, 2304LL);
    flash_attn<<<dim3(cdiv(tN, 64), B * 12), 256, 0, stream>>>(
        bufA, bufA + 768, vtb, bufB, /*Nq=*/tN, /*Nk=*/tN, /*Nkp=*/1600,
        (long long)tN * 2304, 2304LL,
        (long long)tN * 2304, 2304LL,
        (long long)tN * 768, 768LL);
    gemm_mfma<4, 128><<<dim3(cdiv(Mt, 128), 6), 256, 0, stream>>>(bufB, W_attnp, biasP + B_ATTNP, yb, t_f, Mt, 768, 768);

    // ---- stage 3: T2S cross (q from LN(s_x), kv from updated t_x) -----------
    gemm_mfma<0, 128><<<dim3(cdiv(Mt, 128), 12), 256, 0, stream>>>(yb, W_t2skv, biasP + B_T2SKV, bufA, (float*)0, Mt, 1536, 768);
    transpose_v<<<dim3(25, B * 12), 256, 0, stream>>>(bufA + 768, vtb, tN, 1600, (long long)tN * 1536, 1536LL);
    ln_kernel<<<Ms, 256, 0, stream>>>(s_f, lnt2s_g, lnt2s_b, yb);
    u16* q3 = bufB;
    u16* o3 = bufB + (size_t)Ms * 768;
    gemm_mfma<0, 64><<<dim3(cdiv(Ms, 64), 6), 256, 0, stream>>>(yb, W_t2sq, biasP + B_T2SQ, q3, (float*)0, Ms, 768, 768);
    flash_attn<<<dim3(cdiv(sN, 64), B * 12), 256, 0, stream>>>(
        q3, bufA, vtb, o3, /*Nq=*/sN, /*Nk=*/tN, /*Nkp=*/1600,
        (long long)sN * 768, 768LL,
        (long long)tN * 1536, 1536LL,
        (long long)sN * 768, 768LL);
    gemm_mfma<4, 64><<<dim3(cdiv(Ms, 64), 6), 256, 0, stream>>>(o3, W_t2sp, biasP + B_T2SP, sxb, s_f, Ms, 768, 768);

    // ---- stage 4: S2T cross (q from LN(t_x), kv from updated s_x) -----------
    ln_kernel<<<Mt, 256, 0, stream>>>(t_f, lns2t_g, lns2t_b, yb);
    gemm_mfma<0, 128><<<dim3(cdiv(Mt, 128), 6), 256, 0, stream>>>(yb, W_s2tq, biasP + B_S2TQ, bufB, (float*)0, Mt, 768, 768);
    gemm_mfma<0, 64><<<dim3(cdiv(Ms, 64), 12), 256, 0, stream>>>(sxb, W_s2tkv, biasP + B_S2TKV, bufA, (float*)0, Ms, 1536, 768);
    transpose_v<<<dim3(4, B * 12), 256, 0, stream>>>(bufA + 768, vtb, sN, 256, (long long)sN * 1536, 1536LL);
    flash_attn<<<dim3(cdiv(tN, 64), B * 12), 256, 0, stream>>>(
        bufB, bufA, vtb, yb, /*Nq=*/tN, /*Nk=*/sN, /*Nkp=*/256,
        (long long)tN * 768, 768LL,
        (long long)sN * 1536, 1536LL,
        (long long)tN * 768, 768LL);
    gemm_mfma<1, 128><<<dim3(cdiv(Mt, 128), 6), 256, 0, stream>>>(yb, W_s2tp, biasP + B_S2TP, (u16*)0, t_f, Mt, 768, 768);

    // ---- stage 5: clip MLP (QuickGELU) --------------------------------------
    ln_kernel<<<Ms, 256, 0, stream>>>(s_f, ln2s_g, ln2s_b, yb);
    gemm_mfma<2, 64><<<dim3(cdiv(Ms, 64), 24), 256, 0, stream>>>(yb, W_cfc, biasP + B_CFC, bufA, (float*)0, Ms, 3072, 768);
    gemm_mfma<1, 64><<<dim3(cdiv(Ms, 64), 6), 256, 0, stream>>>(bufA, W_cproj, biasP + B_CPROJ, (u16*)0, s_f, Ms, 768, 3072);

    // ---- stage 6: video MLP (exact GELU), two row-halves --------------------
    ln_kernel<<<Mt, 256, 0, stream>>>(t_f, ln2t_g, ln2t_b, yb);
    for (int c = 0; c < 2; c++) {
        int r0 = c * (Mt / 2), Mc = Mt / 2;
        gemm_mfma<3, 128><<<dim3(cdiv(Mc, 128), 24), 256, 0, stream>>>(
            yb + (size_t)r0 * 768, W_fc1, biasP + B_FC1, bufA, (float*)0, Mc, 3072, 768);
        gemm_mfma<1, 128><<<dim3(cdiv(Mc, 128), 6), 256, 0, stream>>>(
            bufA, W_fc2, biasP + B_FC2, (u16*)0, t_f + (size_t)r0 * 768, Mc, 768, 3072);
    }
}

// Round 11
// 1049.617 us; speedup vs baseline: 21.1136x; 1.0376x over previous
//
#include <hip/hip_runtime.h>
#include <stdint.h>

// ---------------------------------------------------------------------------
// Block_6554120094246: dual-stream transformer block (CLIP + video streams).
// f32 in/out. Residual streams in d_out. bf16 intermediates + MFMA GEMM
// (BMx128x64 twin-slab, global_load_lds) + MFMA flash attention v5:
// double-buffered K/V staging with counted vmcnt across raw s_barriers
// (loads in flight under compute), setprio MFMA clusters, max3 fmax tree,
// swizzled LDS, defer-max, exp2 softmax. ws ~175 MB.
// ---------------------------------------------------------------------------

typedef uint16_t u16;
typedef uint16_t u16x8 __attribute__((ext_vector_type(8)));
typedef uint16_t u16x4 __attribute__((ext_vector_type(4)));
typedef short bf16x8 __attribute__((ext_vector_type(8)));
typedef float f32x4 __attribute__((ext_vector_type(4)));

__device__ __forceinline__ float b2f(u16 u) {
    union { float f; uint32_t i; } x;
    x.i = ((uint32_t)u) << 16;
    return x.f;
}
__device__ __forceinline__ u16 f2b(float f) {
    union { float f; uint32_t i; } x;
    x.f = f;
    uint32_t i = x.i;
    uint32_t r = (i + 0x7FFFu + ((i >> 16) & 1u)) >> 16;  // RNE
    return (u16)r;
}
__device__ __forceinline__ u16 f2b_trunc(float f) {      // for P in [0,256]
    union { float f; uint32_t i; } x;
    x.f = f;
    return (u16)(x.i >> 16);
}

// async global->LDS, 16B per lane; LDS dest wave-uniform base (+lane*16B).
__device__ __forceinline__ void gload16(const u16* g, u16* l) {
    __builtin_amdgcn_global_load_lds(
        (const __attribute__((address_space(1))) uint32_t*)g,
        (__attribute__((address_space(3))) uint32_t*)l, 16, 0, 0);
}

__global__ void f2b_kernel(const float* __restrict__ in, u16* __restrict__ out, int n) {
    int i = blockIdx.x * 256 + threadIdx.x;
    if (i < n) out[i] = f2b(in[i]);
}
__global__ void copy_f32(const float* __restrict__ in, float* __restrict__ out, int n) {
    int i = blockIdx.x * 256 + threadIdx.x;
    if (i < n) out[i] = in[i];
}

// ---- bias pool (single launch). Layout (f32 offsets):
// 0 mha_b[2304] | 2304 [attn_q_b,0,attn_v_b] | 4608 mha_ob | 5376 attn_pb |
// 6144 [0,t2s_kvb] | 7680 t2s_qb | 8448 t2s_pb | 9216 s2t_qb |
// 9984 [0,s2t_kvb] | 11520 s2t_pb | 12288 cfc_b[3072] | 15360 cproj_b |
// 16128 fc1_b[3072] | 19200 fc2_b | total 19968
__global__ void build_bias_pool(float* __restrict__ dst,
    const float* mha_b, const float* attn_q_b, const float* attn_v_b,
    const float* mha_ob, const float* attn_pb, const float* t2s_kvb,
    const float* t2s_qb, const float* t2s_pb, const float* s2t_qb,
    const float* s2t_kvb, const float* s2t_pb, const float* cfc_b,
    const float* cproj_b, const float* fc1_b, const float* fc2_b) {
    int i = blockIdx.x * 256 + threadIdx.x;
    float v = 0.f;
    if (i < 2304) v = mha_b[i];
    else if (i < 4608) { int j = i - 2304; v = (j < 768) ? attn_q_b[j] : (j < 1536 ? 0.f : attn_v_b[j - 1536]); }
    else if (i < 5376) v = mha_ob[i - 4608];
    else if (i < 6144) v = attn_pb[i - 5376];
    else if (i < 7680) { int j = i - 6144; v = (j < 768) ? 0.f : t2s_kvb[j - 768]; }
    else if (i < 8448) v = t2s_qb[i - 7680];
    else if (i < 9216) v = t2s_pb[i - 8448];
    else if (i < 9984) v = s2t_qb[i - 9216];
    else if (i < 11520) { int j = i - 9984; v = (j < 768) ? 0.f : s2t_kvb[j - 768]; }
    else if (i < 12288) v = s2t_pb[i - 11520];
    else if (i < 15360) v = cfc_b[i - 12288];
    else if (i < 16128) v = cproj_b[i - 15360];
    else if (i < 19200) v = fc1_b[i - 16128];
    else if (i < 19968) v = fc2_b[i - 19200];
    else return;
    dst[i] = v;
}

// ---- block reductions ---------------------------------------------------------
__device__ __forceinline__ float block_sum(float v, float* red) {
    #pragma unroll
    for (int o = 32; o > 0; o >>= 1) v += __shfl_down(v, o, 64);
    int w = threadIdx.x >> 6, l = threadIdx.x & 63;
    __syncthreads();
    if (l == 0) red[w] = v;
    __syncthreads();
    return red[0] + red[1] + red[2] + red[3];
}

// ---- LayerNorm over C=768 ------------------------------------------------------
__global__ __launch_bounds__(256) void ln_kernel(
    const float* __restrict__ x, const float* __restrict__ g,
    const float* __restrict__ bta, u16* __restrict__ y) {
    const int r = blockIdx.x;
    const int t = threadIdx.x;
    const float* xr = x + (size_t)r * 768;
    float v0 = xr[t], v1 = xr[t + 256], v2 = xr[t + 512];
    __shared__ float red[4];
    float mean = block_sum(v0 + v1 + v2, red) * (1.0f / 768.0f);
    float d0 = v0 - mean, d1 = v1 - mean, d2 = v2 - mean;
    float var = block_sum(d0 * d0 + d1 * d1 + d2 * d2, red) * (1.0f / 768.0f);
    float rs = rsqrtf(var + 1e-5f);
    u16* yr = y + (size_t)r * 768;
    yr[t]       = f2b(d0 * rs * g[t]       + bta[t]);
    yr[t + 256] = f2b(d1 * rs * g[t + 256] + bta[t + 256]);
    yr[t + 512] = f2b(d2 * rs * g[t + 512] + bta[t + 512]);
}

// ---- V transpose: vt[(inst*64+d)*Nkp + kv] = V[kv][d], zero-padded to Nkp ----
__global__ __launch_bounds__(256) void transpose_v(
    const u16* __restrict__ vp, u16* __restrict__ vt, int Nk, int Nkp,
    long long vA, long long vJ) {
    const int inst = blockIdx.y;
    const int a = inst / 12, h = inst % 12;
    const int t0 = blockIdx.x * 64;
    const int tid = threadIdx.x;
    __shared__ u16 T[64][72];
    const int kvl = tid >> 2, dseg = (tid & 3) * 16;
    u16x8 v0 = {}, v1 = {};
    if (t0 + kvl < Nk) {
        const u16* src = vp + a * vA + (long long)(t0 + kvl) * vJ + h * 64 + dseg;
        v0 = *(const u16x8*)src;
        v1 = *(const u16x8*)(src + 8);
    }
    *(u16x8*)&T[kvl][dseg]     = v0;
    *(u16x8*)&T[kvl][dseg + 8] = v1;
    __syncthreads();
    const int dl = tid >> 2, kseg = (tid & 3) * 16;
    u16x8 w0, w1;
    #pragma unroll
    for (int j = 0; j < 8; j++) w0[j] = T[kseg + j][dl];
    #pragma unroll
    for (int j = 0; j < 8; j++) w1[j] = T[kseg + 8 + j][dl];
    u16* orow = vt + ((size_t)inst * 64 + dl) * Nkp + t0 + kseg;
    *(u16x8*)orow = w0;
    *(u16x8*)(orow + 8) = w1;
}

// ---- MFMA GEMM: C[M,N] = A[M,K](bf16) @ W[N,K](bf16)^T + bias[N] --------------
// BM x 128 x 64 tile (twin 32-wide K slabs). MODE 0: bf16. 1: Cf += v.
// 2: QuickGELU. 3: exact GELU. 4: Cf += v AND Cb = f2b(new Cf).
template <int MODE, int BM>
__global__ __launch_bounds__(256) void gemm_mfma(
    const u16* __restrict__ A, const u16* __restrict__ W,
    const float* __restrict__ bias, u16* __restrict__ Cb,
    float* __restrict__ Cf, int M, int N, int K) {
    constexpr int MI = BM / 32;              // acc rows per wave / 16
    __shared__ u16 As[2][BM][32];
    __shared__ u16 Bs[2][128][32];
    const int tid = threadIdx.x;
    const int lane = tid & 63;
    const int wid = tid >> 6;
    const int wr = (wid >> 1) * (BM / 2), wc = (wid & 1) * 64;
    const int m0 = blockIdx.x * BM, n0 = blockIdx.y * 128;
    const int lr = lane >> 2, lc = (lane & 3) * 8;   // 16 rows x 32 cols / call
    const int fr = lane & 15, fk = (lane >> 4) * 8;
    const int abase = wid * (BM / 4);
    const int bbase = wid * 32;
    f32x4 acc[MI][4] = {};
    for (int k0 = 0; k0 < K; k0 += 64) {
        #pragma unroll
        for (int s = 0; s < 2; s++) {
            #pragma unroll
            for (int j = 0; j < BM / 64; j++) {
                int rowa = m0 + abase + j * 16 + lr;
                rowa = rowa < M ? rowa : M - 1;      // clamp (values unused)
                gload16(A + (size_t)rowa * K + k0 + s * 32 + lc, &As[s][abase + j * 16][0]);
            }
            #pragma unroll
            for (int j = 0; j < 2; j++) {
                gload16(W + (size_t)(n0 + bbase + j * 16 + lr) * K + k0 + s * 32 + lc,
                        &Bs[s][bbase + j * 16][0]);
            }
        }
        __syncthreads();
        #pragma unroll
        for (int s = 0; s < 2; s++) {
            bf16x8 a[MI], b[4];
            #pragma unroll
            for (int i = 0; i < MI; i++) a[i] = *(const bf16x8*)&As[s][wr + i * 16 + fr][fk];
            #pragma unroll
            for (int j = 0; j < 4; j++) b[j] = *(const bf16x8*)&Bs[s][wc + j * 16 + fr][fk];
            #pragma unroll
            for (int i = 0; i < MI; i++)
                #pragma unroll
                for (int j = 0; j < 4; j++)
                    acc[i][j] = __builtin_amdgcn_mfma_f32_16x16x32_bf16(a[i], b[j], acc[i][j], 0, 0, 0);
        }
        __syncthreads();
    }
    const int er = (lane >> 4) * 4;
    #pragma unroll
    for (int i = 0; i < MI; i++) {
        #pragma unroll
        for (int reg = 0; reg < 4; reg++) {
            int r = m0 + wr + i * 16 + er + reg;
            if (r >= M) continue;
            #pragma unroll
            for (int j = 0; j < 4; j++) {
                int c = n0 + wc + j * 16 + fr;
                float v = acc[i][j][reg] + bias[c];
                size_t idx = (size_t)r * N + c;
                if (MODE == 1) {
                    Cf[idx] += v;
                } else if (MODE == 4) {
                    float nv = Cf[idx] + v;
                    Cf[idx] = nv;
                    Cb[idx] = f2b(nv);
                } else {
                    if (MODE == 2) v = v / (1.0f + expf(-1.702f * v));
                    if (MODE == 3) v = 0.5f * v * (1.0f + erff(v * 0.70710678118654752f));
                    Cb[idx] = f2b(v);
                }
            }
        }
    }
}

// ---- MFMA flash attention v5 -------------------------------------------------
// Swapped QK^T (lane q = fr), KV tiles 64, DOUBLE-BUFFERED K/V staging:
// next tile's global_load_lds issued before computing current; raw s_barrier
// + counted vmcnt(4) keeps loads in flight under compute. setprio around
// MFMA clusters. XOR-swizzled LDS (2-way banks). exp2-domain, defer-max.
__global__ __launch_bounds__(256) void flash_attn(
    const u16* __restrict__ qp, const u16* __restrict__ kp,
    const u16* __restrict__ vt, u16* __restrict__ op,
    int Nq, int Nk, int Nkp,
    long long qA, long long qI, long long kA, long long kJ,
    long long oA, long long oI) {
    const int inst = blockIdx.y;
    const int a = inst / 12, h = inst % 12;
    const int tid = threadIdx.x, lane = tid & 63, w = tid >> 6;
    const int fr = lane & 15, g = lane >> 4, fk = g * 8;
    const int f3s = (fr & 7) << 3;                  // read-side XOR (u16 units)
    __shared__ u16 Ks[2][64][64];
    __shared__ u16 Vs[2][64][64];                    // logical [d][kv]
    __shared__ u16 Ps[4][16][64];                    // logical [q][kv], swizzled
    const u16* qb = qp + a * qA + h * 64;
    const u16* kb = kp + a * kA + h * 64;
    const u16* vtb = vt + (size_t)inst * 64 * Nkp;
    const int q0 = blockIdx.x * 64 + w * 16;

    // Q fragments, pre-scaled by 0.125*log2(e) (softmax in exp2 domain)
    bf16x8 qf[2];
    {
        u16x8 raw0 = {}, raw1 = {};
        int qr = q0 + fr;
        if (qr < Nq) {
            const u16* qrp = qb + (long long)qr * qI;
            raw0 = *(const u16x8*)(qrp + fk);
            raw1 = *(const u16x8*)(qrp + 32 + fk);
        }
        const float QS = 0.125f * 1.44269504088896340736f;
        u16x8 s0, s1;
        #pragma unroll
        for (int e = 0; e < 8; e++) {
            s0[e] = f2b(b2f(raw0[e]) * QS);
            s1[e] = f2b(b2f(raw1[e]) * QS);
        }
        qf[0] = *(bf16x8*)&s0;
        qf[1] = *(bf16x8*)&s1;
    }
    float mrun = -1e30f, lrun = 0.f;
    f32x4 o[4] = {};

    const int l = lane;
    const int srow = w * 8 + (l >> 3);               // +c*32
    const int sdcol = ((l & 7) * 8) ^ (((l >> 3) & 7) << 3);

    // stage tile starting at kv=t0 into buffer s (4 gloads per wave)
    auto STAGE = [&](int s, int t0) {
        #pragma unroll
        for (int c = 0; c < 2; c++) {
            int row = c * 32 + srow;
            int kr = t0 + row; if (kr >= Nk) kr = Nk - 1;     // masked later
            gload16(kb + (long long)kr * kJ + sdcol, &Ks[s][0][0] + c * 2048 + w * 512);
            gload16(vtb + (size_t)row * Nkp + t0 + sdcol, &Vs[s][0][0] + c * 2048 + w * 512);
        }
    };

    const int nt = (Nk + 63) >> 6;
    STAGE(0, 0);
    for (int it = 0; it < nt; ++it) {
        const int t0 = it << 6;
        const int cur = it & 1;
        if (it + 1 < nt) {
            STAGE(cur ^ 1, t0 + 64);                 // next tile in flight
            asm volatile("s_waitcnt vmcnt(4)" ::: "memory");  // oldest 4 = cur
        } else {
            asm volatile("s_waitcnt vmcnt(0)" ::: "memory");
        }
        __builtin_amdgcn_s_barrier();

        // ---- S^T = K Qs^T : s[hh][r] = S[q=fr][kv = t0 + hh*16 + 4g + r] ----
        f32x4 s[4] = {};
        __builtin_amdgcn_s_setprio(1);
        #pragma unroll
        for (int hh = 0; hh < 4; hh++) {
            bf16x8 k0f = *(const bf16x8*)&Ks[cur][hh * 16 + fr][fk ^ f3s];
            bf16x8 k1f = *(const bf16x8*)&Ks[cur][hh * 16 + fr][(32 + fk) ^ f3s];
            s[hh] = __builtin_amdgcn_mfma_f32_16x16x32_bf16(k0f, qf[0], s[hh], 0, 0, 0);
            s[hh] = __builtin_amdgcn_mfma_f32_16x16x32_bf16(k1f, qf[1], s[hh], 0, 0, 0);
        }
        __builtin_amdgcn_s_setprio(0);

        // ---- online softmax (exp2 domain), defer-max THR=8 -------------------
        if (t0 + 64 > Nk) {
            #pragma unroll
            for (int hh = 0; hh < 4; hh++)
                #pragma unroll
                for (int r = 0; r < 4; r++)
                    if (t0 + hh * 16 + 4 * g + r >= Nk) s[hh][r] = -1e30f;
        }
        // balanced max tree (v_max3-friendly)
        float a0 = fmaxf(fmaxf(s[0][0], s[0][1]), s[0][2]);
        float a1 = fmaxf(fmaxf(s[0][3], s[1][0]), s[1][1]);
        float a2 = fmaxf(fmaxf(s[1][2], s[1][3]), s[2][0]);
        float a3 = fmaxf(fmaxf(s[2][1], s[2][2]), s[2][3]);
        float a4 = fmaxf(fmaxf(s[3][0], s[3][1]), s[3][2]);
        float b0 = fmaxf(fmaxf(a0, a1), a2);
        float b1 = fmaxf(fmaxf(a3, a4), s[3][3]);
        float lmax = fmaxf(b0, b1);
        lmax = fmaxf(lmax, __shfl_xor(lmax, 16, 64));
        lmax = fmaxf(lmax, __shfl_xor(lmax, 32, 64));
        if (!__all(lmax <= mrun + 8.0f)) {            // rescale (rare)
            float mn = fmaxf(mrun, lmax);
            float sf = exp2f(mrun - mn);
            mrun = mn;
            lrun *= sf;
            float sfo[4];
            #pragma unroll
            for (int r = 0; r < 4; r++) sfo[r] = __shfl(sf, g * 4 + r, 64);
            #pragma unroll
            for (int dt = 0; dt < 4; dt++)
                #pragma unroll
                for (int r = 0; r < 4; r++) o[dt][r] *= sfo[r];
        }
        float p[4][4];
        float ps = 0.f;
        #pragma unroll
        for (int hh = 0; hh < 4; hh++)
            #pragma unroll
            for (int r = 0; r < 4; r++) {
                p[hh][r] = exp2f(s[hh][r] - mrun);
                ps += p[hh][r];
            }
        ps += __shfl_xor(ps, 16, 64);
        ps += __shfl_xor(ps, 32, 64);
        lrun += ps;
        // ---- P -> LDS (b64, swizzled cols) -----------------------------------
        #pragma unroll
        for (int hh = 0; hh < 4; hh++) {
            u16x4 pk;
            #pragma unroll
            for (int r = 0; r < 4; r++) pk[r] = f2b_trunc(p[hh][r]);
            *(u16x4*)&Ps[w][fr][(hh * 16 + g * 4) ^ f3s] = pk;
        }
        // ---- PV --------------------------------------------------------------
        bf16x8 pa0 = *(const bf16x8*)&Ps[w][fr][fk ^ f3s];
        bf16x8 pa1 = *(const bf16x8*)&Ps[w][fr][(32 + fk) ^ f3s];
        __builtin_amdgcn_s_setprio(1);
        #pragma unroll
        for (int dt = 0; dt < 4; dt++) {
            bf16x8 vf0 = *(const bf16x8*)&Vs[cur][dt * 16 + fr][fk ^ f3s];
            bf16x8 vf1 = *(const bf16x8*)&Vs[cur][dt * 16 + fr][(32 + fk) ^ f3s];
            o[dt] = __builtin_amdgcn_mfma_f32_16x16x32_bf16(pa0, vf0, o[dt], 0, 0, 0);
            o[dt] = __builtin_amdgcn_mfma_f32_16x16x32_bf16(pa1, vf1, o[dt], 0, 0, 0);
        }
        __builtin_amdgcn_s_setprio(0);
        __builtin_amdgcn_s_barrier();                // all waves done with cur
    }
    // ---- epilogue: O[q][d] = o/l --------------------------------------------
    float rcp = 1.0f / lrun;
    #pragma unroll
    for (int r = 0; r < 4; r++) {
        float rr = __shfl(rcp, g * 4 + r, 64);
        int q = q0 + g * 4 + r;
        if (q >= Nq) continue;
        u16* orow = op + a * oA + (long long)q * oI + h * 64;
        #pragma unroll
        for (int dt = 0; dt < 4; dt++)
            orow[dt * 16 + fr] = f2b(o[dt][r] * rr);
    }
}

// ---------------------------------------------------------------------------
extern "C" void kernel_launch(void* const* d_in, const int* in_sizes, int n_in,
                              void* d_out, int out_size, void* d_ws, size_t ws_size,
                              hipStream_t stream) {
    const int B = 8, sN = 196, tN = 1568;
    const int Ms = B * sN;            // 1568
    const int Mt = B * tN;            // 12544
    const int n_sf = Ms * 768;        // 1204224
    const int n_tf = Mt * 768;        // 9633792
    (void)n_in; (void)out_size; (void)ws_size;

    const bool dict_order = (in_sizes[0] == n_sf);
    auto IN = [&](int di, int ai) -> const float* {
        return (const float*)d_in[dict_order ? di : ai];
    };
    const float* in_sx      = IN(0, 35);
    const float* in_tx      = IN(1, 42);
    const float* ln1s_g     = IN(2, 14);
    const float* ln1s_b     = IN(3, 13);
    const float* mha_w      = IN(4, 28);
    const float* mha_b      = IN(5, 25);
    const float* mha_ow     = IN(6, 27);
    const float* mha_ob     = IN(7, 26);
    const float* ln1t_g     = IN(8, 16);
    const float* ln1t_b     = IN(9, 15);
    const float* attn_qkv_w = IN(10, 3);
    const float* attn_q_b   = IN(11, 2);
    const float* attn_v_b   = IN(12, 4);
    const float* attn_pw    = IN(13, 1);
    const float* attn_pb    = IN(14, 0);
    const float* lnt2s_g    = IN(15, 24);
    const float* lnt2s_b    = IN(16, 23);
    const float* t2s_qw     = IN(17, 41);
    const float* t2s_qb     = IN(18, 40);
    const float* t2s_kvw    = IN(19, 37);
    const float* t2s_kvb    = IN(20, 36);
    const float* t2s_pw     = IN(21, 39);
    const float* t2s_pb     = IN(22, 38);
    const float* lns2t_g    = IN(23, 22);
    const float* lns2t_b    = IN(24, 21);
    const float* s2t_qw     = IN(25, 34);
    const float* s2t_qb     = IN(26, 33);
    const float* s2t_kvw    = IN(27, 30);
    const float* s2t_kvb    = IN(28, 29);
    const float* s2t_pw     = IN(29, 32);
    const float* s2t_pb     = IN(30, 31);
    const float* ln2s_g     = IN(31, 18);
    const float* ln2s_b     = IN(32, 17);
    const float* cfc_w      = IN(33, 6);
    const float* cfc_b      = IN(34, 5);
    const float* cproj_w    = IN(35, 8);
    const float* cproj_b    = IN(36, 7);
    const float* ln2t_g     = IN(37, 20);
    const float* ln2t_b     = IN(38, 19);
    const float* fc1_w      = IN(39, 10);
    const float* fc1_b      = IN(40, 9);
    const float* fc2_w      = IN(41, 12);
    const float* fc2_b      = IN(42, 11);

    // ---- residual streams live in d_out (f32) -------------------------------
    float* s_f = (float*)d_out;
    float* t_f = (float*)d_out + n_sf;

    // ---- workspace (~175 MB) ------------------------------------------------
    char* ws = (char*)d_ws;
    size_t off = 0;
    auto take = [&](size_t bytes) { size_t o = off; off += (bytes + 255) & ~(size_t)255; return o; };
    float* biasP = (float*)(ws + take(19968 * 4));
    u16*   yb    = (u16*)(ws + take((size_t)Mt * 768 * 2));   // 19.3 MB
    u16*   bufA  = (u16*)(ws + take((size_t)Mt * 3072 * 2));  // 77.1 MB
    u16*   bufB  = (u16*)(ws + take((size_t)Mt * 768 * 2));   // 19.3 MB
    u16*   sxb   = (u16*)(ws + take((size_t)Ms * 768 * 2));   // 2.4 MB
    u16*   vtb   = (u16*)(ws + take((size_t)2352 * 64 * 64 * 2)); // 19.3 MB
    auto wtake = [&](size_t nelem) { return (u16*)(ws + take(nelem * 2)); };
    u16 *W_mha   = wtake(2304 * 768), *W_mhao  = wtake(768 * 768);
    u16 *W_qkv   = wtake(2304 * 768), *W_attnp = wtake(768 * 768);
    u16 *W_t2sq  = wtake(768 * 768),  *W_t2skv = wtake(1536 * 768), *W_t2sp = wtake(768 * 768);
    u16 *W_s2tq  = wtake(768 * 768),  *W_s2tkv = wtake(1536 * 768), *W_s2tp = wtake(768 * 768);
    u16 *W_cfc   = wtake(3072 * 768), *W_cproj = wtake(768 * 3072);
    u16 *W_fc1   = wtake(3072 * 768), *W_fc2   = wtake(768 * 3072);

    // bias pool offsets
    const int B_MHA = 0, B_QKV = 2304, B_MHAO = 4608, B_ATTNP = 5376;
    const int B_T2SKV = 6144, B_T2SQ = 7680, B_T2SP = 8448, B_S2TQ = 9216;
    const int B_S2TKV = 9984, B_S2TP = 11520, B_CFC = 12288, B_CPROJ = 15360;
    const int B_FC1 = 16128, B_FC2 = 19200;

    auto cdiv = [](int a, int b) { return (a + b - 1) / b; };
    auto CW = [&](const float* src, u16* dst, int n) {
        f2b_kernel<<<cdiv(n, 256), 256, 0, stream>>>(src, dst, n);
    };
    // weights -> bf16 pool
    CW(mha_w, W_mha, 2304 * 768);      CW(mha_ow, W_mhao, 768 * 768);
    CW(attn_qkv_w, W_qkv, 2304 * 768); CW(attn_pw, W_attnp, 768 * 768);
    CW(t2s_qw, W_t2sq, 768 * 768);     CW(t2s_kvw, W_t2skv, 1536 * 768);
    CW(t2s_pw, W_t2sp, 768 * 768);     CW(s2t_qw, W_s2tq, 768 * 768);
    CW(s2t_kvw, W_s2tkv, 1536 * 768);  CW(s2t_pw, W_s2tp, 768 * 768);
    CW(cfc_w, W_cfc, 3072 * 768);      CW(cproj_w, W_cproj, 768 * 3072);
    CW(fc1_w, W_fc1, 3072 * 768);      CW(fc2_w, W_fc2, 768 * 3072);

    build_bias_pool<<<78, 256, 0, stream>>>(biasP,
        mha_b, attn_q_b, attn_v_b, mha_ob, attn_pb, t2s_kvb, t2s_qb, t2s_pb,
        s2t_qb, s2t_kvb, s2t_pb, cfc_b, cproj_b, fc1_b, fc2_b);

    // residual streams <- inputs
    copy_f32<<<cdiv(n_sf, 256), 256, 0, stream>>>(in_sx, s_f, n_sf);
    copy_f32<<<cdiv(n_tf, 256), 256, 0, stream>>>(in_tx, t_f, n_tf);

    // ---- stage 1: clip self-attention (attends over the batch axis) ---------
    ln_kernel<<<Ms, 256, 0, stream>>>(s_f, ln1s_g, ln1s_b, yb);
    gemm_mfma<0, 64><<<dim3(cdiv(Ms, 64), 18), 256, 0, stream>>>(yb, W_mha, biasP + B_MHA, bufA, (float*)0, Ms, 2304, 768);
    transpose_v<<<dim3(1, sN * 12), 256, 0, stream>>>(bufA + 1536, vtb, 8, 64, 2304LL, (long long)sN * 2304);
    flash_attn<<<dim3(1, sN * 12), 256, 0, stream>>>(
        bufA, bufA + 768, vtb, bufB, /*Nq=*/8, /*Nk=*/8, /*Nkp=*/64,
        /*qA=*/2304LL, /*qI=*/(long long)sN * 2304,
        /*kA=*/2304LL, /*kJ=*/(long long)sN * 2304,
        /*oA=*/768LL,  /*oI=*/(long long)sN * 768);
    gemm_mfma<1, 64><<<dim3(cdiv(Ms, 64), 6), 256, 0, stream>>>(bufB, W_mhao, biasP + B_MHAO, (u16*)0, s_f, Ms, 768, 768);

    // ---- stage 2: video self-attention --------------------------------------
    ln_kernel<<<Mt, 256, 0, stream>>>(t_f, ln1t_g, ln1t_b, yb);
    gemm_mfma<0, 128><<<dim3(cdiv(Mt, 128), 18), 256, 0, stream>>>(yb, W_qkv, biasP + B_QKV, bufA, (float*)0, Mt, 2304, 768);
    transpose_v<<<dim3(25, B * 12), 256, 0, stream>>>(bufA + 1536, vtb, tN, 1600, (long long)tN * 2304, 2304LL);
    flash_attn<<<dim3(cdiv(tN, 64), B * 12), 256, 0, stream>>>(
        bufA, bufA + 768, vtb, bufB, /*Nq=*/tN, /*Nk=*/tN, /*Nkp=*/1600,
        (long long)tN * 2304, 2304LL,
        (long long)tN * 2304, 2304LL,
        (long long)tN * 768, 768LL);
    gemm_mfma<4, 128><<<dim3(cdiv(Mt, 128), 6), 256, 0, stream>>>(bufB, W_attnp, biasP + B_ATTNP, yb, t_f, Mt, 768, 768);

    // ---- stage 3: T2S cross (q from LN(s_x), kv from updated t_x) -----------
    gemm_mfma<0, 128><<<dim3(cdiv(Mt, 128), 12), 256, 0, stream>>>(yb, W_t2skv, biasP + B_T2SKV, bufA, (float*)0, Mt, 1536, 768);
    transpose_v<<<dim3(25, B * 12), 256, 0, stream>>>(bufA + 768, vtb, tN, 1600, (long long)tN * 1536, 1536LL);
    ln_kernel<<<Ms, 256, 0, stream>>>(s_f, lnt2s_g, lnt2s_b, yb);
    u16* q3 = bufB;
    u16* o3 = bufB + (size_t)Ms * 768;
    gemm_mfma<0, 64><<<dim3(cdiv(Ms, 64), 6), 256, 0, stream>>>(yb, W_t2sq, biasP + B_T2SQ, q3, (float*)0, Ms, 768, 768);
    flash_attn<<<dim3(cdiv(sN, 64), B * 12), 256, 0, stream>>>(
        q3, bufA, vtb, o3, /*Nq=*/sN, /*Nk=*/tN, /*Nkp=*/1600,
        (long long)sN * 768, 768LL,
        (long long)tN * 1536, 1536LL,
        (long long)sN * 768, 768LL);
    gemm_mfma<4, 64><<<dim3(cdiv(Ms, 64), 6), 256, 0, stream>>>(o3, W_t2sp, biasP + B_T2SP, sxb, s_f, Ms, 768, 768);

    // ---- stage 4: S2T cross (q from LN(t_x), kv from updated s_x) -----------
    ln_kernel<<<Mt, 256, 0, stream>>>(t_f, lns2t_g, lns2t_b, yb);
    gemm_mfma<0, 128><<<dim3(cdiv(Mt, 128), 6), 256, 0, stream>>>(yb, W_s2tq, biasP + B_S2TQ, bufB, (float*)0, Mt, 768, 768);
    gemm_mfma<0, 64><<<dim3(cdiv(Ms, 64), 12), 256, 0, stream>>>(sxb, W_s2tkv, biasP + B_S2TKV, bufA, (float*)0, Ms, 1536, 768);
    transpose_v<<<dim3(4, B * 12), 256, 0, stream>>>(bufA + 768, vtb, sN, 256, (long long)sN * 1536, 1536LL);
    flash_attn<<<dim3(cdiv(tN, 64), B * 12), 256, 0, stream>>>(
        bufB, bufA, vtb, yb, /*Nq=*/tN, /*Nk=*/sN, /*Nkp=*/256,
        (long long)tN * 768, 768LL,
        (long long)sN * 1536, 1536LL,
        (long long)tN * 768, 768LL);
    gemm_mfma<1, 128><<<dim3(cdiv(Mt, 128), 6), 256, 0, stream>>>(yb, W_s2tp, biasP + B_S2TP, (u16*)0, t_f, Mt, 768, 768);

    // ---- stage 5: clip MLP (QuickGELU) --------------------------------------
    ln_kernel<<<Ms, 256, 0, stream>>>(s_f, ln2s_g, ln2s_b, yb);
    gemm_mfma<2, 64><<<dim3(cdiv(Ms, 64), 24), 256, 0, stream>>>(yb, W_cfc, biasP + B_CFC, bufA, (float*)0, Ms, 3072, 768);
    gemm_mfma<1, 64><<<dim3(cdiv(Ms, 64), 6), 256, 0, stream>>>(bufA, W_cproj, biasP + B_CPROJ, (u16*)0, s_f, Ms, 768, 3072);

    // ---- stage 6: video MLP (exact GELU), single shot ------------------------
    ln_kernel<<<Mt, 256, 0, stream>>>(t_f, ln2t_g, ln2t_b, yb);
    gemm_mfma<3, 128><<<dim3(cdiv(Mt, 128), 24), 256, 0, stream>>>(yb, W_fc1, biasP + B_FC1, bufA, (float*)0, Mt, 3072, 768);
    gemm_mfma<1, 128><<<dim3(cdiv(Mt, 128), 6), 256, 0, stream>>>(bufA, W_fc2, biasP + B_FC2, (u16*)0, t_f, Mt, 768, 3072);
}

// Round 12
// 967.959 us; speedup vs baseline: 22.8948x; 1.0844x over previous
//
#include <hip/hip_runtime.h>
#include <stdint.h>

// ---------------------------------------------------------------------------
// Block_6554120094246: dual-stream transformer block (CLIP + video streams).
// f32 in/out. Residual streams in d_out. bf16 intermediates + MFMA GEMM
// (BMx128x64 twin-slab, global_load_lds) + MFMA flash attention v5.
// This round: paired multi-problem launches (50 -> 21 dispatches), dual-
// stream LN, mega weight-convert. ws ~197 MB.
// ---------------------------------------------------------------------------

typedef uint16_t u16;
typedef uint16_t u16x8 __attribute__((ext_vector_type(8)));
typedef uint16_t u16x4 __attribute__((ext_vector_type(4)));
typedef short bf16x8 __attribute__((ext_vector_type(8)));
typedef float f32x4 __attribute__((ext_vector_type(4)));

__device__ __forceinline__ float b2f(u16 u) {
    union { float f; uint32_t i; } x;
    x.i = ((uint32_t)u) << 16;
    return x.f;
}
__device__ __forceinline__ u16 f2b(float f) {
    union { float f; uint32_t i; } x;
    x.f = f;
    uint32_t i = x.i;
    uint32_t r = (i + 0x7FFFu + ((i >> 16) & 1u)) >> 16;  // RNE
    return (u16)r;
}
__device__ __forceinline__ u16 f2b_trunc(float f) {      // for P in [0,256]
    union { float f; uint32_t i; } x;
    x.f = f;
    return (u16)(x.i >> 16);
}

// async global->LDS, 16B per lane; LDS dest wave-uniform base (+lane*16B).
__device__ __forceinline__ void gload16(const u16* g, u16* l) {
    __builtin_amdgcn_global_load_lds(
        (const __attribute__((address_space(1))) uint32_t*)g,
        (__attribute__((address_space(3))) uint32_t*)l, 16, 0, 0);
}

// ---- mega weight convert (one launch, 14 segments) --------------------------
struct CvtAll {
    const float* s[14];
    u16* d[14];
    int cum[15];
};
__global__ __launch_bounds__(256) void cvt_all(CvtAll c) {
    int i = blockIdx.x * 256 + threadIdx.x;
    if (i >= c.cum[14]) return;
    int seg = 0;
    #pragma unroll
    for (int k = 1; k < 14; k++) seg += (i >= c.cum[k]);
    int j = i - c.cum[seg];
    c.d[seg][j] = f2b(c.s[seg][j]);
}

__global__ __launch_bounds__(256) void copy_both(
    const float* __restrict__ a, const float* __restrict__ b,
    float* __restrict__ out, int na, int ntot) {
    int i = blockIdx.x * 256 + threadIdx.x;
    if (i < ntot) out[i] = (i < na) ? a[i] : b[i - na];
}

// ---- bias pool (single launch; offsets documented at call site) -------------
__global__ __launch_bounds__(256) void build_bias_pool(float* __restrict__ dst,
    const float* mha_b, const float* attn_q_b, const float* attn_v_b,
    const float* mha_ob, const float* attn_pb, const float* t2s_kvb,
    const float* t2s_qb, const float* t2s_pb, const float* s2t_qb,
    const float* s2t_kvb, const float* s2t_pb, const float* cfc_b,
    const float* cproj_b, const float* fc1_b, const float* fc2_b) {
    int i = blockIdx.x * 256 + threadIdx.x;
    float v = 0.f;
    if (i < 2304) v = mha_b[i];
    else if (i < 4608) { int j = i - 2304; v = (j < 768) ? attn_q_b[j] : (j < 1536 ? 0.f : attn_v_b[j - 1536]); }
    else if (i < 5376) v = mha_ob[i - 4608];
    else if (i < 6144) v = attn_pb[i - 5376];
    else if (i < 7680) { int j = i - 6144; v = (j < 768) ? 0.f : t2s_kvb[j - 768]; }
    else if (i < 8448) v = t2s_qb[i - 7680];
    else if (i < 9216) v = t2s_pb[i - 8448];
    else if (i < 9984) v = s2t_qb[i - 9216];
    else if (i < 11520) { int j = i - 9984; v = (j < 768) ? 0.f : s2t_kvb[j - 768]; }
    else if (i < 12288) v = s2t_pb[i - 11520];
    else if (i < 15360) v = cfc_b[i - 12288];
    else if (i < 16128) v = cproj_b[i - 15360];
    else if (i < 19200) v = fc1_b[i - 16128];
    else if (i < 19968) v = fc2_b[i - 19200];
    else return;
    dst[i] = v;
}

// ---- block reductions ---------------------------------------------------------
__device__ __forceinline__ float block_sum(float v, float* red) {
    #pragma unroll
    for (int o = 32; o > 0; o >>= 1) v += __shfl_down(v, o, 64);
    int w = threadIdx.x >> 6, l = threadIdx.x & 63;
    __syncthreads();
    if (l == 0) red[w] = v;
    __syncthreads();
    return red[0] + red[1] + red[2] + red[3];
}

// ---- dual-stream LayerNorm over C=768 (rows 0..rows0-1 -> set0, rest set1) ----
__global__ __launch_bounds__(256) void ln_dual(
    const float* __restrict__ x, int rows0,
    const float* __restrict__ g0, const float* __restrict__ b0, u16* __restrict__ y0,
    const float* __restrict__ g1, const float* __restrict__ b1, u16* __restrict__ y1) {
    const int r = blockIdx.x;
    const int t = threadIdx.x;
    const float* g; const float* bta; u16* yr;
    if (r < rows0) { g = g0; bta = b0; yr = y0 + (size_t)r * 768; }
    else           { g = g1; bta = b1; yr = y1 + (size_t)(r - rows0) * 768; }
    const float* xr = x + (size_t)r * 768;
    float v0 = xr[t], v1 = xr[t + 256], v2 = xr[t + 512];
    __shared__ float red[4];
    float mean = block_sum(v0 + v1 + v2, red) * (1.0f / 768.0f);
    float d0 = v0 - mean, d1 = v1 - mean, d2 = v2 - mean;
    float var = block_sum(d0 * d0 + d1 * d1 + d2 * d2, red) * (1.0f / 768.0f);
    float rs = rsqrtf(var + 1e-5f);
    yr[t]       = f2b(d0 * rs * g[t]       + bta[t]);
    yr[t + 256] = f2b(d1 * rs * g[t + 256] + bta[t + 256]);
    yr[t + 512] = f2b(d2 * rs * g[t + 512] + bta[t + 512]);
}

// ---- V transpose (pairable) ---------------------------------------------------
struct TransP {
    const u16* vp; u16* vt;
    int Nk, Nkp, gx, nb;
    long long vA, vJ;
};
__device__ __forceinline__ void transpose_body(const TransP p, int bid, u16 (*T)[72]) {
    const int x = bid % p.gx, inst = bid / p.gx;
    const int a = inst / 12, h = inst % 12;
    const int t0 = x * 64;
    const int tid = threadIdx.x;
    const int kvl = tid >> 2, dseg = (tid & 3) * 16;
    u16x8 v0 = {}, v1 = {};
    if (t0 + kvl < p.Nk) {
        const u16* src = p.vp + a * p.vA + (long long)(t0 + kvl) * p.vJ + h * 64 + dseg;
        v0 = *(const u16x8*)src;
        v1 = *(const u16x8*)(src + 8);
    }
    *(u16x8*)&T[kvl][dseg]     = v0;
    *(u16x8*)&T[kvl][dseg + 8] = v1;
    __syncthreads();
    const int dl = tid >> 2, kseg = (tid & 3) * 16;
    u16x8 w0, w1;
    #pragma unroll
    for (int j = 0; j < 8; j++) w0[j] = T[kseg + j][dl];
    #pragma unroll
    for (int j = 0; j < 8; j++) w1[j] = T[kseg + 8 + j][dl];
    u16* orow = p.vt + ((size_t)inst * 64 + dl) * p.Nkp + t0 + kseg;
    *(u16x8*)orow = w0;
    *(u16x8*)(orow + 8) = w1;
}
__global__ __launch_bounds__(256) void transpose_pair(TransP p0, TransP p1) {
    __shared__ u16 T[64][72];
    int bid = blockIdx.x;
    if (bid < p0.nb) transpose_body(p0, bid, T);
    else transpose_body(p1, bid - p0.nb, T);
}

// ---- MFMA GEMM body (pairable) ------------------------------------------------
// MODE 0: bf16. 1: Cf += v. 2: QuickGELU. 3: exact GELU. 4: Cf += v, Cb mirror.
struct GemmP {
    const u16* A; const u16* W; const float* bias;
    u16* Cb; float* Cf;
    int M, N, K, gx, nb;
};
template <int MODE, int BM>
__device__ __forceinline__ void gemm_body(const GemmP p, int bid,
                                          u16 (*AsF)[32], u16 (*BsF)[32]) {
    constexpr int MI = BM / 32;              // acc row-fragments per wave
    const int tid = threadIdx.x;
    const int lane = tid & 63;
    const int wid = tid >> 6;
    const int wr = (wid >> 1) * (BM / 2), wc = (wid & 1) * 64;
    const int bx = bid % p.gx, by = bid / p.gx;
    const int m0 = bx * BM, n0 = by * 128;
    const int lr = lane >> 2, lc = (lane & 3) * 8;   // 16 rows x 32 cols / call
    const int fr = lane & 15, fk = (lane >> 4) * 8;
    const int abase = wid * (BM / 4);
    const int bbase = wid * 32;
    f32x4 acc[MI][4] = {};
    for (int k0 = 0; k0 < p.K; k0 += 64) {
        #pragma unroll
        for (int s = 0; s < 2; s++) {
            #pragma unroll
            for (int j = 0; j < BM / 64; j++) {
                int rowa = m0 + abase + j * 16 + lr;
                rowa = rowa < p.M ? rowa : p.M - 1;  // clamp (values unused)
                gload16(p.A + (size_t)rowa * p.K + k0 + s * 32 + lc,
                        &AsF[s * 128 + abase + j * 16][0]);
            }
            #pragma unroll
            for (int j = 0; j < 2; j++) {
                gload16(p.W + (size_t)(n0 + bbase + j * 16 + lr) * p.K + k0 + s * 32 + lc,
                        &BsF[s * 128 + bbase + j * 16][0]);
            }
        }
        __syncthreads();
        #pragma unroll
        for (int s = 0; s < 2; s++) {
            bf16x8 a[MI], b[4];
            #pragma unroll
            for (int i = 0; i < MI; i++) a[i] = *(const bf16x8*)&AsF[s * 128 + wr + i * 16 + fr][fk];
            #pragma unroll
            for (int j = 0; j < 4; j++) b[j] = *(const bf16x8*)&BsF[s * 128 + wc + j * 16 + fr][fk];
            #pragma unroll
            for (int i = 0; i < MI; i++)
                #pragma unroll
                for (int j = 0; j < 4; j++)
                    acc[i][j] = __builtin_amdgcn_mfma_f32_16x16x32_bf16(a[i], b[j], acc[i][j], 0, 0, 0);
        }
        __syncthreads();
    }
    const int er = (lane >> 4) * 4;
    #pragma unroll
    for (int i = 0; i < MI; i++) {
        #pragma unroll
        for (int reg = 0; reg < 4; reg++) {
            int r = m0 + wr + i * 16 + er + reg;
            if (r >= p.M) continue;
            #pragma unroll
            for (int j = 0; j < 4; j++) {
                int c = n0 + wc + j * 16 + fr;
                float v = acc[i][j][reg] + p.bias[c];
                size_t idx = (size_t)r * p.N + c;
                if (MODE == 1) {
                    p.Cf[idx] += v;
                } else if (MODE == 4) {
                    float nv = p.Cf[idx] + v;
                    p.Cf[idx] = nv;
                    p.Cb[idx] = f2b(nv);
                } else {
                    if (MODE == 2) v = v / (1.0f + expf(-1.702f * v));
                    if (MODE == 3) v = 0.5f * v * (1.0f + erff(v * 0.70710678118654752f));
                    p.Cb[idx] = f2b(v);
                }
            }
        }
    }
}
template <int M0, int B0, int M1, int B1>
__global__ __launch_bounds__(256) void gemm_pair(GemmP p0, GemmP p1) {
    __shared__ u16 As[2 * 128][32];
    __shared__ u16 Bs[2 * 128][32];
    int bid = blockIdx.x;
    if (bid < p0.nb) gemm_body<M0, B0>(p0, bid, As, Bs);
    else gemm_body<M1, B1>(p1, bid - p0.nb, As, Bs);
}

// ---- MFMA flash attention v5 body (pairable) -----------------------------------
struct FlashP {
    const u16* qp; const u16* kp; const u16* vt; u16* op;
    int Nq, Nk, Nkp, gx, nb;
    long long qA, qI, kA, kJ, oA, oI;
};
__device__ __forceinline__ void flash_body(const FlashP p, int bid,
    u16 (*Ks)[64][64], u16 (*Vs)[64][64], u16 (*Ps)[16][64]) {
    const int x = bid % p.gx, inst = bid / p.gx;
    const int a = inst / 12, h = inst % 12;
    const int tid = threadIdx.x, lane = tid & 63, w = tid >> 6;
    const int fr = lane & 15, g = lane >> 4, fk = g * 8;
    const int f3s = (fr & 7) << 3;                  // read-side XOR (u16 units)
    const u16* qb = p.qp + a * p.qA + h * 64;
    const u16* kb = p.kp + a * p.kA + h * 64;
    const u16* vtb = p.vt + (size_t)inst * 64 * p.Nkp;
    const int q0 = x * 64 + w * 16;

    bf16x8 qf[2];
    {
        u16x8 raw0 = {}, raw1 = {};
        int qr = q0 + fr;
        if (qr < p.Nq) {
            const u16* qrp = qb + (long long)qr * p.qI;
            raw0 = *(const u16x8*)(qrp + fk);
            raw1 = *(const u16x8*)(qrp + 32 + fk);
        }
        const float QS = 0.125f * 1.44269504088896340736f;
        u16x8 s0, s1;
        #pragma unroll
        for (int e = 0; e < 8; e++) {
            s0[e] = f2b(b2f(raw0[e]) * QS);
            s1[e] = f2b(b2f(raw1[e]) * QS);
        }
        qf[0] = *(bf16x8*)&s0;
        qf[1] = *(bf16x8*)&s1;
    }
    float mrun = -1e30f, lrun = 0.f;
    f32x4 o[4] = {};

    const int l = lane;
    const int srow = w * 8 + (l >> 3);               // +c*32
    const int sdcol = ((l & 7) * 8) ^ (((l >> 3) & 7) << 3);

    auto STAGE = [&](int s, int t0) {
        #pragma unroll
        for (int c = 0; c < 2; c++) {
            int row = c * 32 + srow;
            int kr = t0 + row; if (kr >= p.Nk) kr = p.Nk - 1;   // masked later
            gload16(kb + (long long)kr * p.kJ + sdcol, &Ks[s][0][0] + c * 2048 + w * 512);
            gload16(vtb + (size_t)row * p.Nkp + t0 + sdcol, &Vs[s][0][0] + c * 2048 + w * 512);
        }
    };

    const int nt = (p.Nk + 63) >> 6;
    STAGE(0, 0);
    for (int it = 0; it < nt; ++it) {
        const int t0 = it << 6;
        const int cur = it & 1;
        if (it + 1 < nt) {
            STAGE(cur ^ 1, t0 + 64);
            asm volatile("s_waitcnt vmcnt(4)" ::: "memory");
        } else {
            asm volatile("s_waitcnt vmcnt(0)" ::: "memory");
        }
        __builtin_amdgcn_s_barrier();

        f32x4 s[4] = {};
        __builtin_amdgcn_s_setprio(1);
        #pragma unroll
        for (int hh = 0; hh < 4; hh++) {
            bf16x8 k0f = *(const bf16x8*)&Ks[cur][hh * 16 + fr][fk ^ f3s];
            bf16x8 k1f = *(const bf16x8*)&Ks[cur][hh * 16 + fr][(32 + fk) ^ f3s];
            s[hh] = __builtin_amdgcn_mfma_f32_16x16x32_bf16(k0f, qf[0], s[hh], 0, 0, 0);
            s[hh] = __builtin_amdgcn_mfma_f32_16x16x32_bf16(k1f, qf[1], s[hh], 0, 0, 0);
        }
        __builtin_amdgcn_s_setprio(0);

        if (t0 + 64 > p.Nk) {
            #pragma unroll
            for (int hh = 0; hh < 4; hh++)
                #pragma unroll
                for (int r = 0; r < 4; r++)
                    if (t0 + hh * 16 + 4 * g + r >= p.Nk) s[hh][r] = -1e30f;
        }
        float a0 = fmaxf(fmaxf(s[0][0], s[0][1]), s[0][2]);
        float a1 = fmaxf(fmaxf(s[0][3], s[1][0]), s[1][1]);
        float a2 = fmaxf(fmaxf(s[1][2], s[1][3]), s[2][0]);
        float a3 = fmaxf(fmaxf(s[2][1], s[2][2]), s[2][3]);
        float a4 = fmaxf(fmaxf(s[3][0], s[3][1]), s[3][2]);
        float b0 = fmaxf(fmaxf(a0, a1), a2);
        float b1 = fmaxf(fmaxf(a3, a4), s[3][3]);
        float lmax = fmaxf(b0, b1);
        lmax = fmaxf(lmax, __shfl_xor(lmax, 16, 64));
        lmax = fmaxf(lmax, __shfl_xor(lmax, 32, 64));
        if (!__all(lmax <= mrun + 8.0f)) {            // rescale (rare)
            float mn = fmaxf(mrun, lmax);
            float sf = exp2f(mrun - mn);
            mrun = mn;
            lrun *= sf;
            float sfo[4];
            #pragma unroll
            for (int r = 0; r < 4; r++) sfo[r] = __shfl(sf, g * 4 + r, 64);
            #pragma unroll
            for (int dt = 0; dt < 4; dt++)
                #pragma unroll
                for (int r = 0; r < 4; r++) o[dt][r] *= sfo[r];
        }
        float pp[4][4];
        float ps = 0.f;
        #pragma unroll
        for (int hh = 0; hh < 4; hh++)
            #pragma unroll
            for (int r = 0; r < 4; r++) {
                pp[hh][r] = exp2f(s[hh][r] - mrun);
                ps += pp[hh][r];
            }
        ps += __shfl_xor(ps, 16, 64);
        ps += __shfl_xor(ps, 32, 64);
        lrun += ps;
        #pragma unroll
        for (int hh = 0; hh < 4; hh++) {
            u16x4 pk;
            #pragma unroll
            for (int r = 0; r < 4; r++) pk[r] = f2b_trunc(pp[hh][r]);
            *(u16x4*)&Ps[w][fr][(hh * 16 + g * 4) ^ f3s] = pk;
        }
        bf16x8 pa0 = *(const bf16x8*)&Ps[w][fr][fk ^ f3s];
        bf16x8 pa1 = *(const bf16x8*)&Ps[w][fr][(32 + fk) ^ f3s];
        __builtin_amdgcn_s_setprio(1);
        #pragma unroll
        for (int dt = 0; dt < 4; dt++) {
            bf16x8 vf0 = *(const bf16x8*)&Vs[cur][dt * 16 + fr][fk ^ f3s];
            bf16x8 vf1 = *(const bf16x8*)&Vs[cur][dt * 16 + fr][(32 + fk) ^ f3s];
            o[dt] = __builtin_amdgcn_mfma_f32_16x16x32_bf16(pa0, vf0, o[dt], 0, 0, 0);
            o[dt] = __builtin_amdgcn_mfma_f32_16x16x32_bf16(pa1, vf1, o[dt], 0, 0, 0);
        }
        __builtin_amdgcn_s_setprio(0);
        __builtin_amdgcn_s_barrier();
    }
    float rcp = 1.0f / lrun;
    #pragma unroll
    for (int r = 0; r < 4; r++) {
        float rr = __shfl(rcp, g * 4 + r, 64);
        int q = q0 + g * 4 + r;
        if (q >= p.Nq) continue;
        u16* orow = p.op + a * p.oA + (long long)q * p.oI + h * 64;
        #pragma unroll
        for (int dt = 0; dt < 4; dt++)
            orow[dt * 16 + fr] = f2b(o[dt][r] * rr);
    }
}
__global__ __launch_bounds__(256) void flash_pair(FlashP p0, FlashP p1) {
    __shared__ u16 Ks[2][64][64];
    __shared__ u16 Vs[2][64][64];
    __shared__ u16 Ps[4][16][64];
    int bid = blockIdx.x;
    if (bid < p0.nb) flash_body(p0, bid, Ks, Vs, Ps);
    else flash_body(p1, bid - p0.nb, Ks, Vs, Ps);
}

// ---------------------------------------------------------------------------
extern "C" void kernel_launch(void* const* d_in, const int* in_sizes, int n_in,
                              void* d_out, int out_size, void* d_ws, size_t ws_size,
                              hipStream_t stream) {
    const int B = 8, sN = 196, tN = 1568;
    const int Ms = B * sN;            // 1568
    const int Mt = B * tN;            // 12544
    const int n_sf = Ms * 768;        // 1204224
    const int n_tf = Mt * 768;        // 9633792
    (void)n_in; (void)out_size; (void)ws_size;

    const bool dict_order = (in_sizes[0] == n_sf);
    auto IN = [&](int di, int ai) -> const float* {
        return (const float*)d_in[dict_order ? di : ai];
    };
    const float* in_sx      = IN(0, 35);
    const float* in_tx      = IN(1, 42);
    const float* ln1s_g     = IN(2, 14);
    const float* ln1s_b     = IN(3, 13);
    const float* mha_w      = IN(4, 28);
    const float* mha_b      = IN(5, 25);
    const float* mha_ow     = IN(6, 27);
    const float* mha_ob     = IN(7, 26);
    const float* ln1t_g     = IN(8, 16);
    const float* ln1t_b     = IN(9, 15);
    const float* attn_qkv_w = IN(10, 3);
    const float* attn_q_b   = IN(11, 2);
    const float* attn_v_b   = IN(12, 4);
    const float* attn_pw    = IN(13, 1);
    const float* attn_pb    = IN(14, 0);
    const float* lnt2s_g    = IN(15, 24);
    const float* lnt2s_b    = IN(16, 23);
    const float* t2s_qw     = IN(17, 41);
    const float* t2s_qb     = IN(18, 40);
    const float* t2s_kvw    = IN(19, 37);
    const float* t2s_kvb    = IN(20, 36);
    const float* t2s_pw     = IN(21, 39);
    const float* t2s_pb     = IN(22, 38);
    const float* lns2t_g    = IN(23, 22);
    const float* lns2t_b    = IN(24, 21);
    const float* s2t_qw     = IN(25, 34);
    const float* s2t_qb     = IN(26, 33);
    const float* s2t_kvw    = IN(27, 30);
    const float* s2t_kvb    = IN(28, 29);
    const float* s2t_pw     = IN(29, 32);
    const float* s2t_pb     = IN(30, 31);
    const float* ln2s_g     = IN(31, 18);
    const float* ln2s_b     = IN(32, 17);
    const float* cfc_w      = IN(33, 6);
    const float* cfc_b      = IN(34, 5);
    const float* cproj_w    = IN(35, 8);
    const float* cproj_b    = IN(36, 7);
    const float* ln2t_g     = IN(37, 20);
    const float* ln2t_b     = IN(38, 19);
    const float* fc1_w      = IN(39, 10);
    const float* fc1_b      = IN(40, 9);
    const float* fc2_w      = IN(41, 12);
    const float* fc2_b      = IN(42, 11);

    // ---- residual streams live in d_out (f32) -------------------------------
    float* s_f = (float*)d_out;
    float* t_f = (float*)d_out + n_sf;

    // ---- workspace (~197 MB) ------------------------------------------------
    char* ws = (char*)d_ws;
    size_t off = 0;
    auto take = [&](size_t bytes) { size_t o = off; off += (bytes + 255) & ~(size_t)255; return o; };
    float* biasP = (float*)(ws + take(19968 * 4));
    u16*   yb    = (u16*)(ws + take((size_t)(Ms + Mt) * 768 * 2));  // 21.7 MB
    u16*   bufA  = (u16*)(ws + take((size_t)Mt * 3072 * 2));        // 77.1 MB
    u16*   bufS  = (u16*)(ws + take((size_t)Mt * 768 * 2));         // 19.3 MB
    u16*   bufB  = (u16*)(ws + take((size_t)Mt * 768 * 2));         // 19.3 MB
    u16*   sxb   = (u16*)(ws + take((size_t)Ms * 768 * 2));         // 2.4 MB
    u16*   vtb_t = (u16*)(ws + take((size_t)96 * 64 * 1600 * 2));   // 19.7 MB
    u16*   yb_s  = yb;
    u16*   yb_t  = yb + (size_t)Ms * 768;
    u16*   vtb_s = yb;   // alias: live only while yb is dead (steps 6-7, 16-17)
    auto wtake = [&](size_t nelem) { return (u16*)(ws + take(nelem * 2)); };
    u16 *W_mha   = wtake(2304 * 768), *W_mhao  = wtake(768 * 768);
    u16 *W_qkv   = wtake(2304 * 768), *W_attnp = wtake(768 * 768);
    u16 *W_t2sq  = wtake(768 * 768),  *W_t2skv = wtake(1536 * 768), *W_t2sp = wtake(768 * 768);
    u16 *W_s2tq  = wtake(768 * 768),  *W_s2tkv = wtake(1536 * 768), *W_s2tp = wtake(768 * 768);
    u16 *W_cfc   = wtake(3072 * 768), *W_cproj = wtake(768 * 3072);
    u16 *W_fc1   = wtake(3072 * 768), *W_fc2   = wtake(768 * 3072);

    const int B_MHA = 0, B_QKV = 2304, B_MHAO = 4608, B_ATTNP = 5376;
    const int B_T2SKV = 6144, B_T2SQ = 7680, B_T2SP = 8448, B_S2TQ = 9216;
    const int B_S2TKV = 9984, B_S2TP = 11520, B_CFC = 12288, B_CPROJ = 15360;
    const int B_FC1 = 16128, B_FC2 = 19200;

    auto cdiv = [](int a, int b) { return (a + b - 1) / b; };

    // 1. weights -> bf16 (one launch)
    {
        CvtAll c;
        const float* ss[14] = { mha_w, mha_ow, attn_qkv_w, attn_pw, t2s_qw, t2s_kvw, t2s_pw,
                                s2t_qw, s2t_kvw, s2t_pw, cfc_w, cproj_w, fc1_w, fc2_w };
        u16* dd[14] = { W_mha, W_mhao, W_qkv, W_attnp, W_t2sq, W_t2skv, W_t2sp,
                        W_s2tq, W_s2tkv, W_s2tp, W_cfc, W_cproj, W_fc1, W_fc2 };
        int nn[14] = { 2304*768, 768*768, 2304*768, 768*768, 768*768, 1536*768, 768*768,
                       768*768, 1536*768, 768*768, 3072*768, 768*3072, 3072*768, 768*3072 };
        int cum = 0;
        for (int k = 0; k < 14; k++) { c.s[k] = ss[k]; c.d[k] = dd[k]; c.cum[k] = cum; cum += nn[k]; }
        c.cum[14] = cum;
        cvt_all<<<cdiv(cum, 256), 256, 0, stream>>>(c);
    }
    // 2. bias pool
    build_bias_pool<<<78, 256, 0, stream>>>(biasP,
        mha_b, attn_q_b, attn_v_b, mha_ob, attn_pb, t2s_kvb, t2s_qb, t2s_pb,
        s2t_qb, s2t_kvb, s2t_pb, cfc_b, cproj_b, fc1_b, fc2_b);
    // 3. residual streams <- inputs
    copy_both<<<cdiv(n_sf + n_tf, 256), 256, 0, stream>>>(in_sx, in_tx, s_f, n_sf, n_sf + n_tf);

    auto GP = [&](const u16* A, const u16* W, const float* bias, u16* Cb, float* Cf,
                  int M, int N, int K, int BM) {
        GemmP p; p.A = A; p.W = W; p.bias = bias; p.Cb = Cb; p.Cf = Cf;
        p.M = M; p.N = N; p.K = K; p.gx = (M + BM - 1) / BM; p.nb = p.gx * (N / 128);
        return p;
    };
    auto FP = [&](const u16* qp, const u16* kp, const u16* vt, u16* op,
                  int Nq, int Nk, int Nkp,
                  long long qA, long long qI, long long kA, long long kJ,
                  long long oA, long long oI) {
        FlashP p; p.qp = qp; p.kp = kp; p.vt = vt; p.op = op;
        p.Nq = Nq; p.Nk = Nk; p.Nkp = Nkp; p.gx = (Nq + 63) / 64;
        p.nb = p.gx * (Nq == 8 ? sN * 12 : B * 12);
        p.qA = qA; p.qI = qI; p.kA = kA; p.kJ = kJ; p.oA = oA; p.oI = oI;
        return p;
    };
    auto TP = [&](const u16* vp, u16* vt, int Nk, int Nkp, long long vA, long long vJ, int insts) {
        TransP p; p.vp = vp; p.vt = vt; p.Nk = Nk; p.Nkp = Nkp;
        p.gx = (Nk + 63) / 64; p.nb = p.gx * insts; p.vA = vA; p.vJ = vJ;
        return p;
    };

    // 4. LN pair: ln1s(s_f)->yb_s  ||  ln1t(t_f)->yb_t
    ln_dual<<<Ms + Mt, 256, 0, stream>>>((const float*)d_out, Ms,
        ln1s_g, ln1s_b, yb_s, ln1t_g, ln1t_b, yb_t);

    // 5. GEMM pair: mha qkv (s) || attn qkv (t)
    {
        GemmP p0 = GP(yb_s, W_mha, biasP + B_MHA, bufS, 0, Ms, 2304, 768, 64);
        GemmP p1 = GP(yb_t, W_qkv, biasP + B_QKV, bufA, 0, Mt, 2304, 768, 128);
        gemm_pair<0, 64, 0, 128><<<p0.nb + p1.nb, 256, 0, stream>>>(p0, p1);
    }
    // 6. transpose pair: V_s -> vtb_s(=yb)  ||  V_t -> vtb_t
    {
        TransP p0 = TP(bufS + 1536, vtb_s, 8, 64, 2304LL, (long long)sN * 2304, sN * 12);
        TransP p1 = TP(bufA + 1536, vtb_t, tN, 1600, (long long)tN * 2304, 2304LL, B * 12);
        transpose_pair<<<p0.nb + p1.nb, 256, 0, stream>>>(p0, p1);
    }
    // 7. flash pair: stage1 (batch-axis attn) -> sxb  ||  stage2 -> bufB
    {
        FlashP p0 = FP(bufS, bufS + 768, vtb_s, sxb, 8, 8, 64,
                       2304LL, (long long)sN * 2304, 2304LL, (long long)sN * 2304,
                       768LL, (long long)sN * 768);
        FlashP p1 = FP(bufA, bufA + 768, vtb_t, bufB, tN, tN, 1600,
                       (long long)tN * 2304, 2304LL, (long long)tN * 2304, 2304LL,
                       (long long)tN * 768, 768LL);
        flash_pair<<<p0.nb + p1.nb, 256, 0, stream>>>(p0, p1);
    }
    // 8. GEMM pair: mha proj (s, MODE1) || attn proj (t, MODE4 -> t_f + yb_t)
    {
        GemmP p0 = GP(sxb, W_mhao, biasP + B_MHAO, 0, s_f, Ms, 768, 768, 64);
        GemmP p1 = GP(bufB, W_attnp, biasP + B_ATTNP, yb_t, t_f, Mt, 768, 768, 128);
        gemm_pair<1, 64, 4, 128><<<p0.nb + p1.nb, 256, 0, stream>>>(p0, p1);
    }
    // 9. LN pair: lnt2s(s_f)->yb_s || lns2t(t_f)->bufB
    ln_dual<<<Ms + Mt, 256, 0, stream>>>((const float*)d_out, Ms,
        lnt2s_g, lnt2s_b, yb_s, lns2t_g, lns2t_b, bufB);

    // 10. GEMM pair: t2s_kv (t_x bf16 -> bufA) || s2t_q (ln_t -> bufS)
    {
        GemmP p0 = GP(yb_t, W_t2skv, biasP + B_T2SKV, bufA, 0, Mt, 1536, 768, 128);
        GemmP p1 = GP(bufB, W_s2tq, biasP + B_S2TQ, bufS, 0, Mt, 768, 768, 128);
        gemm_pair<0, 128, 0, 128><<<p0.nb + p1.nb, 256, 0, stream>>>(p0, p1);
    }
    // 11. transpose (t2s V) -> vtb_t
    {
        TransP p0 = TP(bufA + 768, vtb_t, tN, 1600, (long long)tN * 1536, 1536LL, B * 12);
        TransP pz = p0; pz.nb = 0;
        transpose_pair<<<p0.nb, 256, 0, stream>>>(p0, pz);
    }
    // 12. GEMM: t2s_q (yb_s -> sxb)
    {
        GemmP p0 = GP(yb_s, W_t2sq, biasP + B_T2SQ, sxb, 0, Ms, 768, 768, 64);
        GemmP pz = p0; pz.nb = 0;
        gemm_pair<0, 64, 0, 64><<<p0.nb, 256, 0, stream>>>(p0, pz);
    }
    // 13. flash stage3: q=sxb, kv=bufA, vt=vtb_t -> o3=yb_s
    {
        FlashP p0 = FP(sxb, bufA, vtb_t, yb_s, sN, tN, 1600,
                       (long long)sN * 768, 768LL, (long long)tN * 1536, 1536LL,
                       (long long)sN * 768, 768LL);
        FlashP pz = p0; pz.nb = 0;
        flash_pair<<<p0.nb, 256, 0, stream>>>(p0, pz);
    }
    // 14. GEMM: t2s proj (MODE4 -> s_f + sxb mirror)
    {
        GemmP p0 = GP(yb_s, W_t2sp, biasP + B_T2SP, sxb, s_f, Ms, 768, 768, 64);
        GemmP pz = p0; pz.nb = 0;
        gemm_pair<4, 64, 4, 64><<<p0.nb, 256, 0, stream>>>(p0, pz);
    }
    // 15. GEMM: s2t_kv (sxb -> bufB)
    {
        GemmP p0 = GP(sxb, W_s2tkv, biasP + B_S2TKV, bufB, 0, Ms, 1536, 768, 64);
        GemmP pz = p0; pz.nb = 0;
        gemm_pair<0, 64, 0, 64><<<p0.nb, 256, 0, stream>>>(p0, pz);
    }
    // 16. transpose (s2t V) -> vtb_s(=yb)
    {
        TransP p0 = TP(bufB + 768, vtb_s, sN, 256, (long long)sN * 1536, 1536LL, B * 12);
        TransP pz = p0; pz.nb = 0;
        transpose_pair<<<p0.nb, 256, 0, stream>>>(p0, pz);
    }
    // 17. flash stage4: q=bufS, kv=bufB, vt=vtb_s -> o4=bufA
    {
        FlashP p0 = FP(bufS, bufB, vtb_s, bufA, tN, sN, 256,
                       (long long)tN * 768, 768LL, (long long)sN * 1536, 1536LL,
                       (long long)tN * 768, 768LL);
        FlashP pz = p0; pz.nb = 0;
        flash_pair<<<p0.nb, 256, 0, stream>>>(p0, pz);
    }
    // 18. GEMM: s2t proj (MODE1 -> t_f)
    {
        GemmP p0 = GP(bufA, W_s2tp, biasP + B_S2TP, 0, t_f, Mt, 768, 768, 128);
        GemmP pz = p0; pz.nb = 0;
        gemm_pair<1, 128, 1, 128><<<p0.nb, 256, 0, stream>>>(p0, pz);
    }
    // 19. LN pair: ln2s(s_f)->yb_s || ln2t(t_f)->yb_t
    ln_dual<<<Ms + Mt, 256, 0, stream>>>((const float*)d_out, Ms,
        ln2s_g, ln2s_b, yb_s, ln2t_g, ln2t_b, yb_t);

    // 20. GEMM pair: cfc (QuickGELU -> bufS) || fc1 (GELU -> bufA)
    {
        GemmP p0 = GP(yb_s, W_cfc, biasP + B_CFC, bufS, 0, Ms, 3072, 768, 64);
        GemmP p1 = GP(yb_t, W_fc1, biasP + B_FC1, bufA, 0, Mt, 3072, 768, 128);
        gemm_pair<2, 64, 3, 128><<<p0.nb + p1.nb, 256, 0, stream>>>(p0, p1);
    }
    // 21. GEMM pair: cproj (MODE1 -> s_f) || fc2 (MODE1 -> t_f)
    {
        GemmP p0 = GP(bufS, W_cproj, biasP + B_CPROJ, 0, s_f, Ms, 768, 3072, 64);
        GemmP p1 = GP(bufA, W_fc2, biasP + B_FC2, 0, t_f, Mt, 768, 3072, 128);
        gemm_pair<1, 64, 1, 128><<<p0.nb + p1.nb, 256, 0, stream>>>(p0, p1);
    }
}

// Round 13
// 929.622 us; speedup vs baseline: 23.8390x; 1.0412x over previous
//
#include <hip/hip_runtime.h>
#include <stdint.h>

// ---------------------------------------------------------------------------
// Block_6554120094246: dual-stream transformer block (CLIP + video streams).
// f32 in/out. Residual streams in d_out. bf16 intermediates.
// GEMMs: 256x256x64 8-wave double-buffered kernel (counted vmcnt, XOR-swizzled
// LDS, XCD swizzle) for the big t-stream GEMMs; 128-tile pair kernel for the
// rest. MFMA flash attention v5. ~21 paired launches. ws ~197 MB.
// ---------------------------------------------------------------------------

typedef uint16_t u16;
typedef uint16_t u16x8 __attribute__((ext_vector_type(8)));
typedef uint16_t u16x4 __attribute__((ext_vector_type(4)));
typedef short bf16x8 __attribute__((ext_vector_type(8)));
typedef float f32x4 __attribute__((ext_vector_type(4)));

__device__ __forceinline__ float b2f(u16 u) {
    union { float f; uint32_t i; } x;
    x.i = ((uint32_t)u) << 16;
    return x.f;
}
__device__ __forceinline__ u16 f2b(float f) {
    union { float f; uint32_t i; } x;
    x.f = f;
    uint32_t i = x.i;
    uint32_t r = (i + 0x7FFFu + ((i >> 16) & 1u)) >> 16;  // RNE
    return (u16)r;
}
__device__ __forceinline__ u16 f2b_trunc(float f) {      // for P in [0,256]
    union { float f; uint32_t i; } x;
    x.f = f;
    return (u16)(x.i >> 16);
}

// async global->LDS, 16B per lane; LDS dest wave-uniform base (+lane*16B).
__device__ __forceinline__ void gload16(const u16* g, u16* l) {
    __builtin_amdgcn_global_load_lds(
        (const __attribute__((address_space(1))) uint32_t*)g,
        (__attribute__((address_space(3))) uint32_t*)l, 16, 0, 0);
}

// ---- mega weight convert (one launch, 14 segments) --------------------------
struct CvtAll {
    const float* s[14];
    u16* d[14];
    int cum[15];
};
__global__ __launch_bounds__(256) void cvt_all(CvtAll c) {
    int i = blockIdx.x * 256 + threadIdx.x;
    if (i >= c.cum[14]) return;
    int seg = 0;
    #pragma unroll
    for (int k = 1; k < 14; k++) seg += (i >= c.cum[k]);
    int j = i - c.cum[seg];
    c.d[seg][j] = f2b(c.s[seg][j]);
}

// ---- bias pool ---------------------------------------------------------------
__global__ __launch_bounds__(256) void build_bias_pool(float* __restrict__ dst,
    const float* mha_b, const float* attn_q_b, const float* attn_v_b,
    const float* mha_ob, const float* attn_pb, const float* t2s_kvb,
    const float* t2s_qb, const float* t2s_pb, const float* s2t_qb,
    const float* s2t_kvb, const float* s2t_pb, const float* cfc_b,
    const float* cproj_b, const float* fc1_b, const float* fc2_b) {
    int i = blockIdx.x * 256 + threadIdx.x;
    float v = 0.f;
    if (i < 2304) v = mha_b[i];
    else if (i < 4608) { int j = i - 2304; v = (j < 768) ? attn_q_b[j] : (j < 1536 ? 0.f : attn_v_b[j - 1536]); }
    else if (i < 5376) v = mha_ob[i - 4608];
    else if (i < 6144) v = attn_pb[i - 5376];
    else if (i < 7680) { int j = i - 6144; v = (j < 768) ? 0.f : t2s_kvb[j - 768]; }
    else if (i < 8448) v = t2s_qb[i - 7680];
    else if (i < 9216) v = t2s_pb[i - 8448];
    else if (i < 9984) v = s2t_qb[i - 9216];
    else if (i < 11520) { int j = i - 9984; v = (j < 768) ? 0.f : s2t_kvb[j - 768]; }
    else if (i < 12288) v = s2t_pb[i - 11520];
    else if (i < 15360) v = cfc_b[i - 12288];
    else if (i < 16128) v = cproj_b[i - 15360];
    else if (i < 19200) v = fc1_b[i - 16128];
    else if (i < 19968) v = fc2_b[i - 19200];
    else return;
    dst[i] = v;
}

// ---- block reductions --------------------------------------------------------
__device__ __forceinline__ float block_sum(float v, float* red) {
    #pragma unroll
    for (int o = 32; o > 0; o >>= 1) v += __shfl_down(v, o, 64);
    int w = threadIdx.x >> 6, l = threadIdx.x & 63;
    __syncthreads();
    if (l == 0) red[w] = v;
    __syncthreads();
    return red[0] + red[1] + red[2] + red[3];
}

// ---- LN core -----------------------------------------------------------------
__device__ __forceinline__ void ln_row(const float* xr, const float* g,
                                       const float* bta, u16* yr, float* red) {
    const int t = threadIdx.x;
    float v0 = xr[t], v1 = xr[t + 256], v2 = xr[t + 512];
    float mean = block_sum(v0 + v1 + v2, red) * (1.0f / 768.0f);
    float d0 = v0 - mean, d1 = v1 - mean, d2 = v2 - mean;
    float var = block_sum(d0 * d0 + d1 * d1 + d2 * d2, red) * (1.0f / 768.0f);
    float rs = rsqrtf(var + 1e-5f);
    yr[t]       = f2b(d0 * rs * g[t]       + bta[t]);
    yr[t + 256] = f2b(d1 * rs * g[t + 256] + bta[t + 256]);
    yr[t + 512] = f2b(d2 * rs * g[t + 512] + bta[t + 512]);
}

// LN with dual param-sets over concatenated rows
__global__ __launch_bounds__(256) void ln_dual(
    const float* __restrict__ x, int rows0,
    const float* g0, const float* b0, u16* y0,
    const float* g1, const float* b1, u16* y1) {
    __shared__ float red[4];
    int r = blockIdx.x;
    if (r < rows0) ln_row(x + (size_t)r * 768, g0, b0, y0 + (size_t)r * 768, red);
    else ln_row(x + (size_t)r * 768, g1, b1, y1 + (size_t)(r - rows0) * 768, red);
}

// first LN fused with stream copy (inputs -> d_out residuals + LN outputs)
__global__ __launch_bounds__(256) void ln_dual_in(
    const float* __restrict__ xs, const float* __restrict__ xt,
    float* __restrict__ xcopy, int rows0,
    const float* g0, const float* b0, u16* y0,
    const float* g1, const float* b1, u16* y1) {
    __shared__ float red[4];
    int r = blockIdx.x, t = threadIdx.x;
    const float* xr; const float* g; const float* bta; u16* yr;
    if (r < rows0) { xr = xs + (size_t)r * 768; g = g0; bta = b0; yr = y0 + (size_t)r * 768; }
    else { xr = xt + (size_t)(r - rows0) * 768; g = g1; bta = b1; yr = y1 + (size_t)(r - rows0) * 768; }
    float v0 = xr[t], v1 = xr[t + 256], v2 = xr[t + 512];
    float* xc = xcopy + (size_t)r * 768;
    xc[t] = v0; xc[t + 256] = v1; xc[t + 512] = v2;
    float mean = block_sum(v0 + v1 + v2, red) * (1.0f / 768.0f);
    float d0 = v0 - mean, d1 = v1 - mean, d2 = v2 - mean;
    float var = block_sum(d0 * d0 + d1 * d1 + d2 * d2, red) * (1.0f / 768.0f);
    float rs = rsqrtf(var + 1e-5f);
    yr[t]       = f2b(d0 * rs * g[t]       + bta[t]);
    yr[t + 256] = f2b(d1 * rs * g[t + 256] + bta[t + 256]);
    yr[t + 512] = f2b(d2 * rs * g[t + 512] + bta[t + 512]);
}

// ---- V transpose (pairable) ---------------------------------------------------
struct TransP {
    const u16* vp; u16* vt;
    int Nk, Nkp, gx, nb;
    long long vA, vJ;
};
__device__ __forceinline__ void transpose_body(const TransP p, int bid, u16 (*T)[72]) {
    const int x = bid % p.gx, inst = bid / p.gx;
    const int a = inst / 12, h = inst % 12;
    const int t0 = x * 64;
    const int tid = threadIdx.x;
    const int kvl = tid >> 2, dseg = (tid & 3) * 16;
    u16x8 v0 = {}, v1 = {};
    if (t0 + kvl < p.Nk) {
        const u16* src = p.vp + a * p.vA + (long long)(t0 + kvl) * p.vJ + h * 64 + dseg;
        v0 = *(const u16x8*)src;
        v1 = *(const u16x8*)(src + 8);
    }
    *(u16x8*)&T[kvl][dseg]     = v0;
    *(u16x8*)&T[kvl][dseg + 8] = v1;
    __syncthreads();
    const int dl = tid >> 2, kseg = (tid & 3) * 16;
    u16x8 w0, w1;
    #pragma unroll
    for (int j = 0; j < 8; j++) w0[j] = T[kseg + j][dl];
    #pragma unroll
    for (int j = 0; j < 8; j++) w1[j] = T[kseg + 8 + j][dl];
    u16* orow = p.vt + ((size_t)inst * 64 + dl) * p.Nkp + t0 + kseg;
    *(u16x8*)orow = w0;
    *(u16x8*)(orow + 8) = w1;
}
__global__ __launch_bounds__(256) void transpose_pair(TransP p0, TransP p1) {
    __shared__ u16 T[64][72];
    int bid = blockIdx.x;
    if (bid < p0.nb) transpose_body(p0, bid, T);
    else transpose_body(p1, bid - p0.nb, T);
}

// ---- 128-tile MFMA GEMM body (pairable) ---------------------------------------
struct GemmP {
    const u16* A; const u16* W; const float* bias;
    u16* Cb; float* Cf;
    int M, N, K, gx, nb;
};
template <int MODE, int BM>
__device__ __forceinline__ void gemm_body(const GemmP p, int bid,
                                          u16 (*AsF)[32], u16 (*BsF)[32]) {
    constexpr int MI = BM / 32;
    const int tid = threadIdx.x;
    const int lane = tid & 63;
    const int wid = tid >> 6;
    const int wr = (wid >> 1) * (BM / 2), wc = (wid & 1) * 64;
    const int bx = bid % p.gx, by = bid / p.gx;
    const int m0 = bx * BM, n0 = by * 128;
    const int lr = lane >> 2, lc = (lane & 3) * 8;
    const int fr = lane & 15, fk = (lane >> 4) * 8;
    const int abase = wid * (BM / 4);
    const int bbase = wid * 32;
    f32x4 acc[MI][4] = {};
    for (int k0 = 0; k0 < p.K; k0 += 64) {
        #pragma unroll
        for (int s = 0; s < 2; s++) {
            #pragma unroll
            for (int j = 0; j < BM / 64; j++) {
                int rowa = m0 + abase + j * 16 + lr;
                rowa = rowa < p.M ? rowa : p.M - 1;
                gload16(p.A + (size_t)rowa * p.K + k0 + s * 32 + lc,
                        &AsF[s * 128 + abase + j * 16][0]);
            }
            #pragma unroll
            for (int j = 0; j < 2; j++) {
                gload16(p.W + (size_t)(n0 + bbase + j * 16 + lr) * p.K + k0 + s * 32 + lc,
                        &BsF[s * 128 + bbase + j * 16][0]);
            }
        }
        __syncthreads();
        #pragma unroll
        for (int s = 0; s < 2; s++) {
            bf16x8 a[MI], b[4];
            #pragma unroll
            for (int i = 0; i < MI; i++) a[i] = *(const bf16x8*)&AsF[s * 128 + wr + i * 16 + fr][fk];
            #pragma unroll
            for (int j = 0; j < 4; j++) b[j] = *(const bf16x8*)&BsF[s * 128 + wc + j * 16 + fr][fk];
            #pragma unroll
            for (int i = 0; i < MI; i++)
                #pragma unroll
                for (int j = 0; j < 4; j++)
                    acc[i][j] = __builtin_amdgcn_mfma_f32_16x16x32_bf16(a[i], b[j], acc[i][j], 0, 0, 0);
        }
        __syncthreads();
    }
    const int er = (lane >> 4) * 4;
    #pragma unroll
    for (int i = 0; i < MI; i++) {
        #pragma unroll
        for (int reg = 0; reg < 4; reg++) {
            int r = m0 + wr + i * 16 + er + reg;
            if (r >= p.M) continue;
            #pragma unroll
            for (int j = 0; j < 4; j++) {
                int c = n0 + wc + j * 16 + fr;
                float v = acc[i][j][reg] + p.bias[c];
                size_t idx = (size_t)r * p.N + c;
                if (MODE == 1) {
                    p.Cf[idx] += v;
                } else if (MODE == 4) {
                    float nv = p.Cf[idx] + v;
                    p.Cf[idx] = nv;
                    p.Cb[idx] = f2b(nv);
                } else {
                    if (MODE == 2) v = v / (1.0f + expf(-1.702f * v));
                    if (MODE == 3) v = 0.5f * v * (1.0f + erff(v * 0.70710678118654752f));
                    p.Cb[idx] = f2b(v);
                }
            }
        }
    }
}
template <int M0, int B0, int M1, int B1>
__global__ __launch_bounds__(256) void gemm_pair(GemmP p0, GemmP p1) {
    __shared__ u16 As[2 * 128][32];
    __shared__ u16 Bs[2 * 128][32];
    int bid = blockIdx.x;
    if (bid < p0.nb) gemm_body<M0, B0>(p0, bid, As, Bs);
    else gemm_body<M1, B1>(p1, bid - p0.nb, As, Bs);
}
// two gemms + a transpose in one launch
template <int M0, int B0, int M1, int B1>
__global__ __launch_bounds__(256) void gemm2_trans(GemmP p0, GemmP p1, TransP t0) {
    __shared__ u16 As[2 * 128][32];
    __shared__ u16 Bs[2 * 128][32];
    int bid = blockIdx.x;
    if (bid < p0.nb) gemm_body<M0, B0>(p0, bid, As, Bs);
    else if (bid < p0.nb + p1.nb) gemm_body<M1, B1>(p1, bid - p0.nb, As, Bs);
    else transpose_body(t0, bid - p0.nb - p1.nb, (u16(*)[72])&As[0][0]);
}

// ---- 256x256x64 8-wave GEMM (T2 swizzle + counted-vmcnt pipeline) ------------
// Requires M%256==0, N%256==0, K%64==0. 512 threads (8 waves: wm=wid>>2,
// wn=wid&3). Wave output rows fi*32+wm*16 (fi<8), cols wn*64+fj*16 (fj<4).
// LDS: double-buffered A/B tiles [256][64] bf16, swizzled col^=(row&7)<<3 via
// pre-swizzled global source (linear gload_lds dest). Halves of next tile
// staged one per phase in order [B0,B1,A0,A1]; waits: vmcnt(2) before phase 1
// (needs B0,B1,A0), vmcnt(4) before phase 3 (needs A1). 2 barriers/K-tile.
template <int MODE>
__global__ __launch_bounds__(512) void gemm256(
    const u16* __restrict__ A, const u16* __restrict__ W,
    const float* __restrict__ bias, u16* __restrict__ Cb,
    float* __restrict__ Cf, int M, int N, int K) {
    __shared__ u16 LA[2][256][64];
    __shared__ u16 LB[2][256][64];
    const int tid = threadIdx.x;
    const int lane = tid & 63, wid = tid >> 6;
    const int wm = wid >> 2, wn = wid & 3;
    // XCD-bijective block swizzle (m204)
    int nwg = gridDim.x;
    int q = nwg >> 3, r8 = nwg & 7;
    int xcd = blockIdx.x & 7, orig = blockIdx.x >> 3;
    int bid = (xcd < r8 ? xcd * (q + 1) : r8 * (q + 1) + (xcd - r8) * q) + orig;
    const int gx = M >> 8;
    const int bx = bid % gx, by = bid / gx;
    const int m0 = bx * 256, n0 = by * 256;
    // staging geometry: per call, thread covers row (tid>>3), col (tid&7)*8
    const int srow = tid >> 3;                      // 0..63 per call
    const int sgcol = ((tid & 7) * 8) ^ (((tid >> 3) & 7) << 3);
    const u16* Ag = A + (size_t)m0 * K;
    const u16* Bg = W + (size_t)n0 * K;
    // fragment geometry
    const int fr = lane & 15, g = lane >> 4, fk = g * 8;
    const int rsw = (fr & 7) << 3;

    auto stageHalf = [&](u16* half, const u16* gsrc, int rowOff, int kc) {
        #pragma unroll
        for (int c = 0; c < 2; c++) {
            int row = rowOff + c * 64 + srow;
            gload16(gsrc + (size_t)row * K + kc + sgcol,
                    half + c * 4096 + wid * 512);
        }
    };
    auto stage1 = [&](int s, int kc, int which) {
        if (which == 0) stageHalf(&LB[s][0][0],   Bg, 0,   kc);
        else if (which == 1) stageHalf(&LB[s][128][0], Bg, 128, kc);
        else if (which == 2) stageHalf(&LA[s][0][0],   Ag, 0,   kc);
        else stageHalf(&LA[s][128][0], Ag, 128, kc);
    };

    f32x4 acc[8][4] = {};
    const int NT = K >> 6;
    // prologue: tile 0 -> buf 0, order B0,B1,A0,A1
    stage1(0, 0, 0); stage1(0, 0, 1); stage1(0, 0, 2); stage1(0, 0, 3);

    for (int kt = 0; kt < NT; kt++) {
        const int cur = kt & 1;
        const int kn = (kt + 1) << 6;
        const bool pf = (kt + 1 < NT);
        // ---- phases 1-2: B all + A rows [0,128) ------------------------------
        asm volatile("s_waitcnt vmcnt(2)" ::: "memory");   // B0,B1,A0 resident
        __builtin_amdgcn_s_barrier();
        bf16x8 bfr[4][2];
        #pragma unroll
        for (int fj = 0; fj < 4; fj++)
            #pragma unroll
            for (int ks = 0; ks < 2; ks++)
                bfr[fj][ks] = *(const bf16x8*)&LB[cur][wn * 64 + fj * 16 + fr][(ks * 32 + fk) ^ rsw];
        #pragma unroll
        for (int ph = 0; ph < 2; ph++) {                   // fi pairs {0,1},{2,3}
            bf16x8 afr[2][2];
            #pragma unroll
            for (int i2 = 0; i2 < 2; i2++)
                #pragma unroll
                for (int ks = 0; ks < 2; ks++)
                    afr[i2][ks] = *(const bf16x8*)&LA[cur][(ph * 2 + i2) * 32 + wm * 16 + fr][(ks * 32 + fk) ^ rsw];
            if (pf) stage1(cur ^ 1, kn, ph);               // B0', B1'
            __builtin_amdgcn_s_setprio(1);
            #pragma unroll
            for (int i2 = 0; i2 < 2; i2++)
                #pragma unroll
                for (int ks = 0; ks < 2; ks++)
                    #pragma unroll
                    for (int fj = 0; fj < 4; fj++)
                        acc[ph * 2 + i2][fj] = __builtin_amdgcn_mfma_f32_16x16x32_bf16(
                            afr[i2][ks], bfr[fj][ks], acc[ph * 2 + i2][fj], 0, 0, 0);
            __builtin_amdgcn_s_setprio(0);
        }
        // ---- phases 3-4: A rows [128,256) -------------------------------------
        if (pf) asm volatile("s_waitcnt vmcnt(4)" ::: "memory");   // A1 resident
        else    asm volatile("s_waitcnt vmcnt(0)" ::: "memory");
        __builtin_amdgcn_s_barrier();
        #pragma unroll
        for (int ph = 2; ph < 4; ph++) {                   // fi pairs {4,5},{6,7}
            bf16x8 afr[2][2];
            #pragma unroll
            for (int i2 = 0; i2 < 2; i2++)
                #pragma unroll
                for (int ks = 0; ks < 2; ks++)
                    afr[i2][ks] = *(const bf16x8*)&LA[cur][(ph * 2 + i2) * 32 + wm * 16 + fr][(ks * 32 + fk) ^ rsw];
            if (pf) stage1(cur ^ 1, kn, ph);               // A0', A1'
            __builtin_amdgcn_s_setprio(1);
            #pragma unroll
            for (int i2 = 0; i2 < 2; i2++)
                #pragma unroll
                for (int ks = 0; ks < 2; ks++)
                    #pragma unroll
                    for (int fj = 0; fj < 4; fj++)
                        acc[ph * 2 + i2][fj] = __builtin_amdgcn_mfma_f32_16x16x32_bf16(
                            afr[i2][ks], bfr[fj][ks], acc[ph * 2 + i2][fj], 0, 0, 0);
            __builtin_amdgcn_s_setprio(0);
        }
    }
    // ---- epilogue -----------------------------------------------------------
    const int er = g * 4;
    #pragma unroll
    for (int fi = 0; fi < 8; fi++) {
        #pragma unroll
        for (int reg = 0; reg < 4; reg++) {
            int rr = m0 + fi * 32 + wm * 16 + er + reg;
            #pragma unroll
            for (int fj = 0; fj < 4; fj++) {
                int c = n0 + wn * 64 + fj * 16 + fr;
                float v = acc[fi][fj][reg] + bias[c];
                size_t idx = (size_t)rr * N + c;
                if (MODE == 1) {
                    Cf[idx] += v;
                } else if (MODE == 4) {
                    float nv = Cf[idx] + v;
                    Cf[idx] = nv;
                    Cb[idx] = f2b(nv);
                } else {
                    if (MODE == 2) v = v / (1.0f + expf(-1.702f * v));
                    if (MODE == 3) v = 0.5f * v * (1.0f + erff(v * 0.70710678118654752f));
                    Cb[idx] = f2b(v);
                }
            }
        }
    }
}

// ---- MFMA flash attention v5 (unchanged, pairable) ---------------------------
struct FlashP {
    const u16* qp; const u16* kp; const u16* vt; u16* op;
    int Nq, Nk, Nkp, gx, nb;
    long long qA, qI, kA, kJ, oA, oI;
};
__device__ __forceinline__ void flash_body(const FlashP p, int bid,
    u16 (*Ks)[64][64], u16 (*Vs)[64][64], u16 (*Ps)[16][64]) {
    const int x = bid % p.gx, inst = bid / p.gx;
    const int a = inst / 12, h = inst % 12;
    const int tid = threadIdx.x, lane = tid & 63, w = tid >> 6;
    const int fr = lane & 15, g = lane >> 4, fk = g * 8;
    const int f3s = (fr & 7) << 3;
    const u16* qb = p.qp + a * p.qA + h * 64;
    const u16* kb = p.kp + a * p.kA + h * 64;
    const u16* vtb = p.vt + (size_t)inst * 64 * p.Nkp;
    const int q0 = x * 64 + w * 16;

    bf16x8 qf[2];
    {
        u16x8 raw0 = {}, raw1 = {};
        int qr = q0 + fr;
        if (qr < p.Nq) {
            const u16* qrp = qb + (long long)qr * p.qI;
            raw0 = *(const u16x8*)(qrp + fk);
            raw1 = *(const u16x8*)(qrp + 32 + fk);
        }
        const float QS = 0.125f * 1.44269504088896340736f;
        u16x8 s0, s1;
        #pragma unroll
        for (int e = 0; e < 8; e++) {
            s0[e] = f2b(b2f(raw0[e]) * QS);
            s1[e] = f2b(b2f(raw1[e]) * QS);
        }
        qf[0] = *(bf16x8*)&s0;
        qf[1] = *(bf16x8*)&s1;
    }
    float mrun = -1e30f, lrun = 0.f;
    f32x4 o[4] = {};

    const int l = lane;
    const int srow = w * 8 + (l >> 3);
    const int sdcol = ((l & 7) * 8) ^ (((l >> 3) & 7) << 3);

    auto STAGE = [&](int s, int t0) {
        #pragma unroll
        for (int c = 0; c < 2; c++) {
            int row = c * 32 + srow;
            int kr = t0 + row; if (kr >= p.Nk) kr = p.Nk - 1;
            gload16(kb + (long long)kr * p.kJ + sdcol, &Ks[s][0][0] + c * 2048 + w * 512);
            gload16(vtb + (size_t)row * p.Nkp + t0 + sdcol, &Vs[s][0][0] + c * 2048 + w * 512);
        }
    };

    const int nt = (p.Nk + 63) >> 6;
    STAGE(0, 0);
    for (int it = 0; it < nt; ++it) {
        const int t0 = it << 6;
        const int cur = it & 1;
        if (it + 1 < nt) {
            STAGE(cur ^ 1, t0 + 64);
            asm volatile("s_waitcnt vmcnt(4)" ::: "memory");
        } else {
            asm volatile("s_waitcnt vmcnt(0)" ::: "memory");
        }
        __builtin_amdgcn_s_barrier();

        f32x4 s[4] = {};
        __builtin_amdgcn_s_setprio(1);
        #pragma unroll
        for (int hh = 0; hh < 4; hh++) {
            bf16x8 k0f = *(const bf16x8*)&Ks[cur][hh * 16 + fr][fk ^ f3s];
            bf16x8 k1f = *(const bf16x8*)&Ks[cur][hh * 16 + fr][(32 + fk) ^ f3s];
            s[hh] = __builtin_amdgcn_mfma_f32_16x16x32_bf16(k0f, qf[0], s[hh], 0, 0, 0);
            s[hh] = __builtin_amdgcn_mfma_f32_16x16x32_bf16(k1f, qf[1], s[hh], 0, 0, 0);
        }
        __builtin_amdgcn_s_setprio(0);

        if (t0 + 64 > p.Nk) {
            #pragma unroll
            for (int hh = 0; hh < 4; hh++)
                #pragma unroll
                for (int r = 0; r < 4; r++)
                    if (t0 + hh * 16 + 4 * g + r >= p.Nk) s[hh][r] = -1e30f;
        }
        float a0 = fmaxf(fmaxf(s[0][0], s[0][1]), s[0][2]);
        float a1 = fmaxf(fmaxf(s[0][3], s[1][0]), s[1][1]);
        float a2 = fmaxf(fmaxf(s[1][2], s[1][3]), s[2][0]);
        float a3 = fmaxf(fmaxf(s[2][1], s[2][2]), s[2][3]);
        float a4 = fmaxf(fmaxf(s[3][0], s[3][1]), s[3][2]);
        float b0 = fmaxf(fmaxf(a0, a1), a2);
        float b1 = fmaxf(fmaxf(a3, a4), s[3][3]);
        float lmax = fmaxf(b0, b1);
        lmax = fmaxf(lmax, __shfl_xor(lmax, 16, 64));
        lmax = fmaxf(lmax, __shfl_xor(lmax, 32, 64));
        if (!__all(lmax <= mrun + 8.0f)) {
            float mn = fmaxf(mrun, lmax);
            float sf = exp2f(mrun - mn);
            mrun = mn;
            lrun *= sf;
            float sfo[4];
            #pragma unroll
            for (int r = 0; r < 4; r++) sfo[r] = __shfl(sf, g * 4 + r, 64);
            #pragma unroll
            for (int dt = 0; dt < 4; dt++)
                #pragma unroll
                for (int r = 0; r < 4; r++) o[dt][r] *= sfo[r];
        }
        float pp[4][4];
        float ps = 0.f;
        #pragma unroll
        for (int hh = 0; hh < 4; hh++)
            #pragma unroll
            for (int r = 0; r < 4; r++) {
                pp[hh][r] = exp2f(s[hh][r] - mrun);
                ps += pp[hh][r];
            }
        ps += __shfl_xor(ps, 16, 64);
        ps += __shfl_xor(ps, 32, 64);
        lrun += ps;
        #pragma unroll
        for (int hh = 0; hh < 4; hh++) {
            u16x4 pk;
            #pragma unroll
            for (int r = 0; r < 4; r++) pk[r] = f2b_trunc(pp[hh][r]);
            *(u16x4*)&Ps[w][fr][(hh * 16 + g * 4) ^ f3s] = pk;
        }
        bf16x8 pa0 = *(const bf16x8*)&Ps[w][fr][fk ^ f3s];
        bf16x8 pa1 = *(const bf16x8*)&Ps[w][fr][(32 + fk) ^ f3s];
        __builtin_amdgcn_s_setprio(1);
        #pragma unroll
        for (int dt = 0; dt < 4; dt++) {
            bf16x8 vf0 = *(const bf16x8*)&Vs[cur][dt * 16 + fr][fk ^ f3s];
            bf16x8 vf1 = *(const bf16x8*)&Vs[cur][dt * 16 + fr][(32 + fk) ^ f3s];
            o[dt] = __builtin_amdgcn_mfma_f32_16x16x32_bf16(pa0, vf0, o[dt], 0, 0, 0);
            o[dt] = __builtin_amdgcn_mfma_f32_16x16x32_bf16(pa1, vf1, o[dt], 0, 0, 0);
        }
        __builtin_amdgcn_s_setprio(0);
        __builtin_amdgcn_s_barrier();
    }
    float rcp = 1.0f / lrun;
    #pragma unroll
    for (int r = 0; r < 4; r++) {
        float rr = __shfl(rcp, g * 4 + r, 64);
        int qq = q0 + g * 4 + r;
        if (qq >= p.Nq) continue;
        u16* orow = p.op + a * p.oA + (long long)qq * p.oI + h * 64;
        #pragma unroll
        for (int dt = 0; dt < 4; dt++)
            orow[dt * 16 + fr] = f2b(o[dt][r] * rr);
    }
}
__global__ __launch_bounds__(256) void flash_pair(FlashP p0, FlashP p1) {
    __shared__ u16 Ks[2][64][64];
    __shared__ u16 Vs[2][64][64];
    __shared__ u16 Ps[4][16][64];
    int bid = blockIdx.x;
    if (bid < p0.nb) flash_body(p0, bid, Ks, Vs, Ps);
    else flash_body(p1, bid - p0.nb, Ks, Vs, Ps);
}

// ---------------------------------------------------------------------------
extern "C" void kernel_launch(void* const* d_in, const int* in_sizes, int n_in,
                              void* d_out, int out_size, void* d_ws, size_t ws_size,
                              hipStream_t stream) {
    const int B = 8, sN = 196, tN = 1568;
    const int Ms = B * sN;            // 1568
    const int Mt = B * tN;            // 12544
    const int n_sf = Ms * 768;
    const int n_tf = Mt * 768;
    (void)n_in; (void)out_size; (void)ws_size;

    const bool dict_order = (in_sizes[0] == n_sf);
    auto IN = [&](int di, int ai) -> const float* {
        return (const float*)d_in[dict_order ? di : ai];
    };
    const float* in_sx      = IN(0, 35);
    const float* in_tx      = IN(1, 42);
    const float* ln1s_g     = IN(2, 14);
    const float* ln1s_b     = IN(3, 13);
    const float* mha_w      = IN(4, 28);
    const float* mha_b      = IN(5, 25);
    const float* mha_ow     = IN(6, 27);
    const float* mha_ob     = IN(7, 26);
    const float* ln1t_g     = IN(8, 16);
    const float* ln1t_b     = IN(9, 15);
    const float* attn_qkv_w = IN(10, 3);
    const float* attn_q_b   = IN(11, 2);
    const float* attn_v_b   = IN(12, 4);
    const float* attn_pw    = IN(13, 1);
    const float* attn_pb    = IN(14, 0);
    const float* lnt2s_g    = IN(15, 24);
    const float* lnt2s_b    = IN(16, 23);
    const float* t2s_qw     = IN(17, 41);
    const float* t2s_qb     = IN(18, 40);
    const float* t2s_kvw    = IN(19, 37);
    const float* t2s_kvb    = IN(20, 36);
    const float* t2s_pw     = IN(21, 39);
    const float* t2s_pb     = IN(22, 38);
    const float* lns2t_g    = IN(23, 22);
    const float* lns2t_b    = IN(24, 21);
    const float* s2t_qw     = IN(25, 34);
    const float* s2t_qb     = IN(26, 33);
    const float* s2t_kvw    = IN(27, 30);
    const float* s2t_kvb    = IN(28, 29);
    const float* s2t_pw     = IN(29, 32);
    const float* s2t_pb     = IN(30, 31);
    const float* ln2s_g     = IN(31, 18);
    const float* ln2s_b     = IN(32, 17);
    const float* cfc_w      = IN(33, 6);
    const float* cfc_b      = IN(34, 5);
    const float* cproj_w    = IN(35, 8);
    const float* cproj_b    = IN(36, 7);
    const float* ln2t_g     = IN(37, 20);
    const float* ln2t_b     = IN(38, 19);
    const float* fc1_w      = IN(39, 10);
    const float* fc1_b      = IN(40, 9);
    const float* fc2_w      = IN(41, 12);
    const float* fc2_b      = IN(42, 11);

    float* s_f = (float*)d_out;
    float* t_f = (float*)d_out + n_sf;

    // ---- workspace ----------------------------------------------------------
    char* ws = (char*)d_ws;
    size_t off = 0;
    auto take = [&](size_t bytes) { size_t o = off; off += (bytes + 255) & ~(size_t)255; return o; };
    float* biasP = (float*)(ws + take(19968 * 4));
    u16*   yb    = (u16*)(ws + take((size_t)(Ms + Mt) * 768 * 2));
    u16*   bufA  = (u16*)(ws + take((size_t)Mt * 3072 * 2));
    u16*   bufS  = (u16*)(ws + take((size_t)Mt * 768 * 2));
    u16*   bufB  = (u16*)(ws + take((size_t)Mt * 768 * 2));
    u16*   sxb   = (u16*)(ws + take((size_t)Ms * 768 * 2));
    u16*   vtb_t = (u16*)(ws + take((size_t)96 * 64 * 1600 * 2));
    u16*   yb_s  = yb;
    u16*   yb_t  = yb + (size_t)Ms * 768;
    u16*   vtb_s = yb;   // alias: live only while yb fully dead (steps 6-7)
    auto wtake = [&](size_t nelem) { return (u16*)(ws + take(nelem * 2)); };
    u16 *W_mha   = wtake(2304 * 768), *W_mhao  = wtake(768 * 768);
    u16 *W_qkv   = wtake(2304 * 768), *W_attnp = wtake(768 * 768);
    u16 *W_t2sq  = wtake(768 * 768),  *W_t2skv = wtake(1536 * 768), *W_t2sp = wtake(768 * 768);
    u16 *W_s2tq  = wtake(768 * 768),  *W_s2tkv = wtake(1536 * 768), *W_s2tp = wtake(768 * 768);
    u16 *W_cfc   = wtake(3072 * 768), *W_cproj = wtake(768 * 3072);
    u16 *W_fc1   = wtake(3072 * 768), *W_fc2   = wtake(768 * 3072);

    const int B_MHA = 0, B_QKV = 2304, B_MHAO = 4608, B_ATTNP = 5376;
    const int B_T2SKV = 6144, B_T2SQ = 7680, B_T2SP = 8448, B_S2TQ = 9216;
    const int B_S2TKV = 9984, B_S2TP = 11520, B_CFC = 12288, B_CPROJ = 15360;
    const int B_FC1 = 16128, B_FC2 = 19200;

    auto cdiv = [](int a, int b) { return (a + b - 1) / b; };

    // 1. weights -> bf16
    {
        CvtAll c;
        const float* ss[14] = { mha_w, mha_ow, attn_qkv_w, attn_pw, t2s_qw, t2s_kvw, t2s_pw,
                                s2t_qw, s2t_kvw, s2t_pw, cfc_w, cproj_w, fc1_w, fc2_w };
        u16* dd[14] = { W_mha, W_mhao, W_qkv, W_attnp, W_t2sq, W_t2skv, W_t2sp,
                        W_s2tq, W_s2tkv, W_s2tp, W_cfc, W_cproj, W_fc1, W_fc2 };
        int nn[14] = { 2304*768, 768*768, 2304*768, 768*768, 768*768, 1536*768, 768*768,
                       768*768, 1536*768, 768*768, 3072*768, 768*3072, 3072*768, 768*3072 };
        int cum = 0;
        for (int k = 0; k < 14; k++) { c.s[k] = ss[k]; c.d[k] = dd[k]; c.cum[k] = cum; cum += nn[k]; }
        c.cum[14] = cum;
        cvt_all<<<cdiv(cum, 256), 256, 0, stream>>>(c);
    }
    // 2. bias pool
    build_bias_pool<<<78, 256, 0, stream>>>(biasP,
        mha_b, attn_q_b, attn_v_b, mha_ob, attn_pb, t2s_kvb, t2s_qb, t2s_pb,
        s2t_qb, s2t_kvb, s2t_pb, cfc_b, cproj_b, fc1_b, fc2_b);

    auto GP = [&](const u16* A, const u16* W, const float* bias, u16* Cb, float* Cf,
                  int M, int N, int K, int BM) {
        GemmP p; p.A = A; p.W = W; p.bias = bias; p.Cb = Cb; p.Cf = Cf;
        p.M = M; p.N = N; p.K = K; p.gx = (M + BM - 1) / BM; p.nb = p.gx * (N / 128);
        return p;
    };
    auto FPm = [&](const u16* qp, const u16* kp, const u16* vt, u16* op,
                   int Nq, int Nk, int Nkp, int insts,
                   long long qA, long long qI, long long kA, long long kJ,
                   long long oA, long long oI) {
        FlashP p; p.qp = qp; p.kp = kp; p.vt = vt; p.op = op;
        p.Nq = Nq; p.Nk = Nk; p.Nkp = Nkp; p.gx = (Nq + 63) / 64;
        p.nb = p.gx * insts;
        p.qA = qA; p.qI = qI; p.kA = kA; p.kJ = kJ; p.oA = oA; p.oI = oI;
        return p;
    };
    auto TP = [&](const u16* vp, u16* vt, int Nk, int Nkp, long long vA, long long vJ, int insts) {
        TransP p; p.vp = vp; p.vt = vt; p.Nk = Nk; p.Nkp = Nkp;
        p.gx = (Nk + 63) / 64; p.nb = p.gx * insts; p.vA = vA; p.vJ = vJ;
        return p;
    };

    // 3. stream copy + LN1 pair
    ln_dual_in<<<Ms + Mt, 256, 0, stream>>>(in_sx, in_tx, (float*)d_out, Ms,
        ln1s_g, ln1s_b, yb_s, ln1t_g, ln1t_b, yb_t);

    // 4. qkv_t (256-tile)
    gemm256<0><<<49 * (2304 / 256), 512, 0, stream>>>(yb_t, W_qkv, biasP + B_QKV, bufA, (float*)0, Mt, 2304, 768);
    // 5. qkv_s (128-tile, single)
    {
        GemmP p0 = GP(yb_s, W_mha, biasP + B_MHA, bufS, 0, Ms, 2304, 768, 64);
        GemmP pz = p0; pz.nb = 0;
        gemm_pair<0, 64, 0, 64><<<p0.nb, 256, 0, stream>>>(p0, pz);
    }
    // 6. transpose pair
    {
        TransP p0 = TP(bufS + 1536, vtb_s, 8, 64, 2304LL, (long long)sN * 2304, sN * 12);
        TransP p1 = TP(bufA + 1536, vtb_t, tN, 1600, (long long)tN * 2304, 2304LL, B * 12);
        transpose_pair<<<p0.nb + p1.nb, 256, 0, stream>>>(p0, p1);
    }
    // 7. flash pair (stage1 -> sxb, stage2 -> bufB)
    {
        FlashP p0 = FPm(bufS, bufS + 768, vtb_s, sxb, 8, 8, 64, sN * 12,
                        2304LL, (long long)sN * 2304, 2304LL, (long long)sN * 2304,
                        768LL, (long long)sN * 768);
        FlashP p1 = FPm(bufA, bufA + 768, vtb_t, bufB, tN, tN, 1600, B * 12,
                        (long long)tN * 2304, 2304LL, (long long)tN * 2304, 2304LL,
                        (long long)tN * 768, 768LL);
        flash_pair<<<p0.nb + p1.nb, 256, 0, stream>>>(p0, p1);
    }
    // 8. proj pair (mha MODE1 || attn MODE4 -> t_f + yb_t)
    {
        GemmP p0 = GP(sxb, W_mhao, biasP + B_MHAO, 0, s_f, Ms, 768, 768, 64);
        GemmP p1 = GP(bufB, W_attnp, biasP + B_ATTNP, yb_t, t_f, Mt, 768, 768, 128);
        gemm_pair<1, 64, 4, 128><<<p0.nb + p1.nb, 256, 0, stream>>>(p0, p1);
    }
    // 9. LN pair: lnt2s -> yb_s || lns2t -> bufB
    ln_dual<<<Ms + Mt, 256, 0, stream>>>((const float*)d_out, Ms,
        lnt2s_g, lnt2s_b, yb_s, lns2t_g, lns2t_b, bufB);
    // 10. t2s_kv (256-tile)
    gemm256<0><<<49 * (1536 / 256), 512, 0, stream>>>(yb_t, W_t2skv, biasP + B_T2SKV, bufA, (float*)0, Mt, 1536, 768);
    // 11. s2t_q || t2s_q || transpose(t2s V)
    {
        GemmP p0 = GP(bufB, W_s2tq, biasP + B_S2TQ, bufS, 0, Mt, 768, 768, 128);
        GemmP p1 = GP(yb_s, W_t2sq, biasP + B_T2SQ, sxb, 0, Ms, 768, 768, 64);
        TransP t0 = TP(bufA + 768, vtb_t, tN, 1600, (long long)tN * 1536, 1536LL, B * 12);
        gemm2_trans<0, 128, 0, 64><<<p0.nb + p1.nb + t0.nb, 256, 0, stream>>>(p0, p1, t0);
    }
    // 12. flash stage3 -> yb_s
    {
        FlashP p0 = FPm(sxb, bufA, vtb_t, yb_s, sN, tN, 1600, B * 12,
                        (long long)sN * 768, 768LL, (long long)tN * 1536, 1536LL,
                        (long long)sN * 768, 768LL);
        FlashP pz = p0; pz.nb = 0;
        flash_pair<<<p0.nb, 256, 0, stream>>>(p0, pz);
    }
    // 13. t2s proj (MODE4 -> s_f + sxb mirror)
    {
        GemmP p0 = GP(yb_s, W_t2sp, biasP + B_T2SP, sxb, s_f, Ms, 768, 768, 64);
        GemmP pz = p0; pz.nb = 0;
        gemm_pair<4, 64, 4, 64><<<p0.nb, 256, 0, stream>>>(p0, pz);
    }
    // 14. LN ln2s -> yb_s
    ln_dual<<<Ms, 256, 0, stream>>>((const float*)d_out, Ms,
        ln2s_g, ln2s_b, yb_s, ln2s_g, ln2s_b, yb_s);
    // 15. s2t_kv || cfc (QuickGELU -> yb_t)
    {
        GemmP p0 = GP(sxb, W_s2tkv, biasP + B_S2TKV, bufB, 0, Ms, 1536, 768, 64);
        GemmP p1 = GP(yb_s, W_cfc, biasP + B_CFC, yb_t, 0, Ms, 3072, 768, 64);
        gemm_pair<0, 64, 2, 64><<<p0.nb + p1.nb, 256, 0, stream>>>(p0, p1);
    }
    // 16. cproj (MODE1 -> s_f) || transpose(s2t V -> bufA)
    {
        GemmP p0 = GP(yb_t, W_cproj, biasP + B_CPROJ, 0, s_f, Ms, 768, 3072, 64);
        GemmP pz = p0; pz.nb = 0;
        TransP t0 = TP(bufB + 768, bufA, sN, 256, (long long)sN * 1536, 1536LL, B * 12);
        gemm2_trans<1, 64, 1, 64><<<p0.nb + t0.nb, 256, 0, stream>>>(p0, pz, t0);
    }
    // 17. flash stage4 -> yb
    {
        FlashP p0 = FPm(bufS, bufB, bufA, yb, tN, sN, 256, B * 12,
                        (long long)tN * 768, 768LL, (long long)sN * 1536, 1536LL,
                        (long long)tN * 768, 768LL);
        FlashP pz = p0; pz.nb = 0;
        flash_pair<<<p0.nb, 256, 0, stream>>>(p0, pz);
    }
    // 18. s2t proj (MODE1 -> t_f)
    {
        GemmP p0 = GP(yb, W_s2tp, biasP + B_S2TP, 0, t_f, Mt, 768, 768, 128);
        GemmP pz = p0; pz.nb = 0;
        gemm_pair<1, 128, 1, 128><<<p0.nb, 256, 0, stream>>>(p0, pz);
    }
    // 19. LN ln2t -> yb_t
    ln_dual<<<Mt, 256, 0, stream>>>(t_f, 0,
        ln2t_g, ln2t_b, yb_t, ln2t_g, ln2t_b, yb_t);
    // 20. fc1 (256-tile, exact GELU)
    gemm256<3><<<49 * (3072 / 256), 512, 0, stream>>>(yb_t, W_fc1, biasP + B_FC1, bufA, (float*)0, Mt, 3072, 768);
    // 21. fc2 (MODE1 -> t_f)
    {
        GemmP p0 = GP(bufA, W_fc2, biasP + B_FC2, 0, t_f, Mt, 768, 3072, 128);
        GemmP pz = p0; pz.nb = 0;
        gemm_pair<1, 128, 1, 128><<<p0.nb, 256, 0, stream>>>(p0, pz);
    }
}